// Round 3
// baseline (643.100 us; speedup 1.0000x reference)
//
#include <hip/hip_runtime.h>

// 2-layer hetero GraphSAGE, fp32 compute, bf16 gather tables, bucketed CSR build,
// persistent-weight register-tiled combines. HARD RULE (R6/R7 post-mortems):
// one K-loop per tile kernel — dual-weight-loop kernels spill to 256 VGPR +
// half-GB scratch regardless of static/dynamic LDS. Fusion happens via the
// PRE operand or block-range parameter selection (k_ctileDual64), never via a
// second weight matrix in the same loop nest. R8: split gathers lower FETCH
// but not time (latency-bound) — keep the fused dual gather.
// R9: one coalesced index-vector load + __shfl distribution + 8-deep load
// burst broke the nbr->row chain: 86.4 -> 74.4 us.
// R10 post-mortem (REVERTED): moving loads under scalar branches w/o zero-init
// let the compiler re-use v0..v7 (VGPR 36->32) and interleave load->acc,
// destroying the burst (74.4 -> 79.6). The per-lane zero-inits are LOAD-
// LIVENESS ANCHORS — keep them. Gather is memory-request-service bound at
// ~74us (VALUBusy 72% vs 53% gave same time); do not diet it further.
// R11: block-range fusion of serialized dispatches: partition P+U in one
// launch; k_ctileDual64 (runtime epilogue flags) merges independent K=64
// combines (layer1 #1+#3, both layer-2 passes); histA+cast8 fused.

using u16 = unsigned short;
using u32 = unsigned int;

__device__ __forceinline__ u16 bf16r(float f) {            // round-to-nearest-even
    u32 b = __float_as_uint(f);
    b += 0x7fffu + ((b >> 16) & 1u);
    return (u16)(b >> 16);
}
__device__ __forceinline__ float bflo(u32 u) { return __uint_as_float(u << 16); }
__device__ __forceinline__ float bfhi(u32 u) { return __uint_as_float(u & 0xffff0000u); }

#define BSH 8          // bucket = key >> BSH, 256 node ids per bucket
#define MAXB 512       // max buckets per direction (NU=100000 -> 391)
#define CHUNK 4096     // edges per partition block
#define RPT 16         // CHUNK / 256
#define HB 512         // histogram blocks in fused hist+cast kernel

// flags for k_ctileDual64 epilogue/prologue
#define FPRE  1
#define FBIAS 2
#define FRELU 4
#define FEMIT 8

// ---- pass A (fused): blocks [0,HB) coarse bucket histograms both directions;
// ---- blocks [HB,..) cast x_user -> bf16 shadow (independent work) ----
__global__ __launch_bounds__(256) void k_histCast(const int* __restrict__ esrc,
                                                  const int* __restrict__ edst,
                                                  int* __restrict__ bcntP,
                                                  int* __restrict__ bcntU,
                                                  int NBP, int NBU, int E,
                                                  const float* __restrict__ xc,
                                                  u16* __restrict__ yc, int n8) {
    __shared__ int hP[MAXB];
    __shared__ int hU[MAXB];
    int tid = threadIdx.x;
    if ((int)blockIdx.x >= HB) {
        int i = (blockIdx.x - HB) * 256 + tid;
        if (i < n8) {
            const float4* x4 = (const float4*)xc;
            float4 a = x4[i * 2], b = x4[i * 2 + 1];
            uint4 o;
            o.x = (u32)bf16r(a.x) | ((u32)bf16r(a.y) << 16);
            o.y = (u32)bf16r(a.z) | ((u32)bf16r(a.w) << 16);
            o.z = (u32)bf16r(b.x) | ((u32)bf16r(b.y) << 16);
            o.w = (u32)bf16r(b.z) | ((u32)bf16r(b.w) << 16);
            ((uint4*)yc)[i] = o;
        }
        return;
    }
    for (int i = tid; i < MAXB; i += 256) { hP[i] = 0; hU[i] = 0; }
    __syncthreads();
    int E4 = E >> 2;
    const int4* s4 = (const int4*)esrc;
    const int4* d4 = (const int4*)edst;
    int stride = HB * 256;
    for (int i = blockIdx.x * 256 + tid; i < E4; i += stride) {
        int4 s = s4[i], d = d4[i];
        atomicAdd(&hU[s.x >> BSH], 1); atomicAdd(&hU[s.y >> BSH], 1);
        atomicAdd(&hU[s.z >> BSH], 1); atomicAdd(&hU[s.w >> BSH], 1);
        atomicAdd(&hP[d.x >> BSH], 1); atomicAdd(&hP[d.y >> BSH], 1);
        atomicAdd(&hP[d.z >> BSH], 1); atomicAdd(&hP[d.w >> BSH], 1);
    }
    if (blockIdx.x == 0 && tid < (E & 3)) {
        int e = E4 * 4 + tid;
        atomicAdd(&hU[esrc[e] >> BSH], 1);
        atomicAdd(&hP[edst[e] >> BSH], 1);
    }
    __syncthreads();
    for (int i = tid; i < NBP; i += 256) if (hP[i]) atomicAdd(&bcntP[i], hP[i]);
    for (int i = tid; i < NBU; i += 256) if (hU[i]) atomicAdd(&bcntU[i], hU[i]);
}

// ---- scan bucket counts -> bases[NB+1] and working cursor[NB]; block 0 = P, 1 = U ----
__global__ __launch_bounds__(256) void k_scanBuckets(const int* __restrict__ cntP,
                                                     int* __restrict__ basesP,
                                                     int* __restrict__ curP, int NBP,
                                                     const int* __restrict__ cntU,
                                                     int* __restrict__ basesU,
                                                     int* __restrict__ curU, int NBU) {
    const int* cnt; int* bases; int* cur; int NB;
    if (blockIdx.x == 0) { cnt = cntP; bases = basesP; cur = curP; NB = NBP; }
    else                 { cnt = cntU; bases = basesU; cur = curU; NB = NBU; }
    __shared__ int sA[MAXB];
    __shared__ int sB[MAXB];
    int tid = threadIdx.x;
    int v0 = (tid < NB) ? cnt[tid] : 0;
    int v1 = (tid + 256 < NB) ? cnt[tid + 256] : 0;
    sA[tid] = v0; sA[tid + 256] = v1;
    __syncthreads();
    int* src = sA; int* dst = sB;
    for (int off = 1; off < MAXB; off <<= 1) {
        dst[tid] = src[tid] + ((tid >= off) ? src[tid - off] : 0);
        int i2 = tid + 256;
        dst[i2] = src[i2] + ((i2 >= off) ? src[i2 - off] : 0);
        __syncthreads();
        int* t = src; src = dst; dst = t;
    }
    if (tid < NB)       { bases[tid] = src[tid] - v0;             cur[tid] = src[tid] - v0; }
    if (tid + 256 < NB) { bases[tid + 256] = src[tid + 256] - v1; cur[tid + 256] = src[tid + 256] - v1; }
    if (tid == 0) bases[NB] = src[MAXB - 1];
}

// ---- pass B (fused both directions): partition edges into bucket-ordered
// (key,payload) pairs, coalesced flush. blocks [0,pblocks) = P, rest = U ----
__global__ __launch_bounds__(256) void k_partition2(
    const int* __restrict__ keysP, const int* __restrict__ payP,
    int* __restrict__ curPp, uint2* __restrict__ pairsP, int NBP,
    const int* __restrict__ keysU, const int* __restrict__ payU,
    int* __restrict__ curUp, uint2* __restrict__ pairsU, int NBU,
    int E, int pblocks) {
    __shared__ int hist[MAXB];
    __shared__ int sA[MAXB];
    __shared__ int sB[MAXB];
    __shared__ int bx[MAXB];
    __shared__ int gbase[MAXB];
    __shared__ uint2 prs[CHUNK];
    const int* keys; const int* payload; int* cursor; uint2* pairs; int NB, cb;
    if ((int)blockIdx.x < pblocks) {
        keys = keysP; payload = payP; cursor = curPp; pairs = pairsP; NB = NBP;
        cb = blockIdx.x;
    } else {
        keys = keysU; payload = payU; cursor = curUp; pairs = pairsU; NB = NBU;
        cb = blockIdx.x - pblocks;
    }
    int tid = threadIdx.x;
    int i0 = cb * CHUNK;
    int count = min(CHUNK, E - i0);
    for (int i = tid; i < MAXB; i += 256) hist[i] = 0;
    __syncthreads();
    int keyr[RPT], payr[RPT], rankr[RPT];
#pragma unroll
    for (int r = 0; r < RPT; ++r) {
        int idx = r * 256 + tid;
        if (idx < count) {
            int k = keys[i0 + idx];
            keyr[r] = k;
            payr[r] = payload[i0 + idx];
            rankr[r] = atomicAdd(&hist[k >> BSH], 1);
        } else keyr[r] = -1;
    }
    __syncthreads();
    // exclusive scan of hist -> bx (ping-pong, 512 wide)
    sA[tid] = hist[tid]; sA[tid + 256] = hist[tid + 256];
    __syncthreads();
    int* src = sA; int* dst = sB;
    for (int off = 1; off < MAXB; off <<= 1) {
        dst[tid] = src[tid] + ((tid >= off) ? src[tid - off] : 0);
        int i2 = tid + 256;
        dst[i2] = src[i2] + ((i2 >= off) ? src[i2 - off] : 0);
        __syncthreads();
        int* t = src; src = dst; dst = t;
    }
    bx[tid] = src[tid] - hist[tid];
    bx[tid + 256] = src[tid + 256] - hist[tid + 256];
    __syncthreads();
    for (int b = tid; b < NB; b += 256) {
        int c = hist[b];
        gbase[b] = c ? atomicAdd(&cursor[b], c) : 0;
    }
    // stage into LDS in bucket order
#pragma unroll
    for (int r = 0; r < RPT; ++r) {
        if (keyr[r] >= 0)
            prs[bx[keyr[r] >> BSH] + rankr[r]] = make_uint2((u32)keyr[r], (u32)payr[r]);
    }
    __syncthreads();
    // coalesced segment copy-out
    for (int j = tid; j < count; j += 256) {
        uint2 pr = prs[j];
        int b = pr.x >> BSH;
        pairs[gbase[b] + (j - bx[b])] = pr;
    }
}

// ---- pass C: per-bucket fine fill -> nbr, deg, ptr(start); both directions fused ----
// nbr stores BYTE offsets into the 128B-row bf16 tables (id << 7).
__global__ __launch_bounds__(256) void k_bucketFill(
    const uint2* __restrict__ pairsP, const int* __restrict__ basesP, int NBP,
    int* __restrict__ nbr_p, int* __restrict__ deg_p, int* __restrict__ ptr_p, int NP,
    const uint2* __restrict__ pairsU, const int* __restrict__ basesU, int NBU,
    int* __restrict__ nbr_u, int* __restrict__ deg_u, int* __restrict__ ptr_u, int NU) {
    const uint2* pairs; const int* bases; int* nbr; int* deg; int* ptr; int N; int bucket;
    if ((int)blockIdx.x < NBP) {
        pairs = pairsP; bases = basesP; nbr = nbr_p; deg = deg_p; ptr = ptr_p; N = NP;
        bucket = blockIdx.x;
    } else {
        pairs = pairsU; bases = basesU; nbr = nbr_u; deg = deg_u; ptr = ptr_u; N = NU;
        bucket = blockIdx.x - NBP;
    }
    int tid = threadIdx.x;
    int base = bases[bucket];
    int cnt = bases[bucket + 1] - base;
    __shared__ int h[256];
    __shared__ int s[256];
    __shared__ int cur[256];
    h[tid] = 0;
    __syncthreads();
    for (int j = tid; j < cnt; j += 256) atomicAdd(&h[pairs[base + j].x & 255], 1);
    __syncthreads();
    int d = h[tid];
    s[tid] = d;
    __syncthreads();
    for (int off = 1; off < 256; off <<= 1) {
        int v = (tid >= off) ? s[tid - off] : 0;
        __syncthreads();
        s[tid] += v;
        __syncthreads();
    }
    int excl = s[tid] - d;
    int node = bucket * 256 + tid;
    if (node < N) { deg[node] = d; ptr[node] = base + excl; }
    cur[tid] = excl;
    __syncthreads();
    for (int j = tid; j < cnt; j += 256) {
        uint2 pr = pairs[base + j];
        int pos = atomicAdd(&cur[pr.x & 255], 1);
        nbr[base + pos] = (int)(pr.y << 7);     // byte offset of row (128B rows)
    }
}

#define ACC8(A0,A1,A2,A3,A4,A5,A6,A7,V) \
    A0 += bflo((V).x); A1 += bfhi((V).x); A2 += bflo((V).y); A3 += bfhi((V).y); \
    A4 += bflo((V).z); A5 += bfhi((V).z); A6 += bflo((V).w); A7 += bfhi((V).w);

// ------- fused dual gather-mean: nodes [0,NA) CSR A, [NA,NA+NB) CSR B -------
// wave per node; 8 lanes per bf16 row (uint4).
// R9 shape (VERIFIED 74.4us — do not restructure): ONE coalesced offset-vector
// load per <=64 rows, __shfl distribution, then 8 row loads issued with
// per-lane masks + ZERO-INIT (the zero-inits force v0..v7 simultaneously live
// -> compiler keeps the 8-deep burst; removing them serializes, see R10).
__global__ __launch_bounds__(256) void k_gather2(
    const u16* __restrict__ yA, const int* __restrict__ nbrA, const int* __restrict__ stpA,
    const int* __restrict__ degA, float* __restrict__ aggA, int NA,
    const u16* __restrict__ yB, const int* __restrict__ nbrB, const int* __restrict__ stpB,
    const int* __restrict__ degB, float* __restrict__ aggB, int NB) {
    int w = (blockIdx.x * 256 + threadIdx.x) >> 6;
    int lane = threadIdx.x & 63;
    if (w >= NA + NB) return;
    const u16* y; const int* nbr; const int* stp; const int* deg; float* agg; int n;
    if (w < NA) { y = yA; nbr = nbrA; stp = stpA; deg = degA; agg = aggA; n = w; }
    else        { y = yB; nbr = nbrB; stp = stpB; deg = degB; agg = aggB; n = w - NA; }
    const int q = lane >> 3, t = lane & 7;
    const int d = deg[n];
    const int st = stp[n];
    const char* yb = (const char*)y + t * 16;
    float a0=0,a1=0,a2=0,a3=0,a4=0,a5=0,a6=0,a7=0;
    for (int j = 0; j < d; j += 64) {
        const int cnt = min(d - j, 64);           // wave-uniform
        int offv = 0;
        if (lane < cnt) offv = nbr[st + j + lane];   // one coalesced 256B load
        // distribute + burst-issue all row loads (independent, exec-masked tails)
#define GLD(R) \
        int g##R = __shfl(offv, R * 8 + q, 64); \
        uint4 v##R = make_uint4(0u, 0u, 0u, 0u); \
        if (R * 8 + q < cnt) v##R = *(const uint4*)(yb + g##R);
        GLD(0) GLD(1) GLD(2) GLD(3) GLD(4) GLD(5) GLD(6) GLD(7)
#undef GLD
        // accumulate (rounds beyond cnt are uniform-skipped; masked lanes hold 0)
#define ACCR(R) if (R * 8 < cnt) { ACC8(a0,a1,a2,a3,a4,a5,a6,a7,v##R) }
        ACCR(0) ACCR(1) ACCR(2) ACCR(3) ACCR(4) ACCR(5) ACCR(6) ACCR(7)
#undef ACCR
    }
#pragma unroll
    for (int m = 8; m < 64; m <<= 1) {
        a0 += __shfl_xor(a0, m, 64); a1 += __shfl_xor(a1, m, 64);
        a2 += __shfl_xor(a2, m, 64); a3 += __shfl_xor(a3, m, 64);
        a4 += __shfl_xor(a4, m, 64); a5 += __shfl_xor(a5, m, 64);
        a6 += __shfl_xor(a6, m, 64); a7 += __shfl_xor(a7, m, 64);
    }
    if (q == 0) {
        float dinv = 1.0f / (float)max(d, 1);
        float* dstp = agg + n * 64 + t * 8;
        *(float4*)dstp       = make_float4(a0 * dinv, a1 * dinv, a2 * dinv, a3 * dinv);
        *(float4*)(dstp + 4) = make_float4(a4 * dinv, a5 * dinv, a6 * dinv, a7 * dinv);
    }
}

// ======= persistent-weight register-tiled combine, single input (STATIC LDS) =======
// h = act( (PRE?pre:0) + (BIAS?b:0) + x@W );  STORE=0 -> only bf16 emit
#define FMA_ROW(ACC, O, W4) \
    ACC[0] += (O) * (W4).x; ACC[1] += (O) * (W4).y; \
    ACC[2] += (O) * (W4).z; ACC[3] += (O) * (W4).w;

template <int K, int ROWS, bool RELU, bool EMIT, bool PRE, bool BIAS, bool STORE>
__global__ __launch_bounds__(256) void k_ctile(const float* __restrict__ pre,
                                               const float* __restrict__ bias,
                                               const float* __restrict__ x,
                                               const float* __restrict__ W,
                                               float* __restrict__ h,
                                               u16* __restrict__ hbf, int N) {
    constexpr int RR = ROWS / 16;
    constexpr int STRIDE = K + 4;
    constexpr int KF4 = K / 4;
    __shared__ float Ws[K * 64];
    __shared__ float op[ROWS * STRIDE];
    const int tid = threadIdx.x;
    for (int i = tid; i < K * 16; i += 256)
        ((float4*)Ws)[i] = ((const float4*)W)[i];
    const int c4 = (tid & 15) * 4;
    const int rb = (tid >> 4) * RR;
    float bx_ = 0.f, by_ = 0.f, bz_ = 0.f, bw_ = 0.f;
    if (BIAS) {
        float4 b4 = *(const float4*)(bias + c4);
        bx_ = b4.x; by_ = b4.y; bz_ = b4.z; bw_ = b4.w;
    }
    const int ntiles = (N + ROWS - 1) / ROWS;
    for (int tile = blockIdx.x; tile < ntiles; tile += gridDim.x) {
        const int row0 = tile * ROWS;
        __syncthreads();
        for (int i = tid; i < ROWS * KF4; i += 256) {
            int r = i / KF4, k4 = (i % KF4) * 4;
            int row = row0 + r;
            float4 v = make_float4(0.f, 0.f, 0.f, 0.f);
            if (row < N) v = *(const float4*)(x + (size_t)row * K + k4);
            *(float4*)(op + r * STRIDE + k4) = v;
        }
        __syncthreads();
        float acc[RR][4];
#pragma unroll
        for (int i = 0; i < RR; ++i) {
            float px = 0.f, py = 0.f, pz = 0.f, pw = 0.f;
            if (PRE) {
                int row = row0 + rb + i;
                if (row < N) {
                    float4 p = *(const float4*)(pre + row * 64 + c4);
                    px = p.x; py = p.y; pz = p.z; pw = p.w;
                }
            }
            acc[i][0] = bx_ + px; acc[i][1] = by_ + py;
            acc[i][2] = bz_ + pz; acc[i][3] = bw_ + pw;
        }
        for (int kk = 0; kk < K; kk += 4) {
            float4 w0 = *(const float4*)(Ws + (kk + 0) * 64 + c4);
            float4 w1 = *(const float4*)(Ws + (kk + 1) * 64 + c4);
            float4 w2 = *(const float4*)(Ws + (kk + 2) * 64 + c4);
            float4 w3 = *(const float4*)(Ws + (kk + 3) * 64 + c4);
#pragma unroll
            for (int i = 0; i < RR; ++i) {
                float4 o = *(const float4*)(op + (rb + i) * STRIDE + kk);
                FMA_ROW(acc[i], o.x, w0);
                FMA_ROW(acc[i], o.y, w1);
                FMA_ROW(acc[i], o.z, w2);
                FMA_ROW(acc[i], o.w, w3);
            }
        }
#pragma unroll
        for (int i = 0; i < RR; ++i) {
            int row = row0 + rb + i;
            if (row >= N) continue;
            float v0 = acc[i][0], v1 = acc[i][1], v2 = acc[i][2], v3 = acc[i][3];
            if (RELU) {
                v0 = fmaxf(v0, 0.f); v1 = fmaxf(v1, 0.f);
                v2 = fmaxf(v2, 0.f); v3 = fmaxf(v3, 0.f);
            }
            if (STORE)
                *(float4*)(h + row * 64 + c4) = make_float4(v0, v1, v2, v3);
            if (EMIT) {
                uint2 o;
                o.x = (u32)bf16r(v0) | ((u32)bf16r(v1) << 16);
                o.y = (u32)bf16r(v2) | ((u32)bf16r(v3) << 16);
                *(uint2*)(hbf + row * 64 + c4) = o;
            }
        }
    }
}

// ======= dual combine: two independent K=64 problems, block-range selected =======
// Runtime epilogue flags (FPRE/FBIAS/FRELU/FEMIT — wave-uniform SGPR branches,
// zero inner-loop cost). One weight matrix, one K-loop per block (HARD RULE).
// Always stores h. h = (PRE?pre:0) + (BIAS?b:0) + x@W, then optional relu/emit.
__global__ __launch_bounds__(256) void k_ctileDual64(
    const float* __restrict__ pre0, const float* __restrict__ bias0,
    const float* __restrict__ x0, const float* __restrict__ W0,
    float* __restrict__ h0, u16* __restrict__ hbf0, int N0, int flags0, int g0,
    const float* __restrict__ pre1, const float* __restrict__ bias1,
    const float* __restrict__ x1, const float* __restrict__ W1,
    float* __restrict__ h1, u16* __restrict__ hbf1, int N1, int flags1) {
    constexpr int ROWS = 64, RR = 4, STRIDE = 68, KF4 = 16;
    __shared__ float Ws[64 * 64];
    __shared__ float op[ROWS * STRIDE];
    const float* pre; const float* bias; const float* x; const float* W;
    float* h; u16* hbf;
    int N, bid, gsz, flags;
    if ((int)blockIdx.x < g0) {
        pre = pre0; bias = bias0; x = x0; W = W0; h = h0; hbf = hbf0;
        N = N0; flags = flags0; bid = blockIdx.x; gsz = g0;
    } else {
        pre = pre1; bias = bias1; x = x1; W = W1; h = h1; hbf = hbf1;
        N = N1; flags = flags1; bid = blockIdx.x - g0; gsz = gridDim.x - g0;
    }
    const int tid = threadIdx.x;
    for (int i = tid; i < 64 * 16; i += 256)
        ((float4*)Ws)[i] = ((const float4*)W)[i];
    const int c4 = (tid & 15) * 4;
    const int rb = (tid >> 4) * RR;
    float bx_ = 0.f, by_ = 0.f, bz_ = 0.f, bw_ = 0.f;
    if (flags & FBIAS) {
        float4 b4 = *(const float4*)(bias + c4);
        bx_ = b4.x; by_ = b4.y; bz_ = b4.z; bw_ = b4.w;
    }
    const int ntiles = (N + ROWS - 1) / ROWS;
    for (int tile = bid; tile < ntiles; tile += gsz) {
        const int row0 = tile * ROWS;
        __syncthreads();
        for (int i = tid; i < ROWS * KF4; i += 256) {
            int r = i / KF4, k4 = (i % KF4) * 4;
            int row = row0 + r;
            float4 v = make_float4(0.f, 0.f, 0.f, 0.f);
            if (row < N) v = *(const float4*)(x + (size_t)row * 64 + k4);
            *(float4*)(op + r * STRIDE + k4) = v;
        }
        __syncthreads();
        float acc[RR][4];
#pragma unroll
        for (int i = 0; i < RR; ++i) {
            float px = 0.f, py = 0.f, pz = 0.f, pw = 0.f;
            if (flags & FPRE) {
                int row = row0 + rb + i;
                if (row < N) {
                    float4 p = *(const float4*)(pre + row * 64 + c4);
                    px = p.x; py = p.y; pz = p.z; pw = p.w;
                }
            }
            acc[i][0] = bx_ + px; acc[i][1] = by_ + py;
            acc[i][2] = bz_ + pz; acc[i][3] = bw_ + pw;
        }
        for (int kk = 0; kk < 64; kk += 4) {
            float4 w0 = *(const float4*)(Ws + (kk + 0) * 64 + c4);
            float4 w1 = *(const float4*)(Ws + (kk + 1) * 64 + c4);
            float4 w2 = *(const float4*)(Ws + (kk + 2) * 64 + c4);
            float4 w3 = *(const float4*)(Ws + (kk + 3) * 64 + c4);
#pragma unroll
            for (int i = 0; i < RR; ++i) {
                float4 o = *(const float4*)(op + (rb + i) * STRIDE + kk);
                FMA_ROW(acc[i], o.x, w0);
                FMA_ROW(acc[i], o.y, w1);
                FMA_ROW(acc[i], o.z, w2);
                FMA_ROW(acc[i], o.w, w3);
            }
        }
#pragma unroll
        for (int i = 0; i < RR; ++i) {
            int row = row0 + rb + i;
            if (row >= N) continue;
            float v0 = acc[i][0], v1 = acc[i][1], v2 = acc[i][2], v3 = acc[i][3];
            if (flags & FRELU) {
                v0 = fmaxf(v0, 0.f); v1 = fmaxf(v1, 0.f);
                v2 = fmaxf(v2, 0.f); v3 = fmaxf(v3, 0.f);
            }
            *(float4*)(h + row * 64 + c4) = make_float4(v0, v1, v2, v3);
            if (flags & FEMIT) {
                uint2 o;
                o.x = (u32)bf16r(v0) | ((u32)bf16r(v1) << 16);
                o.y = (u32)bf16r(v2) | ((u32)bf16r(v3) << 16);
                *(uint2*)(hbf + row * 64 + c4) = o;
            }
        }
    }
}

// ------- out[e] = dot64(hu[lu[e]], hp[lp[e]]); quarter-wave per edge, float4 -------
__global__ __launch_bounds__(256) void k_classify4(const float* __restrict__ hu,
                                                   const float* __restrict__ hp,
                                                   const int* __restrict__ lu,
                                                   const int* __restrict__ lp,
                                                   float* __restrict__ out, int EL) {
    int w = (blockIdx.x * 256 + threadIdx.x) >> 6;
    int lane = threadIdx.x & 63;
    int q = lane >> 4, t = lane & 15;
    int e = w * 4 + q;
    float v = 0.f;
    if (e < EL) {
        int u = lu[e], p = lp[e];
        float4 a = *(const float4*)(hu + u * 64 + t * 4);
        float4 b = *(const float4*)(hp + p * 64 + t * 4);
        v = a.x * b.x + a.y * b.y + a.z * b.z + a.w * b.w;
    }
#pragma unroll
    for (int m = 1; m < 16; m <<= 1) v += __shfl_xor(v, m, 64);
    if (t == 0 && e < EL) out[e] = v;
}

extern "C" void kernel_launch(void* const* d_in, const int* in_sizes, int n_in,
                              void* d_out, int out_size, void* d_ws, size_t ws_size,
                              hipStream_t stream) {
    const float* x_user    = (const float*)d_in[0];
    const float* x_product = (const float*)d_in[1];
    const float* W1bl = (const float*)d_in[2];
    const float* b1b  = (const float*)d_in[3];
    const float* W1br = (const float*)d_in[4];
    const float* W1rl = (const float*)d_in[5];
    const float* b1r  = (const float*)d_in[6];
    const float* W1rr = (const float*)d_in[7];
    const float* W2bl = (const float*)d_in[8];
    const float* b2b  = (const float*)d_in[9];
    const float* W2br = (const float*)d_in[10];
    const float* W2rl = (const float*)d_in[11];
    const float* b2r  = (const float*)d_in[12];
    const float* W2rr = (const float*)d_in[13];
    const int* esrc = (const int*)d_in[14];
    const int* edst = (const int*)d_in[15];
    const int* lu   = (const int*)d_in[16];
    const int* lp   = (const int*)d_in[17];

    const int NU = in_sizes[0] / 64;
    const int NP = in_sizes[1] / 128;
    const int E  = in_sizes[14];
    const int EL = in_sizes[16];
    const int NBP = (NP + 255) >> BSH;
    const int NBU = (NU + 255) >> BSH;

    // ---- workspace layout ----
    char* ws = (char*)d_ws;
    size_t off = 0;
    auto alloc = [&](size_t bytes) -> void* {
        void* p = ws + off;
        off += (bytes + 255) & ~(size_t)255;
        return p;
    };
    int*   deg_u  = (int*)alloc((size_t)NU * 4);
    int*   deg_p  = (int*)alloc((size_t)NP * 4);
    int*   ptr_u  = (int*)alloc((size_t)NU * 4);
    int*   ptr_p  = (int*)alloc((size_t)NP * 4);
    int*   bcntP  = (int*)alloc((size_t)MAXB * 4);   // contiguous with bcntU: one memset
    int*   bcntU  = (int*)alloc((size_t)MAXB * 4);
    int*   basesP = (int*)alloc((size_t)(MAXB + 1) * 4);
    int*   basesU = (int*)alloc((size_t)(MAXB + 1) * 4);
    int*   curP   = (int*)alloc((size_t)MAXB * 4);
    int*   curU   = (int*)alloc((size_t)MAXB * 4);
    int*   nbr_u  = (int*)alloc((size_t)E * 4);
    int*   nbr_p  = (int*)alloc((size_t)E * 4);
    // union region: pairs (CSR build) then agg (gather onward)
    size_t aggBytes = (size_t)(NP + NU) * 64 * 4;
    size_t pairBytes = (size_t)E * 8 * 2;
    char* uni = (char*)alloc(aggBytes > pairBytes ? aggBytes : pairBytes);
    float* aggP   = (float*)uni;
    float* aggU   = (float*)(uni + (size_t)NP * 64 * 4);
    uint2* pairsP = (uint2*)uni;
    uint2* pairsU = (uint2*)(uni + (size_t)E * 8);
    u16*   bfA    = (u16*)alloc((size_t)NU * 64 * 2);  // x_user_bf, then h_u_bf
    u16*   bfB    = (u16*)alloc((size_t)NP * 64 * 2);  // y_p1_bf,  then h_p_bf
    float* h_p    = (float*)alloc((size_t)NP * 64 * 4);
    float* h_u    = (float*)alloc((size_t)NU * 64 * 4);

    // ---- CSR build: bucketed counting sort, both directions ----
    hipMemsetAsync(bcntP, 0, (size_t)MAXB * 2 * 4, stream);  // bcntP+bcntU contiguous
    const int n8 = NU * 64 / 8;
    const int castBlocks = (n8 + 255) / 256;
    k_histCast<<<HB + castBlocks, 256, 0, stream>>>(esrc, edst, bcntP, bcntU, NBP, NBU, E,
                                                    x_user, bfA, n8);
    k_scanBuckets<<<2, 256, 0, stream>>>(bcntP, basesP, curP, NBP, bcntU, basesU, curU, NBU);
    const int pblocks = (E + CHUNK - 1) / CHUNK;
    k_partition2<<<2 * pblocks, 256, 0, stream>>>(edst, esrc, curP, pairsP, NBP,
                                                  esrc, edst, curU, pairsU, NBU, E, pblocks);
    k_bucketFill<<<NBP + NBU, 256, 0, stream>>>(pairsP, basesP, NBP, nbr_p, deg_p, ptr_p, NP,
                                                pairsU, basesU, NBU, nbr_u, deg_u, ptr_u, NU);

    // bfB = bf16(x_product @ W1rl): persistent ctile, EMIT-only (static LDS 48.5 KB)
    {
        const int tiles = (NP + 31) / 32;
        k_ctile<128, 32, false, true, false, false, false><<<(tiles < 768 ? tiles : 768), 256, 0, stream>>>(
            nullptr, nullptr, x_product, W1rl, nullptr, bfB, NP);
    }

    const int tP64 = (NP + 63) / 64, tP32 = (NP + 31) / 32;
    const int tU64 = (NU + 63) / 64;
    auto cap = [](int t, int c) { return t < c ? t : c; };
    const int gP = cap(tP64, 512), gU = cap(tU64, 512);

    // ---- layer 1: fused dual gather, then combines ----
    k_gather2<<<(NP + NU + 3) / 4, 256, 0, stream>>>(bfA, nbr_p, ptr_p, deg_p, aggP, NP,
                                                     bfB, nbr_u, ptr_u, deg_u, aggU, NU);
    // dual: h_p(part) = aggP@W1bl + b1b  ||  h_u = relu(aggU + b1r + x_user@W1rr), emit bfA
    k_ctileDual64<<<gP + gU, 256, 0, stream>>>(
        nullptr, b1b, aggP, W1bl, h_p, nullptr, NP, FBIAS, gP,
        aggU, b1r, x_user, W1rr, h_u, bfA, NU, FPRE | FBIAS | FRELU | FEMIT);
    // h_p = relu(h_p + x_product@W1br), emit bfB
    k_ctile<128, 32, true, true, true, false, true><<<cap(tP32, 768), 256, 0, stream>>>(
        h_p, nullptr, x_product, W1br, h_p, bfB, NP);

    // ---- layer 2: fused dual gather, then dual combines (2 dispatches) ----
    k_gather2<<<(NP + NU + 3) / 4, 256, 0, stream>>>(bfA, nbr_p, ptr_p, deg_p, aggP, NP,
                                                     bfB, nbr_u, ptr_u, deg_u, aggU, NU);
    // pass 1: aggP = aggP@W2bl + b2b  ||  aggU = aggU@W2rl + b2r
    k_ctileDual64<<<gP + gU, 256, 0, stream>>>(
        nullptr, b2b, aggP, W2bl, aggP, nullptr, NP, FBIAS, gP,
        nullptr, b2r, aggU, W2rl, aggU, nullptr, NU, FBIAS);
    // pass 2: h_p = aggP + h_p@W2br  ||  h_u = aggU + h_u@W2rr
    k_ctileDual64<<<gP + gU, 256, 0, stream>>>(
        aggP, nullptr, h_p, W2br, h_p, nullptr, NP, FPRE, gP,
        aggU, nullptr, h_u, W2rr, h_u, nullptr, NU, FPRE);

    // ---- classifier ----
    k_classify4<<<((EL + 3) / 4 + 3) / 4, 256, 0, stream>>>(h_u, h_p, lu, lp, (float*)d_out, EL);
}

// Round 4
// 519.277 us; speedup vs baseline: 1.2385x; 1.2385x over previous
//
#include <hip/hip_runtime.h>

// 2-layer hetero GraphSAGE, fp32 compute, bf16 gather tables, bucketed CSR build,
// persistent-weight register-tiled combines.
// HARD RULES (accumulated post-mortems):
//  R6/R7: one K-loop (one weight matrix) per tile kernel — dual-weight loops
//    spill to 256 VGPR + scratch. Fusion via PRE operand or block-range select.
//  R8: split gathers lower FETCH but not time (latency-bound) — keep fused dual gather.
//  R9 (VERIFIED 74.4us): gather = one coalesced offset-vector load + __shfl
//    distribution + 8-deep burst of row loads with per-lane masks + ZERO-INIT.
//    The zero-inits are LOAD-LIVENESS ANCHORS (force v0..v7 live together).
//  R10: removing the anchors lets the compiler interleave load->acc and
//    serialize the burst (74.4 -> 79.6). Gather is memory-request-service
//    bound at ~74us; VALU dieting doesn't move it.
//  R11 (REVERTED): RUNTIME epilogue flags in the combine kernel -> VGPR 248,
//    occupancy 10%, 79.9us/launch (3x regression). Combine polymorphism must
//    be COMPILE-TIME (template), never runtime flags. Block-range fusion of
//    identical bodies (k_partition2, k_histCast) is safe — kept.

using u16 = unsigned short;
using u32 = unsigned int;

__device__ __forceinline__ u16 bf16r(float f) {            // round-to-nearest-even
    u32 b = __float_as_uint(f);
    b += 0x7fffu + ((b >> 16) & 1u);
    return (u16)(b >> 16);
}
__device__ __forceinline__ float bflo(u32 u) { return __uint_as_float(u << 16); }
__device__ __forceinline__ float bfhi(u32 u) { return __uint_as_float(u & 0xffff0000u); }

#define BSH 8          // bucket = key >> BSH, 256 node ids per bucket
#define MAXB 512       // max buckets per direction (NU=100000 -> 391)
#define CHUNK 4096     // edges per partition block
#define RPT 16         // CHUNK / 256
#define HB 512         // histogram blocks in fused hist+cast kernel

// ---- pass A (fused): blocks [0,HB) coarse bucket histograms both directions;
// ---- blocks [HB,..) cast x_user -> bf16 shadow (independent work) ----
__global__ __launch_bounds__(256) void k_histCast(const int* __restrict__ esrc,
                                                  const int* __restrict__ edst,
                                                  int* __restrict__ bcntP,
                                                  int* __restrict__ bcntU,
                                                  int NBP, int NBU, int E,
                                                  const float* __restrict__ xc,
                                                  u16* __restrict__ yc, int n8) {
    __shared__ int hP[MAXB];
    __shared__ int hU[MAXB];
    int tid = threadIdx.x;
    if ((int)blockIdx.x >= HB) {
        int i = (blockIdx.x - HB) * 256 + tid;
        if (i < n8) {
            const float4* x4 = (const float4*)xc;
            float4 a = x4[i * 2], b = x4[i * 2 + 1];
            uint4 o;
            o.x = (u32)bf16r(a.x) | ((u32)bf16r(a.y) << 16);
            o.y = (u32)bf16r(a.z) | ((u32)bf16r(a.w) << 16);
            o.z = (u32)bf16r(b.x) | ((u32)bf16r(b.y) << 16);
            o.w = (u32)bf16r(b.z) | ((u32)bf16r(b.w) << 16);
            ((uint4*)yc)[i] = o;
        }
        return;
    }
    for (int i = tid; i < MAXB; i += 256) { hP[i] = 0; hU[i] = 0; }
    __syncthreads();
    int E4 = E >> 2;
    const int4* s4 = (const int4*)esrc;
    const int4* d4 = (const int4*)edst;
    int stride = HB * 256;
    for (int i = blockIdx.x * 256 + tid; i < E4; i += stride) {
        int4 s = s4[i], d = d4[i];
        atomicAdd(&hU[s.x >> BSH], 1); atomicAdd(&hU[s.y >> BSH], 1);
        atomicAdd(&hU[s.z >> BSH], 1); atomicAdd(&hU[s.w >> BSH], 1);
        atomicAdd(&hP[d.x >> BSH], 1); atomicAdd(&hP[d.y >> BSH], 1);
        atomicAdd(&hP[d.z >> BSH], 1); atomicAdd(&hP[d.w >> BSH], 1);
    }
    if (blockIdx.x == 0 && tid < (E & 3)) {
        int e = E4 * 4 + tid;
        atomicAdd(&hU[esrc[e] >> BSH], 1);
        atomicAdd(&hP[edst[e] >> BSH], 1);
    }
    __syncthreads();
    for (int i = tid; i < NBP; i += 256) if (hP[i]) atomicAdd(&bcntP[i], hP[i]);
    for (int i = tid; i < NBU; i += 256) if (hU[i]) atomicAdd(&bcntU[i], hU[i]);
}

// ---- scan bucket counts -> bases[NB+1] and working cursor[NB]; block 0 = P, 1 = U ----
__global__ __launch_bounds__(256) void k_scanBuckets(const int* __restrict__ cntP,
                                                     int* __restrict__ basesP,
                                                     int* __restrict__ curP, int NBP,
                                                     const int* __restrict__ cntU,
                                                     int* __restrict__ basesU,
                                                     int* __restrict__ curU, int NBU) {
    const int* cnt; int* bases; int* cur; int NB;
    if (blockIdx.x == 0) { cnt = cntP; bases = basesP; cur = curP; NB = NBP; }
    else                 { cnt = cntU; bases = basesU; cur = curU; NB = NBU; }
    __shared__ int sA[MAXB];
    __shared__ int sB[MAXB];
    int tid = threadIdx.x;
    int v0 = (tid < NB) ? cnt[tid] : 0;
    int v1 = (tid + 256 < NB) ? cnt[tid + 256] : 0;
    sA[tid] = v0; sA[tid + 256] = v1;
    __syncthreads();
    int* src = sA; int* dst = sB;
    for (int off = 1; off < MAXB; off <<= 1) {
        dst[tid] = src[tid] + ((tid >= off) ? src[tid - off] : 0);
        int i2 = tid + 256;
        dst[i2] = src[i2] + ((i2 >= off) ? src[i2 - off] : 0);
        __syncthreads();
        int* t = src; src = dst; dst = t;
    }
    if (tid < NB)       { bases[tid] = src[tid] - v0;             cur[tid] = src[tid] - v0; }
    if (tid + 256 < NB) { bases[tid + 256] = src[tid + 256] - v1; cur[tid + 256] = src[tid + 256] - v1; }
    if (tid == 0) bases[NB] = src[MAXB - 1];
}

// ---- pass B (fused both directions): partition edges into bucket-ordered
// (key,payload) pairs, coalesced flush. blocks [0,pblocks) = P, rest = U ----
__global__ __launch_bounds__(256) void k_partition2(
    const int* __restrict__ keysP, const int* __restrict__ payP,
    int* __restrict__ curPp, uint2* __restrict__ pairsP, int NBP,
    const int* __restrict__ keysU, const int* __restrict__ payU,
    int* __restrict__ curUp, uint2* __restrict__ pairsU, int NBU,
    int E, int pblocks) {
    __shared__ int hist[MAXB];
    __shared__ int sA[MAXB];
    __shared__ int sB[MAXB];
    __shared__ int bx[MAXB];
    __shared__ int gbase[MAXB];
    __shared__ uint2 prs[CHUNK];
    const int* keys; const int* payload; int* cursor; uint2* pairs; int NB, cb;
    if ((int)blockIdx.x < pblocks) {
        keys = keysP; payload = payP; cursor = curPp; pairs = pairsP; NB = NBP;
        cb = blockIdx.x;
    } else {
        keys = keysU; payload = payU; cursor = curUp; pairs = pairsU; NB = NBU;
        cb = blockIdx.x - pblocks;
    }
    int tid = threadIdx.x;
    int i0 = cb * CHUNK;
    int count = min(CHUNK, E - i0);
    for (int i = tid; i < MAXB; i += 256) hist[i] = 0;
    __syncthreads();
    int keyr[RPT], payr[RPT], rankr[RPT];
#pragma unroll
    for (int r = 0; r < RPT; ++r) {
        int idx = r * 256 + tid;
        if (idx < count) {
            int k = keys[i0 + idx];
            keyr[r] = k;
            payr[r] = payload[i0 + idx];
            rankr[r] = atomicAdd(&hist[k >> BSH], 1);
        } else keyr[r] = -1;
    }
    __syncthreads();
    // exclusive scan of hist -> bx (ping-pong, 512 wide)
    sA[tid] = hist[tid]; sA[tid + 256] = hist[tid + 256];
    __syncthreads();
    int* src = sA; int* dst = sB;
    for (int off = 1; off < MAXB; off <<= 1) {
        dst[tid] = src[tid] + ((tid >= off) ? src[tid - off] : 0);
        int i2 = tid + 256;
        dst[i2] = src[i2] + ((i2 >= off) ? src[i2 - off] : 0);
        __syncthreads();
        int* t = src; src = dst; dst = t;
    }
    bx[tid] = src[tid] - hist[tid];
    bx[tid + 256] = src[tid + 256] - hist[tid + 256];
    __syncthreads();
    for (int b = tid; b < NB; b += 256) {
        int c = hist[b];
        gbase[b] = c ? atomicAdd(&cursor[b], c) : 0;
    }
    // stage into LDS in bucket order
#pragma unroll
    for (int r = 0; r < RPT; ++r) {
        if (keyr[r] >= 0)
            prs[bx[keyr[r] >> BSH] + rankr[r]] = make_uint2((u32)keyr[r], (u32)payr[r]);
    }
    __syncthreads();
    // coalesced segment copy-out
    for (int j = tid; j < count; j += 256) {
        uint2 pr = prs[j];
        int b = pr.x >> BSH;
        pairs[gbase[b] + (j - bx[b])] = pr;
    }
}

// ---- pass C: per-bucket fine fill -> nbr, deg, ptr(start); both directions fused ----
// nbr stores BYTE offsets into the 128B-row bf16 tables (id << 7).
__global__ __launch_bounds__(256) void k_bucketFill(
    const uint2* __restrict__ pairsP, const int* __restrict__ basesP, int NBP,
    int* __restrict__ nbr_p, int* __restrict__ deg_p, int* __restrict__ ptr_p, int NP,
    const uint2* __restrict__ pairsU, const int* __restrict__ basesU, int NBU,
    int* __restrict__ nbr_u, int* __restrict__ deg_u, int* __restrict__ ptr_u, int NU) {
    const uint2* pairs; const int* bases; int* nbr; int* deg; int* ptr; int N; int bucket;
    if ((int)blockIdx.x < NBP) {
        pairs = pairsP; bases = basesP; nbr = nbr_p; deg = deg_p; ptr = ptr_p; N = NP;
        bucket = blockIdx.x;
    } else {
        pairs = pairsU; bases = basesU; nbr = nbr_u; deg = deg_u; ptr = ptr_u; N = NU;
        bucket = blockIdx.x - NBP;
    }
    int tid = threadIdx.x;
    int base = bases[bucket];
    int cnt = bases[bucket + 1] - base;
    __shared__ int h[256];
    __shared__ int s[256];
    __shared__ int cur[256];
    h[tid] = 0;
    __syncthreads();
    for (int j = tid; j < cnt; j += 256) atomicAdd(&h[pairs[base + j].x & 255], 1);
    __syncthreads();
    int d = h[tid];
    s[tid] = d;
    __syncthreads();
    for (int off = 1; off < 256; off <<= 1) {
        int v = (tid >= off) ? s[tid - off] : 0;
        __syncthreads();
        s[tid] += v;
        __syncthreads();
    }
    int excl = s[tid] - d;
    int node = bucket * 256 + tid;
    if (node < N) { deg[node] = d; ptr[node] = base + excl; }
    cur[tid] = excl;
    __syncthreads();
    for (int j = tid; j < cnt; j += 256) {
        uint2 pr = pairs[base + j];
        int pos = atomicAdd(&cur[pr.x & 255], 1);
        nbr[base + pos] = (int)(pr.y << 7);     // byte offset of row (128B rows)
    }
}

#define ACC8(A0,A1,A2,A3,A4,A5,A6,A7,V) \
    A0 += bflo((V).x); A1 += bfhi((V).x); A2 += bflo((V).y); A3 += bfhi((V).y); \
    A4 += bflo((V).z); A5 += bfhi((V).z); A6 += bflo((V).w); A7 += bfhi((V).w);

// ------- fused dual gather-mean: nodes [0,NA) CSR A, [NA,NA+NB) CSR B -------
// wave per node; 8 lanes per bf16 row (uint4). R9 shape — do not restructure.
__global__ __launch_bounds__(256) void k_gather2(
    const u16* __restrict__ yA, const int* __restrict__ nbrA, const int* __restrict__ stpA,
    const int* __restrict__ degA, float* __restrict__ aggA, int NA,
    const u16* __restrict__ yB, const int* __restrict__ nbrB, const int* __restrict__ stpB,
    const int* __restrict__ degB, float* __restrict__ aggB, int NB) {
    int w = (blockIdx.x * 256 + threadIdx.x) >> 6;
    int lane = threadIdx.x & 63;
    if (w >= NA + NB) return;
    const u16* y; const int* nbr; const int* stp; const int* deg; float* agg; int n;
    if (w < NA) { y = yA; nbr = nbrA; stp = stpA; deg = degA; agg = aggA; n = w; }
    else        { y = yB; nbr = nbrB; stp = stpB; deg = degB; agg = aggB; n = w - NA; }
    const int q = lane >> 3, t = lane & 7;
    const int d = deg[n];
    const int st = stp[n];
    const char* yb = (const char*)y + t * 16;
    float a0=0,a1=0,a2=0,a3=0,a4=0,a5=0,a6=0,a7=0;
    for (int j = 0; j < d; j += 64) {
        const int cnt = min(d - j, 64);           // wave-uniform
        int offv = 0;
        if (lane < cnt) offv = nbr[st + j + lane];   // one coalesced 256B load
        // distribute + burst-issue all row loads (independent, exec-masked tails)
#define GLD(R) \
        int g##R = __shfl(offv, R * 8 + q, 64); \
        uint4 v##R = make_uint4(0u, 0u, 0u, 0u); \
        if (R * 8 + q < cnt) v##R = *(const uint4*)(yb + g##R);
        GLD(0) GLD(1) GLD(2) GLD(3) GLD(4) GLD(5) GLD(6) GLD(7)
#undef GLD
        // accumulate (rounds beyond cnt are uniform-skipped; masked lanes hold 0)
#define ACCR(R) if (R * 8 < cnt) { ACC8(a0,a1,a2,a3,a4,a5,a6,a7,v##R) }
        ACCR(0) ACCR(1) ACCR(2) ACCR(3) ACCR(4) ACCR(5) ACCR(6) ACCR(7)
#undef ACCR
    }
#pragma unroll
    for (int m = 8; m < 64; m <<= 1) {
        a0 += __shfl_xor(a0, m, 64); a1 += __shfl_xor(a1, m, 64);
        a2 += __shfl_xor(a2, m, 64); a3 += __shfl_xor(a3, m, 64);
        a4 += __shfl_xor(a4, m, 64); a5 += __shfl_xor(a5, m, 64);
        a6 += __shfl_xor(a6, m, 64); a7 += __shfl_xor(a7, m, 64);
    }
    if (q == 0) {
        float dinv = 1.0f / (float)max(d, 1);
        float* dstp = agg + n * 64 + t * 8;
        *(float4*)dstp       = make_float4(a0 * dinv, a1 * dinv, a2 * dinv, a3 * dinv);
        *(float4*)(dstp + 4) = make_float4(a4 * dinv, a5 * dinv, a6 * dinv, a7 * dinv);
    }
}

// ======= persistent-weight register-tiled combine, single input (STATIC LDS) =======
// h = act( (PRE?pre:0) + (BIAS?b:0) + x@W );  STORE=0 -> only bf16 emit
// All behavior flags are COMPILE-TIME (R11 hard rule).
#define FMA_ROW(ACC, O, W4) \
    ACC[0] += (O) * (W4).x; ACC[1] += (O) * (W4).y; \
    ACC[2] += (O) * (W4).z; ACC[3] += (O) * (W4).w;

template <int K, int ROWS, bool RELU, bool EMIT, bool PRE, bool BIAS, bool STORE>
__global__ __launch_bounds__(256) void k_ctile(const float* __restrict__ pre,
                                               const float* __restrict__ bias,
                                               const float* __restrict__ x,
                                               const float* __restrict__ W,
                                               float* __restrict__ h,
                                               u16* __restrict__ hbf, int N) {
    constexpr int RR = ROWS / 16;
    constexpr int STRIDE = K + 4;
    constexpr int KF4 = K / 4;
    __shared__ float Ws[K * 64];
    __shared__ float op[ROWS * STRIDE];
    const int tid = threadIdx.x;
    for (int i = tid; i < K * 16; i += 256)
        ((float4*)Ws)[i] = ((const float4*)W)[i];
    const int c4 = (tid & 15) * 4;
    const int rb = (tid >> 4) * RR;
    float bx_ = 0.f, by_ = 0.f, bz_ = 0.f, bw_ = 0.f;
    if (BIAS) {
        float4 b4 = *(const float4*)(bias + c4);
        bx_ = b4.x; by_ = b4.y; bz_ = b4.z; bw_ = b4.w;
    }
    const int ntiles = (N + ROWS - 1) / ROWS;
    for (int tile = blockIdx.x; tile < ntiles; tile += gridDim.x) {
        const int row0 = tile * ROWS;
        __syncthreads();
        for (int i = tid; i < ROWS * KF4; i += 256) {
            int r = i / KF4, k4 = (i % KF4) * 4;
            int row = row0 + r;
            float4 v = make_float4(0.f, 0.f, 0.f, 0.f);
            if (row < N) v = *(const float4*)(x + (size_t)row * K + k4);
            *(float4*)(op + r * STRIDE + k4) = v;
        }
        __syncthreads();
        float acc[RR][4];
#pragma unroll
        for (int i = 0; i < RR; ++i) {
            float px = 0.f, py = 0.f, pz = 0.f, pw = 0.f;
            if (PRE) {
                int row = row0 + rb + i;
                if (row < N) {
                    float4 p = *(const float4*)(pre + row * 64 + c4);
                    px = p.x; py = p.y; pz = p.z; pw = p.w;
                }
            }
            acc[i][0] = bx_ + px; acc[i][1] = by_ + py;
            acc[i][2] = bz_ + pz; acc[i][3] = bw_ + pw;
        }
        for (int kk = 0; kk < K; kk += 4) {
            float4 w0 = *(const float4*)(Ws + (kk + 0) * 64 + c4);
            float4 w1 = *(const float4*)(Ws + (kk + 1) * 64 + c4);
            float4 w2 = *(const float4*)(Ws + (kk + 2) * 64 + c4);
            float4 w3 = *(const float4*)(Ws + (kk + 3) * 64 + c4);
#pragma unroll
            for (int i = 0; i < RR; ++i) {
                float4 o = *(const float4*)(op + (rb + i) * STRIDE + kk);
                FMA_ROW(acc[i], o.x, w0);
                FMA_ROW(acc[i], o.y, w1);
                FMA_ROW(acc[i], o.z, w2);
                FMA_ROW(acc[i], o.w, w3);
            }
        }
#pragma unroll
        for (int i = 0; i < RR; ++i) {
            int row = row0 + rb + i;
            if (row >= N) continue;
            float v0 = acc[i][0], v1 = acc[i][1], v2 = acc[i][2], v3 = acc[i][3];
            if (RELU) {
                v0 = fmaxf(v0, 0.f); v1 = fmaxf(v1, 0.f);
                v2 = fmaxf(v2, 0.f); v3 = fmaxf(v3, 0.f);
            }
            if (STORE)
                *(float4*)(h + row * 64 + c4) = make_float4(v0, v1, v2, v3);
            if (EMIT) {
                uint2 o;
                o.x = (u32)bf16r(v0) | ((u32)bf16r(v1) << 16);
                o.y = (u32)bf16r(v2) | ((u32)bf16r(v3) << 16);
                *(uint2*)(hbf + row * 64 + c4) = o;
            }
        }
    }
}

// ======= paired combine: two independent K=64 problems, block-range selected =======
// COMPILE-TIME flags, identical for both sides (R11 rule). Single K-loop body.
// h = (PRE?pre:0) + (BIAS?b:0) + x@W.
template <bool PRE, bool BIAS>
__global__ __launch_bounds__(256) void k_ctilePair64(
    const float* __restrict__ pre0, const float* __restrict__ bias0,
    const float* __restrict__ x0, const float* __restrict__ W0,
    float* __restrict__ h0, int N0, int g0,
    const float* __restrict__ pre1, const float* __restrict__ bias1,
    const float* __restrict__ x1, const float* __restrict__ W1,
    float* __restrict__ h1, int N1) {
    constexpr int ROWS = 64, RR = 4, STRIDE = 68, KF4 = 16;
    __shared__ float Ws[64 * 64];
    __shared__ float op[ROWS * STRIDE];
    const float* pre; const float* bias; const float* x; const float* W; float* h;
    int N, bid, gsz;
    if ((int)blockIdx.x < g0) {
        pre = pre0; bias = bias0; x = x0; W = W0; h = h0; N = N0;
        bid = blockIdx.x; gsz = g0;
    } else {
        pre = pre1; bias = bias1; x = x1; W = W1; h = h1; N = N1;
        bid = blockIdx.x - g0; gsz = gridDim.x - g0;
    }
    const int tid = threadIdx.x;
    for (int i = tid; i < 64 * 16; i += 256)
        ((float4*)Ws)[i] = ((const float4*)W)[i];
    const int c4 = (tid & 15) * 4;
    const int rb = (tid >> 4) * RR;
    float bx_ = 0.f, by_ = 0.f, bz_ = 0.f, bw_ = 0.f;
    if (BIAS) {
        float4 b4 = *(const float4*)(bias + c4);
        bx_ = b4.x; by_ = b4.y; bz_ = b4.z; bw_ = b4.w;
    }
    const int ntiles = (N + ROWS - 1) / ROWS;
    for (int tile = bid; tile < ntiles; tile += gsz) {
        const int row0 = tile * ROWS;
        __syncthreads();
        for (int i = tid; i < ROWS * KF4; i += 256) {
            int r = i / KF4, k4 = (i % KF4) * 4;
            int row = row0 + r;
            float4 v = make_float4(0.f, 0.f, 0.f, 0.f);
            if (row < N) v = *(const float4*)(x + (size_t)row * 64 + k4);
            *(float4*)(op + r * STRIDE + k4) = v;
        }
        __syncthreads();
        float acc[RR][4];
#pragma unroll
        for (int i = 0; i < RR; ++i) {
            float px = 0.f, py = 0.f, pz = 0.f, pw = 0.f;
            if (PRE) {
                int row = row0 + rb + i;
                if (row < N) {
                    float4 p = *(const float4*)(pre + row * 64 + c4);
                    px = p.x; py = p.y; pz = p.z; pw = p.w;
                }
            }
            acc[i][0] = bx_ + px; acc[i][1] = by_ + py;
            acc[i][2] = bz_ + pz; acc[i][3] = bw_ + pw;
        }
        for (int kk = 0; kk < 64; kk += 4) {
            float4 w0 = *(const float4*)(Ws + (kk + 0) * 64 + c4);
            float4 w1 = *(const float4*)(Ws + (kk + 1) * 64 + c4);
            float4 w2 = *(const float4*)(Ws + (kk + 2) * 64 + c4);
            float4 w3 = *(const float4*)(Ws + (kk + 3) * 64 + c4);
#pragma unroll
            for (int i = 0; i < RR; ++i) {
                float4 o = *(const float4*)(op + (rb + i) * STRIDE + kk);
                FMA_ROW(acc[i], o.x, w0);
                FMA_ROW(acc[i], o.y, w1);
                FMA_ROW(acc[i], o.z, w2);
                FMA_ROW(acc[i], o.w, w3);
            }
        }
#pragma unroll
        for (int i = 0; i < RR; ++i) {
            int row = row0 + rb + i;
            if (row >= N) continue;
            *(float4*)(h + row * 64 + c4) =
                make_float4(acc[i][0], acc[i][1], acc[i][2], acc[i][3]);
        }
    }
}

// ------- out[e] = dot64(hu[lu[e]], hp[lp[e]]); quarter-wave per edge, float4 -------
__global__ __launch_bounds__(256) void k_classify4(const float* __restrict__ hu,
                                                   const float* __restrict__ hp,
                                                   const int* __restrict__ lu,
                                                   const int* __restrict__ lp,
                                                   float* __restrict__ out, int EL) {
    int w = (blockIdx.x * 256 + threadIdx.x) >> 6;
    int lane = threadIdx.x & 63;
    int q = lane >> 4, t = lane & 15;
    int e = w * 4 + q;
    float v = 0.f;
    if (e < EL) {
        int u = lu[e], p = lp[e];
        float4 a = *(const float4*)(hu + u * 64 + t * 4);
        float4 b = *(const float4*)(hp + p * 64 + t * 4);
        v = a.x * b.x + a.y * b.y + a.z * b.z + a.w * b.w;
    }
#pragma unroll
    for (int m = 1; m < 16; m <<= 1) v += __shfl_xor(v, m, 64);
    if (t == 0 && e < EL) out[e] = v;
}

extern "C" void kernel_launch(void* const* d_in, const int* in_sizes, int n_in,
                              void* d_out, int out_size, void* d_ws, size_t ws_size,
                              hipStream_t stream) {
    const float* x_user    = (const float*)d_in[0];
    const float* x_product = (const float*)d_in[1];
    const float* W1bl = (const float*)d_in[2];
    const float* b1b  = (const float*)d_in[3];
    const float* W1br = (const float*)d_in[4];
    const float* W1rl = (const float*)d_in[5];
    const float* b1r  = (const float*)d_in[6];
    const float* W1rr = (const float*)d_in[7];
    const float* W2bl = (const float*)d_in[8];
    const float* b2b  = (const float*)d_in[9];
    const float* W2br = (const float*)d_in[10];
    const float* W2rl = (const float*)d_in[11];
    const float* b2r  = (const float*)d_in[12];
    const float* W2rr = (const float*)d_in[13];
    const int* esrc = (const int*)d_in[14];
    const int* edst = (const int*)d_in[15];
    const int* lu   = (const int*)d_in[16];
    const int* lp   = (const int*)d_in[17];

    const int NU = in_sizes[0] / 64;
    const int NP = in_sizes[1] / 128;
    const int E  = in_sizes[14];
    const int EL = in_sizes[16];
    const int NBP = (NP + 255) >> BSH;
    const int NBU = (NU + 255) >> BSH;

    // ---- workspace layout ----
    char* ws = (char*)d_ws;
    size_t off = 0;
    auto alloc = [&](size_t bytes) -> void* {
        void* p = ws + off;
        off += (bytes + 255) & ~(size_t)255;
        return p;
    };
    int*   deg_u  = (int*)alloc((size_t)NU * 4);
    int*   deg_p  = (int*)alloc((size_t)NP * 4);
    int*   ptr_u  = (int*)alloc((size_t)NU * 4);
    int*   ptr_p  = (int*)alloc((size_t)NP * 4);
    int*   bcntP  = (int*)alloc((size_t)MAXB * 4);   // contiguous with bcntU: one memset
    int*   bcntU  = (int*)alloc((size_t)MAXB * 4);
    int*   basesP = (int*)alloc((size_t)(MAXB + 1) * 4);
    int*   basesU = (int*)alloc((size_t)(MAXB + 1) * 4);
    int*   curP   = (int*)alloc((size_t)MAXB * 4);
    int*   curU   = (int*)alloc((size_t)MAXB * 4);
    int*   nbr_u  = (int*)alloc((size_t)E * 4);
    int*   nbr_p  = (int*)alloc((size_t)E * 4);
    // union region: pairs (CSR build) then agg (gather onward)
    size_t aggBytes = (size_t)(NP + NU) * 64 * 4;
    size_t pairBytes = (size_t)E * 8 * 2;
    char* uni = (char*)alloc(aggBytes > pairBytes ? aggBytes : pairBytes);
    float* aggP   = (float*)uni;
    float* aggU   = (float*)(uni + (size_t)NP * 64 * 4);
    uint2* pairsP = (uint2*)uni;
    uint2* pairsU = (uint2*)(uni + (size_t)E * 8);
    u16*   bfA    = (u16*)alloc((size_t)NU * 64 * 2);  // x_user_bf, then h_u_bf
    u16*   bfB    = (u16*)alloc((size_t)NP * 64 * 2);  // y_p1_bf,  then h_p_bf
    float* h_p    = (float*)alloc((size_t)NP * 64 * 4);
    float* h_u    = (float*)alloc((size_t)NU * 64 * 4);

    // ---- CSR build: bucketed counting sort, both directions ----
    hipMemsetAsync(bcntP, 0, (size_t)MAXB * 2 * 4, stream);  // bcntP+bcntU contiguous
    const int n8 = NU * 64 / 8;
    const int castBlocks = (n8 + 255) / 256;
    k_histCast<<<HB + castBlocks, 256, 0, stream>>>(esrc, edst, bcntP, bcntU, NBP, NBU, E,
                                                    x_user, bfA, n8);
    k_scanBuckets<<<2, 256, 0, stream>>>(bcntP, basesP, curP, NBP, bcntU, basesU, curU, NBU);
    const int pblocks = (E + CHUNK - 1) / CHUNK;
    k_partition2<<<2 * pblocks, 256, 0, stream>>>(edst, esrc, curP, pairsP, NBP,
                                                  esrc, edst, curU, pairsU, NBU, E, pblocks);
    k_bucketFill<<<NBP + NBU, 256, 0, stream>>>(pairsP, basesP, NBP, nbr_p, deg_p, ptr_p, NP,
                                                pairsU, basesU, NBU, nbr_u, deg_u, ptr_u, NU);

    // bfB = bf16(x_product @ W1rl): persistent ctile, EMIT-only (static LDS 48.5 KB)
    {
        const int tiles = (NP + 31) / 32;
        k_ctile<128, 32, false, true, false, false, false><<<(tiles < 768 ? tiles : 768), 256, 0, stream>>>(
            nullptr, nullptr, x_product, W1rl, nullptr, bfB, NP);
    }

    const int tP64 = (NP + 63) / 64, tP32 = (NP + 31) / 32;
    const int tU64 = (NU + 63) / 64;
    auto cap = [](int t, int c) { return t < c ? t : c; };
    const int gP = cap(tP64, 512), gU = cap(tU64, 512);

    // ---- layer 1: fused dual gather, then combines (R1-proven shapes) ----
    k_gather2<<<(NP + NU + 3) / 4, 256, 0, stream>>>(bfA, nbr_p, ptr_p, deg_p, aggP, NP,
                                                     bfB, nbr_u, ptr_u, deg_u, aggU, NU);
    // h_p = relu(aggP@W1bl + b1b + x_product@W1br): two-pass
    k_ctile<64, 64, false, false, false, true, true><<<cap(tP64, 1024), 256, 0, stream>>>(
        nullptr, b1b, aggP, W1bl, h_p, nullptr, NP);
    k_ctile<128, 32, true, true, true, false, true><<<cap(tP32, 768), 256, 0, stream>>>(
        h_p, nullptr, x_product, W1br, h_p, bfB, NP);
    // h_u = relu(aggU + b1r + x_user@W1rr), emit bfA
    k_ctile<64, 64, true, true, true, true, true><<<cap(tU64, 1024), 256, 0, stream>>>(
        aggU, b1r, x_user, W1rr, h_u, bfA, NU);

    // ---- layer 2: fused dual gather, then paired combines (2 dispatches) ----
    k_gather2<<<(NP + NU + 3) / 4, 256, 0, stream>>>(bfA, nbr_p, ptr_p, deg_p, aggP, NP,
                                                     bfB, nbr_u, ptr_u, deg_u, aggU, NU);
    // pass 1: aggP = aggP@W2bl + b2b  ||  aggU = aggU@W2rl + b2r
    k_ctilePair64<false, true><<<gP + gU, 256, 0, stream>>>(
        nullptr, b2b, aggP, W2bl, aggP, NP, gP,
        nullptr, b2r, aggU, W2rl, aggU, NU);
    // pass 2: h_p = aggP + h_p@W2br  ||  h_u = aggU + h_u@W2rr
    k_ctilePair64<true, false><<<gP + gU, 256, 0, stream>>>(
        aggP, nullptr, h_p, W2br, h_p, NP, gP,
        aggU, nullptr, h_u, W2rr, h_u, NU);

    // ---- classifier ----
    k_classify4<<<((EL + 3) / 4 + 3) / 4, 256, 0, stream>>>(h_u, h_p, lu, lp, (float*)d_out, EL);
}

// Round 5
// 497.629 us; speedup vs baseline: 1.2923x; 1.0435x over previous
//
#include <hip/hip_runtime.h>

// 2-layer hetero GraphSAGE, fp32 compute, bf16 gather tables, bucketed CSR build,
// persistent-weight register-tiled combines.
// HARD RULES (accumulated post-mortems):
//  R6/R7: one K-loop (one weight matrix tile) per kernel body — dual-weight
//    loops spill to 256 VGPR + scratch. Fusion via PRE operand, block-range
//    select, or CONCAT-K (stacked weights in ONE LDS tile, one loop).
//  R8: split gathers lower FETCH but not time (latency-bound) — keep fused dual gather.
//  R9 (VERIFIED 73.9us): gather = one coalesced offset-vector load + __shfl
//    distribution + 8-deep burst of row loads with per-lane masks + ZERO-INIT.
//    The zero-inits are LOAD-LIVENESS ANCHORS (force v0..v7 live together).
//  R10: removing the anchors serializes the burst (74.4 -> 79.6). Gather is
//    memory-request-service bound at ~74us; VALU dieting doesn't move it.
//  R11 (REVERTED): RUNTIME epilogue flags -> VGPR 248, occupancy 10%, 3x
//    regression. Combine polymorphism must be COMPILE-TIME, identical flags
//    on both sides of a block-range pair. Block-range fusion of identical
//    bodies (k_partition2, k_histCast) is safe.
//  R13: (a) layer-2 two-pass -> concat-K=128 single pass ([agg|h] @ [Wl;Wr]),
//    linearity removes a 77MB agg round-trip; (b) x_product@W1br hoisted
//    before the gather so both post-gather layer-1 combines share the same
//    flag set and fuse into one k_ctilePair64X launch.

using u16 = unsigned short;
using u32 = unsigned int;

__device__ __forceinline__ u16 bf16r(float f) {            // round-to-nearest-even
    u32 b = __float_as_uint(f);
    b += 0x7fffu + ((b >> 16) & 1u);
    return (u16)(b >> 16);
}
__device__ __forceinline__ float bflo(u32 u) { return __uint_as_float(u << 16); }
__device__ __forceinline__ float bfhi(u32 u) { return __uint_as_float(u & 0xffff0000u); }

#define BSH 8          // bucket = key >> BSH, 256 node ids per bucket
#define MAXB 512       // max buckets per direction (NU=100000 -> 391)
#define CHUNK 4096     // edges per partition block
#define RPT 16         // CHUNK / 256
#define HB 512         // histogram blocks in fused hist+cast kernel

// ---- pass A (fused): blocks [0,HB) coarse bucket histograms both directions;
// ---- blocks [HB,..) cast x_user -> bf16 shadow (independent work) ----
__global__ __launch_bounds__(256) void k_histCast(const int* __restrict__ esrc,
                                                  const int* __restrict__ edst,
                                                  int* __restrict__ bcntP,
                                                  int* __restrict__ bcntU,
                                                  int NBP, int NBU, int E,
                                                  const float* __restrict__ xc,
                                                  u16* __restrict__ yc, int n8) {
    __shared__ int hP[MAXB];
    __shared__ int hU[MAXB];
    int tid = threadIdx.x;
    if ((int)blockIdx.x >= HB) {
        int i = (blockIdx.x - HB) * 256 + tid;
        if (i < n8) {
            const float4* x4 = (const float4*)xc;
            float4 a = x4[i * 2], b = x4[i * 2 + 1];
            uint4 o;
            o.x = (u32)bf16r(a.x) | ((u32)bf16r(a.y) << 16);
            o.y = (u32)bf16r(a.z) | ((u32)bf16r(a.w) << 16);
            o.z = (u32)bf16r(b.x) | ((u32)bf16r(b.y) << 16);
            o.w = (u32)bf16r(b.z) | ((u32)bf16r(b.w) << 16);
            ((uint4*)yc)[i] = o;
        }
        return;
    }
    for (int i = tid; i < MAXB; i += 256) { hP[i] = 0; hU[i] = 0; }
    __syncthreads();
    int E4 = E >> 2;
    const int4* s4 = (const int4*)esrc;
    const int4* d4 = (const int4*)edst;
    int stride = HB * 256;
    for (int i = blockIdx.x * 256 + tid; i < E4; i += stride) {
        int4 s = s4[i], d = d4[i];
        atomicAdd(&hU[s.x >> BSH], 1); atomicAdd(&hU[s.y >> BSH], 1);
        atomicAdd(&hU[s.z >> BSH], 1); atomicAdd(&hU[s.w >> BSH], 1);
        atomicAdd(&hP[d.x >> BSH], 1); atomicAdd(&hP[d.y >> BSH], 1);
        atomicAdd(&hP[d.z >> BSH], 1); atomicAdd(&hP[d.w >> BSH], 1);
    }
    if (blockIdx.x == 0 && tid < (E & 3)) {
        int e = E4 * 4 + tid;
        atomicAdd(&hU[esrc[e] >> BSH], 1);
        atomicAdd(&hP[edst[e] >> BSH], 1);
    }
    __syncthreads();
    for (int i = tid; i < NBP; i += 256) if (hP[i]) atomicAdd(&bcntP[i], hP[i]);
    for (int i = tid; i < NBU; i += 256) if (hU[i]) atomicAdd(&bcntU[i], hU[i]);
}

// ---- scan bucket counts -> bases[NB+1] and working cursor[NB]; block 0 = P, 1 = U ----
__global__ __launch_bounds__(256) void k_scanBuckets(const int* __restrict__ cntP,
                                                     int* __restrict__ basesP,
                                                     int* __restrict__ curP, int NBP,
                                                     const int* __restrict__ cntU,
                                                     int* __restrict__ basesU,
                                                     int* __restrict__ curU, int NBU) {
    const int* cnt; int* bases; int* cur; int NB;
    if (blockIdx.x == 0) { cnt = cntP; bases = basesP; cur = curP; NB = NBP; }
    else                 { cnt = cntU; bases = basesU; cur = curU; NB = NBU; }
    __shared__ int sA[MAXB];
    __shared__ int sB[MAXB];
    int tid = threadIdx.x;
    int v0 = (tid < NB) ? cnt[tid] : 0;
    int v1 = (tid + 256 < NB) ? cnt[tid + 256] : 0;
    sA[tid] = v0; sA[tid + 256] = v1;
    __syncthreads();
    int* src = sA; int* dst = sB;
    for (int off = 1; off < MAXB; off <<= 1) {
        dst[tid] = src[tid] + ((tid >= off) ? src[tid - off] : 0);
        int i2 = tid + 256;
        dst[i2] = src[i2] + ((i2 >= off) ? src[i2 - off] : 0);
        __syncthreads();
        int* t = src; src = dst; dst = t;
    }
    if (tid < NB)       { bases[tid] = src[tid] - v0;             cur[tid] = src[tid] - v0; }
    if (tid + 256 < NB) { bases[tid + 256] = src[tid + 256] - v1; cur[tid + 256] = src[tid + 256] - v1; }
    if (tid == 0) bases[NB] = src[MAXB - 1];
}

// ---- pass B (fused both directions): partition edges into bucket-ordered
// (key,payload) pairs, coalesced flush. blocks [0,pblocks) = P, rest = U ----
__global__ __launch_bounds__(256) void k_partition2(
    const int* __restrict__ keysP, const int* __restrict__ payP,
    int* __restrict__ curPp, uint2* __restrict__ pairsP, int NBP,
    const int* __restrict__ keysU, const int* __restrict__ payU,
    int* __restrict__ curUp, uint2* __restrict__ pairsU, int NBU,
    int E, int pblocks) {
    __shared__ int hist[MAXB];
    __shared__ int sA[MAXB];
    __shared__ int sB[MAXB];
    __shared__ int bx[MAXB];
    __shared__ int gbase[MAXB];
    __shared__ uint2 prs[CHUNK];
    const int* keys; const int* payload; int* cursor; uint2* pairs; int NB, cb;
    if ((int)blockIdx.x < pblocks) {
        keys = keysP; payload = payP; cursor = curPp; pairs = pairsP; NB = NBP;
        cb = blockIdx.x;
    } else {
        keys = keysU; payload = payU; cursor = curUp; pairs = pairsU; NB = NBU;
        cb = blockIdx.x - pblocks;
    }
    int tid = threadIdx.x;
    int i0 = cb * CHUNK;
    int count = min(CHUNK, E - i0);
    for (int i = tid; i < MAXB; i += 256) hist[i] = 0;
    __syncthreads();
    int keyr[RPT], payr[RPT], rankr[RPT];
#pragma unroll
    for (int r = 0; r < RPT; ++r) {
        int idx = r * 256 + tid;
        if (idx < count) {
            int k = keys[i0 + idx];
            keyr[r] = k;
            payr[r] = payload[i0 + idx];
            rankr[r] = atomicAdd(&hist[k >> BSH], 1);
        } else keyr[r] = -1;
    }
    __syncthreads();
    // exclusive scan of hist -> bx (ping-pong, 512 wide)
    sA[tid] = hist[tid]; sA[tid + 256] = hist[tid + 256];
    __syncthreads();
    int* src = sA; int* dst = sB;
    for (int off = 1; off < MAXB; off <<= 1) {
        dst[tid] = src[tid] + ((tid >= off) ? src[tid - off] : 0);
        int i2 = tid + 256;
        dst[i2] = src[i2] + ((i2 >= off) ? src[i2 - off] : 0);
        __syncthreads();
        int* t = src; src = dst; dst = t;
    }
    bx[tid] = src[tid] - hist[tid];
    bx[tid + 256] = src[tid + 256] - hist[tid + 256];
    __syncthreads();
    for (int b = tid; b < NB; b += 256) {
        int c = hist[b];
        gbase[b] = c ? atomicAdd(&cursor[b], c) : 0;
    }
    // stage into LDS in bucket order
#pragma unroll
    for (int r = 0; r < RPT; ++r) {
        if (keyr[r] >= 0)
            prs[bx[keyr[r] >> BSH] + rankr[r]] = make_uint2((u32)keyr[r], (u32)payr[r]);
    }
    __syncthreads();
    // coalesced segment copy-out
    for (int j = tid; j < count; j += 256) {
        uint2 pr = prs[j];
        int b = pr.x >> BSH;
        pairs[gbase[b] + (j - bx[b])] = pr;
    }
}

// ---- pass C: per-bucket fine fill -> nbr, deg, ptr(start); both directions fused ----
// nbr stores BYTE offsets into the 128B-row bf16 tables (id << 7).
__global__ __launch_bounds__(256) void k_bucketFill(
    const uint2* __restrict__ pairsP, const int* __restrict__ basesP, int NBP,
    int* __restrict__ nbr_p, int* __restrict__ deg_p, int* __restrict__ ptr_p, int NP,
    const uint2* __restrict__ pairsU, const int* __restrict__ basesU, int NBU,
    int* __restrict__ nbr_u, int* __restrict__ deg_u, int* __restrict__ ptr_u, int NU) {
    const uint2* pairs; const int* bases; int* nbr; int* deg; int* ptr; int N; int bucket;
    if ((int)blockIdx.x < NBP) {
        pairs = pairsP; bases = basesP; nbr = nbr_p; deg = deg_p; ptr = ptr_p; N = NP;
        bucket = blockIdx.x;
    } else {
        pairs = pairsU; bases = basesU; nbr = nbr_u; deg = deg_u; ptr = ptr_u; N = NU;
        bucket = blockIdx.x - NBP;
    }
    int tid = threadIdx.x;
    int base = bases[bucket];
    int cnt = bases[bucket + 1] - base;
    __shared__ int h[256];
    __shared__ int s[256];
    __shared__ int cur[256];
    h[tid] = 0;
    __syncthreads();
    for (int j = tid; j < cnt; j += 256) atomicAdd(&h[pairs[base + j].x & 255], 1);
    __syncthreads();
    int d = h[tid];
    s[tid] = d;
    __syncthreads();
    for (int off = 1; off < 256; off <<= 1) {
        int v = (tid >= off) ? s[tid - off] : 0;
        __syncthreads();
        s[tid] += v;
        __syncthreads();
    }
    int excl = s[tid] - d;
    int node = bucket * 256 + tid;
    if (node < N) { deg[node] = d; ptr[node] = base + excl; }
    cur[tid] = excl;
    __syncthreads();
    for (int j = tid; j < cnt; j += 256) {
        uint2 pr = pairs[base + j];
        int pos = atomicAdd(&cur[pr.x & 255], 1);
        nbr[base + pos] = (int)(pr.y << 7);     // byte offset of row (128B rows)
    }
}

#define ACC8(A0,A1,A2,A3,A4,A5,A6,A7,V) \
    A0 += bflo((V).x); A1 += bfhi((V).x); A2 += bflo((V).y); A3 += bfhi((V).y); \
    A4 += bflo((V).z); A5 += bfhi((V).z); A6 += bflo((V).w); A7 += bfhi((V).w);

// ------- fused dual gather-mean: nodes [0,NA) CSR A, [NA,NA+NB) CSR B -------
// wave per node; 8 lanes per bf16 row (uint4). R9 shape — do not restructure.
__global__ __launch_bounds__(256) void k_gather2(
    const u16* __restrict__ yA, const int* __restrict__ nbrA, const int* __restrict__ stpA,
    const int* __restrict__ degA, float* __restrict__ aggA, int NA,
    const u16* __restrict__ yB, const int* __restrict__ nbrB, const int* __restrict__ stpB,
    const int* __restrict__ degB, float* __restrict__ aggB, int NB) {
    int w = (blockIdx.x * 256 + threadIdx.x) >> 6;
    int lane = threadIdx.x & 63;
    if (w >= NA + NB) return;
    const u16* y; const int* nbr; const int* stp; const int* deg; float* agg; int n;
    if (w < NA) { y = yA; nbr = nbrA; stp = stpA; deg = degA; agg = aggA; n = w; }
    else        { y = yB; nbr = nbrB; stp = stpB; deg = degB; agg = aggB; n = w - NA; }
    const int q = lane >> 3, t = lane & 7;
    const int d = deg[n];
    const int st = stp[n];
    const char* yb = (const char*)y + t * 16;
    float a0=0,a1=0,a2=0,a3=0,a4=0,a5=0,a6=0,a7=0;
    for (int j = 0; j < d; j += 64) {
        const int cnt = min(d - j, 64);           // wave-uniform
        int offv = 0;
        if (lane < cnt) offv = nbr[st + j + lane];   // one coalesced 256B load
        // distribute + burst-issue all row loads (independent, exec-masked tails)
#define GLD(R) \
        int g##R = __shfl(offv, R * 8 + q, 64); \
        uint4 v##R = make_uint4(0u, 0u, 0u, 0u); \
        if (R * 8 + q < cnt) v##R = *(const uint4*)(yb + g##R);
        GLD(0) GLD(1) GLD(2) GLD(3) GLD(4) GLD(5) GLD(6) GLD(7)
#undef GLD
        // accumulate (rounds beyond cnt are uniform-skipped; masked lanes hold 0)
#define ACCR(R) if (R * 8 < cnt) { ACC8(a0,a1,a2,a3,a4,a5,a6,a7,v##R) }
        ACCR(0) ACCR(1) ACCR(2) ACCR(3) ACCR(4) ACCR(5) ACCR(6) ACCR(7)
#undef ACCR
    }
#pragma unroll
    for (int m = 8; m < 64; m <<= 1) {
        a0 += __shfl_xor(a0, m, 64); a1 += __shfl_xor(a1, m, 64);
        a2 += __shfl_xor(a2, m, 64); a3 += __shfl_xor(a3, m, 64);
        a4 += __shfl_xor(a4, m, 64); a5 += __shfl_xor(a5, m, 64);
        a6 += __shfl_xor(a6, m, 64); a7 += __shfl_xor(a7, m, 64);
    }
    if (q == 0) {
        float dinv = 1.0f / (float)max(d, 1);
        float* dstp = agg + n * 64 + t * 8;
        *(float4*)dstp       = make_float4(a0 * dinv, a1 * dinv, a2 * dinv, a3 * dinv);
        *(float4*)(dstp + 4) = make_float4(a4 * dinv, a5 * dinv, a6 * dinv, a7 * dinv);
    }
}

// ======= persistent-weight register-tiled combine, single input (STATIC LDS) =======
// h = act( (PRE?pre:0) + (BIAS?b:0) + x@W );  STORE=0 -> only bf16 emit
// All behavior flags are COMPILE-TIME (R11 hard rule).
#define FMA_ROW(ACC, O, W4) \
    ACC[0] += (O) * (W4).x; ACC[1] += (O) * (W4).y; \
    ACC[2] += (O) * (W4).z; ACC[3] += (O) * (W4).w;

template <int K, int ROWS, bool RELU, bool EMIT, bool PRE, bool BIAS, bool STORE>
__global__ __launch_bounds__(256) void k_ctile(const float* __restrict__ pre,
                                               const float* __restrict__ bias,
                                               const float* __restrict__ x,
                                               const float* __restrict__ W,
                                               float* __restrict__ h,
                                               u16* __restrict__ hbf, int N) {
    constexpr int RR = ROWS / 16;
    constexpr int STRIDE = K + 4;
    constexpr int KF4 = K / 4;
    __shared__ float Ws[K * 64];
    __shared__ float op[ROWS * STRIDE];
    const int tid = threadIdx.x;
    for (int i = tid; i < K * 16; i += 256)
        ((float4*)Ws)[i] = ((const float4*)W)[i];
    const int c4 = (tid & 15) * 4;
    const int rb = (tid >> 4) * RR;
    float bx_ = 0.f, by_ = 0.f, bz_ = 0.f, bw_ = 0.f;
    if (BIAS) {
        float4 b4 = *(const float4*)(bias + c4);
        bx_ = b4.x; by_ = b4.y; bz_ = b4.z; bw_ = b4.w;
    }
    const int ntiles = (N + ROWS - 1) / ROWS;
    for (int tile = blockIdx.x; tile < ntiles; tile += gridDim.x) {
        const int row0 = tile * ROWS;
        __syncthreads();
        for (int i = tid; i < ROWS * KF4; i += 256) {
            int r = i / KF4, k4 = (i % KF4) * 4;
            int row = row0 + r;
            float4 v = make_float4(0.f, 0.f, 0.f, 0.f);
            if (row < N) v = *(const float4*)(x + (size_t)row * K + k4);
            *(float4*)(op + r * STRIDE + k4) = v;
        }
        __syncthreads();
        float acc[RR][4];
#pragma unroll
        for (int i = 0; i < RR; ++i) {
            float px = 0.f, py = 0.f, pz = 0.f, pw = 0.f;
            if (PRE) {
                int row = row0 + rb + i;
                if (row < N) {
                    float4 p = *(const float4*)(pre + row * 64 + c4);
                    px = p.x; py = p.y; pz = p.z; pw = p.w;
                }
            }
            acc[i][0] = bx_ + px; acc[i][1] = by_ + py;
            acc[i][2] = bz_ + pz; acc[i][3] = bw_ + pw;
        }
        for (int kk = 0; kk < K; kk += 4) {
            float4 w0 = *(const float4*)(Ws + (kk + 0) * 64 + c4);
            float4 w1 = *(const float4*)(Ws + (kk + 1) * 64 + c4);
            float4 w2 = *(const float4*)(Ws + (kk + 2) * 64 + c4);
            float4 w3 = *(const float4*)(Ws + (kk + 3) * 64 + c4);
#pragma unroll
            for (int i = 0; i < RR; ++i) {
                float4 o = *(const float4*)(op + (rb + i) * STRIDE + kk);
                FMA_ROW(acc[i], o.x, w0);
                FMA_ROW(acc[i], o.y, w1);
                FMA_ROW(acc[i], o.z, w2);
                FMA_ROW(acc[i], o.w, w3);
            }
        }
#pragma unroll
        for (int i = 0; i < RR; ++i) {
            int row = row0 + rb + i;
            if (row >= N) continue;
            float v0 = acc[i][0], v1 = acc[i][1], v2 = acc[i][2], v3 = acc[i][3];
            if (RELU) {
                v0 = fmaxf(v0, 0.f); v1 = fmaxf(v1, 0.f);
                v2 = fmaxf(v2, 0.f); v3 = fmaxf(v3, 0.f);
            }
            if (STORE)
                *(float4*)(h + row * 64 + c4) = make_float4(v0, v1, v2, v3);
            if (EMIT) {
                uint2 o;
                o.x = (u32)bf16r(v0) | ((u32)bf16r(v1) << 16);
                o.y = (u32)bf16r(v2) | ((u32)bf16r(v3) << 16);
                *(uint2*)(hbf + row * 64 + c4) = o;
            }
        }
    }
}

// ======= paired combine: two independent K=64 problems, block-range selected =======
// COMPILE-TIME flags, IDENTICAL for both sides (R11 rule). Single K-loop body.
// h = act((PRE?pre:0) + (BIAS?b:0) + x@W); optional RELU + bf16 EMIT.
template <bool PRE, bool BIAS, bool RELU, bool EMIT>
__global__ __launch_bounds__(256) void k_ctilePair64X(
    const float* __restrict__ pre0, const float* __restrict__ bias0,
    const float* __restrict__ x0, const float* __restrict__ W0,
    float* __restrict__ h0, u16* __restrict__ hbf0, int N0, int g0,
    const float* __restrict__ pre1, const float* __restrict__ bias1,
    const float* __restrict__ x1, const float* __restrict__ W1,
    float* __restrict__ h1, u16* __restrict__ hbf1, int N1) {
    constexpr int ROWS = 64, RR = 4, STRIDE = 68, KF4 = 16;
    __shared__ float Ws[64 * 64];
    __shared__ float op[ROWS * STRIDE];
    const float* pre; const float* bias; const float* x; const float* W;
    float* h; u16* hbf;
    int N, bid, gsz;
    if ((int)blockIdx.x < g0) {
        pre = pre0; bias = bias0; x = x0; W = W0; h = h0; hbf = hbf0; N = N0;
        bid = blockIdx.x; gsz = g0;
    } else {
        pre = pre1; bias = bias1; x = x1; W = W1; h = h1; hbf = hbf1; N = N1;
        bid = blockIdx.x - g0; gsz = gridDim.x - g0;
    }
    const int tid = threadIdx.x;
    for (int i = tid; i < 64 * 16; i += 256)
        ((float4*)Ws)[i] = ((const float4*)W)[i];
    const int c4 = (tid & 15) * 4;
    const int rb = (tid >> 4) * RR;
    float bx_ = 0.f, by_ = 0.f, bz_ = 0.f, bw_ = 0.f;
    if (BIAS) {
        float4 b4 = *(const float4*)(bias + c4);
        bx_ = b4.x; by_ = b4.y; bz_ = b4.z; bw_ = b4.w;
    }
    const int ntiles = (N + ROWS - 1) / ROWS;
    for (int tile = bid; tile < ntiles; tile += gsz) {
        const int row0 = tile * ROWS;
        __syncthreads();
        for (int i = tid; i < ROWS * KF4; i += 256) {
            int r = i / KF4, k4 = (i % KF4) * 4;
            int row = row0 + r;
            float4 v = make_float4(0.f, 0.f, 0.f, 0.f);
            if (row < N) v = *(const float4*)(x + (size_t)row * 64 + k4);
            *(float4*)(op + r * STRIDE + k4) = v;
        }
        __syncthreads();
        float acc[RR][4];
#pragma unroll
        for (int i = 0; i < RR; ++i) {
            float px = 0.f, py = 0.f, pz = 0.f, pw = 0.f;
            if (PRE) {
                int row = row0 + rb + i;
                if (row < N) {
                    float4 p = *(const float4*)(pre + row * 64 + c4);
                    px = p.x; py = p.y; pz = p.z; pw = p.w;
                }
            }
            acc[i][0] = bx_ + px; acc[i][1] = by_ + py;
            acc[i][2] = bz_ + pz; acc[i][3] = bw_ + pw;
        }
        for (int kk = 0; kk < 64; kk += 4) {
            float4 w0 = *(const float4*)(Ws + (kk + 0) * 64 + c4);
            float4 w1 = *(const float4*)(Ws + (kk + 1) * 64 + c4);
            float4 w2 = *(const float4*)(Ws + (kk + 2) * 64 + c4);
            float4 w3 = *(const float4*)(Ws + (kk + 3) * 64 + c4);
#pragma unroll
            for (int i = 0; i < RR; ++i) {
                float4 o = *(const float4*)(op + (rb + i) * STRIDE + kk);
                FMA_ROW(acc[i], o.x, w0);
                FMA_ROW(acc[i], o.y, w1);
                FMA_ROW(acc[i], o.z, w2);
                FMA_ROW(acc[i], o.w, w3);
            }
        }
#pragma unroll
        for (int i = 0; i < RR; ++i) {
            int row = row0 + rb + i;
            if (row >= N) continue;
            float v0 = acc[i][0], v1 = acc[i][1], v2 = acc[i][2], v3 = acc[i][3];
            if (RELU) {
                v0 = fmaxf(v0, 0.f); v1 = fmaxf(v1, 0.f);
                v2 = fmaxf(v2, 0.f); v3 = fmaxf(v3, 0.f);
            }
            *(float4*)(h + row * 64 + c4) = make_float4(v0, v1, v2, v3);
            if (EMIT) {
                uint2 o;
                o.x = (u32)bf16r(v0) | ((u32)bf16r(v1) << 16);
                o.y = (u32)bf16r(v2) | ((u32)bf16r(v3) << 16);
                *(uint2*)(hbf + row * 64 + c4) = o;
            }
        }
    }
}

// ======= paired CONCAT combine: h = bias + [xa|xb] @ [Wa;Wb], K=128 =======
// ONE K-loop, ONE LDS weight tile (filled from two 64x64 sources) — satisfies
// the one-loop hard rule. Geometry mirrors proven k_ctile<128,32> (48.9KB LDS).
// Two independent problems block-range selected, identical compile-time shape.
template <bool BIAS>
__global__ __launch_bounds__(256) void k_ctilePairCat(
    const float* __restrict__ bias0, const float* __restrict__ xa0,
    const float* __restrict__ xb0, const float* __restrict__ Wa0,
    const float* __restrict__ Wb0, float* __restrict__ h0, int N0, int g0,
    const float* __restrict__ bias1, const float* __restrict__ xa1,
    const float* __restrict__ xb1, const float* __restrict__ Wa1,
    const float* __restrict__ Wb1, float* __restrict__ h1, int N1) {
    constexpr int ROWS = 32, RR = 2, STRIDE = 132, KF4 = 32;
    __shared__ float Ws[128 * 64];
    __shared__ float op[ROWS * STRIDE];
    const float* bias; const float* xa; const float* xb;
    const float* Wa; const float* Wb; float* h;
    int N, bid, gsz;
    if ((int)blockIdx.x < g0) {
        bias = bias0; xa = xa0; xb = xb0; Wa = Wa0; Wb = Wb0; h = h0; N = N0;
        bid = blockIdx.x; gsz = g0;
    } else {
        bias = bias1; xa = xa1; xb = xb1; Wa = Wa1; Wb = Wb1; h = h1; N = N1;
        bid = blockIdx.x - g0; gsz = gridDim.x - g0;
    }
    const int tid = threadIdx.x;
    // Ws rows [0,64) = Wa, rows [64,128) = Wb  (1024 float4 each)
    for (int i = tid; i < 64 * 16; i += 256) {
        ((float4*)Ws)[i]           = ((const float4*)Wa)[i];
        ((float4*)Ws)[64 * 16 + i] = ((const float4*)Wb)[i];
    }
    const int c4 = (tid & 15) * 4;
    const int rb = (tid >> 4) * RR;
    float bx_ = 0.f, by_ = 0.f, bz_ = 0.f, bw_ = 0.f;
    if (BIAS) {
        float4 b4 = *(const float4*)(bias + c4);
        bx_ = b4.x; by_ = b4.y; bz_ = b4.z; bw_ = b4.w;
    }
    const int ntiles = (N + ROWS - 1) / ROWS;
    for (int tile = bid; tile < ntiles; tile += gsz) {
        const int row0 = tile * ROWS;
        __syncthreads();
        for (int i = tid; i < ROWS * KF4; i += 256) {
            int r = i >> 5, k4 = (i & 31) * 4;
            int row = row0 + r;
            float4 v = make_float4(0.f, 0.f, 0.f, 0.f);
            if (row < N)
                v = (k4 < 64) ? *(const float4*)(xa + (size_t)row * 64 + k4)
                              : *(const float4*)(xb + (size_t)row * 64 + (k4 - 64));
            *(float4*)(op + r * STRIDE + k4) = v;
        }
        __syncthreads();
        float acc[RR][4];
#pragma unroll
        for (int i = 0; i < RR; ++i) {
            acc[i][0] = bx_; acc[i][1] = by_; acc[i][2] = bz_; acc[i][3] = bw_;
        }
        for (int kk = 0; kk < 128; kk += 4) {
            float4 w0 = *(const float4*)(Ws + (kk + 0) * 64 + c4);
            float4 w1 = *(const float4*)(Ws + (kk + 1) * 64 + c4);
            float4 w2 = *(const float4*)(Ws + (kk + 2) * 64 + c4);
            float4 w3 = *(const float4*)(Ws + (kk + 3) * 64 + c4);
#pragma unroll
            for (int i = 0; i < RR; ++i) {
                float4 o = *(const float4*)(op + (rb + i) * STRIDE + kk);
                FMA_ROW(acc[i], o.x, w0);
                FMA_ROW(acc[i], o.y, w1);
                FMA_ROW(acc[i], o.z, w2);
                FMA_ROW(acc[i], o.w, w3);
            }
        }
#pragma unroll
        for (int i = 0; i < RR; ++i) {
            int row = row0 + rb + i;
            if (row >= N) continue;
            *(float4*)(h + row * 64 + c4) =
                make_float4(acc[i][0], acc[i][1], acc[i][2], acc[i][3]);
        }
    }
}

// ------- out[e] = dot64(hu[lu[e]], hp[lp[e]]); quarter-wave per edge, float4 -------
__global__ __launch_bounds__(256) void k_classify4(const float* __restrict__ hu,
                                                   const float* __restrict__ hp,
                                                   const int* __restrict__ lu,
                                                   const int* __restrict__ lp,
                                                   float* __restrict__ out, int EL) {
    int w = (blockIdx.x * 256 + threadIdx.x) >> 6;
    int lane = threadIdx.x & 63;
    int q = lane >> 4, t = lane & 15;
    int e = w * 4 + q;
    float v = 0.f;
    if (e < EL) {
        int u = lu[e], p = lp[e];
        float4 a = *(const float4*)(hu + u * 64 + t * 4);
        float4 b = *(const float4*)(hp + p * 64 + t * 4);
        v = a.x * b.x + a.y * b.y + a.z * b.z + a.w * b.w;
    }
#pragma unroll
    for (int m = 1; m < 16; m <<= 1) v += __shfl_xor(v, m, 64);
    if (t == 0 && e < EL) out[e] = v;
}

extern "C" void kernel_launch(void* const* d_in, const int* in_sizes, int n_in,
                              void* d_out, int out_size, void* d_ws, size_t ws_size,
                              hipStream_t stream) {
    const float* x_user    = (const float*)d_in[0];
    const float* x_product = (const float*)d_in[1];
    const float* W1bl = (const float*)d_in[2];
    const float* b1b  = (const float*)d_in[3];
    const float* W1br = (const float*)d_in[4];
    const float* W1rl = (const float*)d_in[5];
    const float* b1r  = (const float*)d_in[6];
    const float* W1rr = (const float*)d_in[7];
    const float* W2bl = (const float*)d_in[8];
    const float* b2b  = (const float*)d_in[9];
    const float* W2br = (const float*)d_in[10];
    const float* W2rl = (const float*)d_in[11];
    const float* b2r  = (const float*)d_in[12];
    const float* W2rr = (const float*)d_in[13];
    const int* esrc = (const int*)d_in[14];
    const int* edst = (const int*)d_in[15];
    const int* lu   = (const int*)d_in[16];
    const int* lp   = (const int*)d_in[17];

    const int NU = in_sizes[0] / 64;
    const int NP = in_sizes[1] / 128;
    const int E  = in_sizes[14];
    const int EL = in_sizes[16];
    const int NBP = (NP + 255) >> BSH;
    const int NBU = (NU + 255) >> BSH;

    // ---- workspace layout ----
    char* ws = (char*)d_ws;
    size_t off = 0;
    auto alloc = [&](size_t bytes) -> void* {
        void* p = ws + off;
        off += (bytes + 255) & ~(size_t)255;
        return p;
    };
    int*   deg_u  = (int*)alloc((size_t)NU * 4);
    int*   deg_p  = (int*)alloc((size_t)NP * 4);
    int*   ptr_u  = (int*)alloc((size_t)NU * 4);
    int*   ptr_p  = (int*)alloc((size_t)NP * 4);
    int*   bcntP  = (int*)alloc((size_t)MAXB * 4);   // contiguous with bcntU: one memset
    int*   bcntU  = (int*)alloc((size_t)MAXB * 4);
    int*   basesP = (int*)alloc((size_t)(MAXB + 1) * 4);
    int*   basesU = (int*)alloc((size_t)(MAXB + 1) * 4);
    int*   curP   = (int*)alloc((size_t)MAXB * 4);
    int*   curU   = (int*)alloc((size_t)MAXB * 4);
    int*   nbr_u  = (int*)alloc((size_t)E * 4);
    int*   nbr_p  = (int*)alloc((size_t)E * 4);
    // union region: pairs (CSR build) then agg (gather onward)
    size_t aggBytes = (size_t)(NP + NU) * 64 * 4;
    size_t pairBytes = (size_t)E * 8 * 2;
    char* uni = (char*)alloc(aggBytes > pairBytes ? aggBytes : pairBytes);
    float* aggP   = (float*)uni;
    float* aggU   = (float*)(uni + (size_t)NP * 64 * 4);
    uint2* pairsP = (uint2*)uni;
    uint2* pairsU = (uint2*)(uni + (size_t)E * 8);
    u16*   bfA    = (u16*)alloc((size_t)NU * 64 * 2);  // x_user_bf, then h_u_bf
    u16*   bfB    = (u16*)alloc((size_t)NP * 64 * 2);  // y_p1_bf,  then h_p_bf
    float* h_p    = (float*)alloc((size_t)NP * 64 * 4);
    float* h_u    = (float*)alloc((size_t)NU * 64 * 4);

    // ---- CSR build: bucketed counting sort, both directions ----
    hipMemsetAsync(bcntP, 0, (size_t)MAXB * 2 * 4, stream);  // bcntP+bcntU contiguous
    const int n8 = NU * 64 / 8;
    const int castBlocks = (n8 + 255) / 256;
    k_histCast<<<HB + castBlocks, 256, 0, stream>>>(esrc, edst, bcntP, bcntU, NBP, NBU, E,
                                                    x_user, bfA, n8);
    k_scanBuckets<<<2, 256, 0, stream>>>(bcntP, basesP, curP, NBP, bcntU, basesU, curU, NBU);
    const int pblocks = (E + CHUNK - 1) / CHUNK;
    k_partition2<<<2 * pblocks, 256, 0, stream>>>(edst, esrc, curP, pairsP, NBP,
                                                  esrc, edst, curU, pairsU, NBU, E, pblocks);
    k_bucketFill<<<NBP + NBU, 256, 0, stream>>>(pairsP, basesP, NBP, nbr_p, deg_p, ptr_p, NP,
                                                pairsU, basesU, NBU, nbr_u, deg_u, ptr_u, NU);

    const int tP32 = (NP + 31) / 32;
    const int tP64 = (NP + 63) / 64, tU64 = (NU + 63) / 64;
    const int tU32 = (NU + 31) / 32;
    auto cap = [](int t, int c) { return t < c ? t : c; };

    // ---- pre-gather combines (depend only on raw inputs) ----
    // bfB = bf16(x_product @ W1rl): EMIT-only
    k_ctile<128, 32, false, true, false, false, false><<<cap(tP32, 768), 256, 0, stream>>>(
        nullptr, nullptr, x_product, W1rl, nullptr, bfB, NP);
    // h_p = x_product @ W1br (STORE only; becomes PRE of the post-gather pass)
    k_ctile<128, 32, false, false, false, false, true><<<cap(tP32, 768), 256, 0, stream>>>(
        nullptr, nullptr, x_product, W1br, h_p, nullptr, NP);

    // ---- layer 1: fused dual gather, then ONE paired combine ----
    k_gather2<<<(NP + NU + 3) / 4, 256, 0, stream>>>(bfA, nbr_p, ptr_p, deg_p, aggP, NP,
                                                     bfB, nbr_u, ptr_u, deg_u, aggU, NU);
    // side0: h_p = relu(h_p + b1b + aggP@W1bl), emit bfB
    // side1: h_u = relu(aggU + b1r + x_user@W1rr), emit bfA
    {
        const int gP = cap(tP64, 512), gU = cap(tU64, 1024);
        k_ctilePair64X<true, true, true, true><<<gP + gU, 256, 0, stream>>>(
            h_p, b1b, aggP, W1bl, h_p, bfB, NP, gP,
            aggU, b1r, x_user, W1rr, h_u, bfA, NU);
    }

    // ---- layer 2: fused dual gather, then ONE concat-K combine ----
    k_gather2<<<(NP + NU + 3) / 4, 256, 0, stream>>>(bfA, nbr_p, ptr_p, deg_p, aggP, NP,
                                                     bfB, nbr_u, ptr_u, deg_u, aggU, NU);
    // side0: h_p = b2b + [aggP|h_p] @ [W2bl;W2br]
    // side1: h_u = b2r + [aggU|h_u] @ [W2rl;W2rr]
    {
        const int gP = cap(tP32, 512), gU = cap(tU32, 1024);
        k_ctilePairCat<true><<<gP + gU, 256, 0, stream>>>(
            b2b, aggP, h_p, W2bl, W2br, h_p, NP, gP,
            b2r, aggU, h_u, W2rl, W2rr, h_u, NU);
    }

    // ---- classifier ----
    k_classify4<<<((EL + 3) / 4 + 3) / 4, 256, 0, stream>>>(h_u, h_p, lu, lp, (float*)d_out, EL);
}

// Round 6
// 492.290 us; speedup vs baseline: 1.3063x; 1.0108x over previous
//
#include <hip/hip_runtime.h>

// 2-layer hetero GraphSAGE, fp32 compute, bf16 gather tables, bucketed CSR build,
// persistent-weight register-tiled combines.
// HARD RULES (accumulated post-mortems):
//  R6/R7: one K-loop (one weight matrix tile) per kernel body — dual-weight
//    loops spill to 256 VGPR + scratch. Fusion via PRE operand, block-range
//    select, or CONCAT-K (stacked weights in ONE LDS tile, one loop).
//  R8: split gathers lower FETCH but not time (latency-bound) — keep fused dual gather.
//  R9 (VERIFIED 73.9-74.2us): gather = one coalesced offset-vector load + __shfl
//    distribution + 8-deep burst of row loads with per-lane masks + ZERO-INIT.
//    The zero-inits are LOAD-LIVENESS ANCHORS (force v0..v7 live together).
//  R10: removing the anchors serializes the burst (74.4 -> 79.6). Gather is
//    memory-request-service bound at ~74us; VALU dieting doesn't move it.
//  R11 (REVERTED): RUNTIME epilogue flags -> VGPR 248, occupancy 10%, 3x
//    regression. Combine polymorphism must be COMPILE-TIME, identical flags
//    on both sides of a block-range pair. Block-range fusion of identical
//    bodies is safe.
//  R13 (VERIFIED −22us): concat-K layer-2 single pass; pre-gather hoist of
//    x_product@W1br enabling a single layer-1 pair.
//  R14: (a) classifier edges bucket-sorted by lab_p (hp reads become 64KB-
//    window local, ~10x row reuse; lu/out random 4B accesses are L2-resident);
//    (b) the two pre-gather K=128 ctiles merged into one k_ctilePairX<128>
//    launch with unified EMIT+STORE flags (dead writes into not-yet-live h_u).

using u16 = unsigned short;
using u32 = unsigned int;

__device__ __forceinline__ u16 bf16r(float f) {            // round-to-nearest-even
    u32 b = __float_as_uint(f);
    b += 0x7fffu + ((b >> 16) & 1u);
    return (u16)(b >> 16);
}
__device__ __forceinline__ float bflo(u32 u) { return __uint_as_float(u << 16); }
__device__ __forceinline__ float bfhi(u32 u) { return __uint_as_float(u & 0xffff0000u); }

#define BSH 8          // bucket = key >> BSH, 256 node ids per bucket
#define MAXB 512       // max buckets per direction (NU=100000 -> 391)
#define CHUNK 4096     // edges per partition block
#define RPT 16         // CHUNK / 256
#define HB 512         // edge-histogram blocks in fused hist kernel
#define LB 64          // label-histogram blocks in fused hist kernel

// ---- pass A (fused): blocks [0,HB) edge bucket histograms (both directions);
// ---- [HB,HB+LB) label-edge histogram over lab_p; [HB+LB,..) cast x_user->bf16 ----
__global__ __launch_bounds__(256) void k_histCast(const int* __restrict__ esrc,
                                                  const int* __restrict__ edst,
                                                  int* __restrict__ bcntP,
                                                  int* __restrict__ bcntU,
                                                  int NBP, int NBU, int E,
                                                  const int* __restrict__ labp,
                                                  int* __restrict__ bcntL,
                                                  int NBL, int EL,
                                                  const float* __restrict__ xc,
                                                  u16* __restrict__ yc, int n8) {
    __shared__ int hP[MAXB];
    __shared__ int hU[MAXB];
    int tid = threadIdx.x;
    int bix = blockIdx.x;
    if (bix >= HB + LB) {                       // ---- cast range ----
        int i = (bix - HB - LB) * 256 + tid;
        if (i < n8) {
            const float4* x4 = (const float4*)xc;
            float4 a = x4[i * 2], b = x4[i * 2 + 1];
            uint4 o;
            o.x = (u32)bf16r(a.x) | ((u32)bf16r(a.y) << 16);
            o.y = (u32)bf16r(a.z) | ((u32)bf16r(a.w) << 16);
            o.z = (u32)bf16r(b.x) | ((u32)bf16r(b.y) << 16);
            o.w = (u32)bf16r(b.z) | ((u32)bf16r(b.w) << 16);
            ((uint4*)yc)[i] = o;
        }
        return;
    }
    if (bix >= HB) {                            // ---- label histogram range ----
        for (int i = tid; i < MAXB; i += 256) hP[i] = 0;
        __syncthreads();
        int EL4 = EL >> 2;
        const int4* l4 = (const int4*)labp;
        int stride = LB * 256;
        for (int i = (bix - HB) * 256 + tid; i < EL4; i += stride) {
            int4 l = l4[i];
            atomicAdd(&hP[l.x >> BSH], 1); atomicAdd(&hP[l.y >> BSH], 1);
            atomicAdd(&hP[l.z >> BSH], 1); atomicAdd(&hP[l.w >> BSH], 1);
        }
        if (bix == HB && tid < (EL & 3))
            atomicAdd(&hP[labp[EL4 * 4 + tid] >> BSH], 1);
        __syncthreads();
        for (int i = tid; i < NBL; i += 256) if (hP[i]) atomicAdd(&bcntL[i], hP[i]);
        return;
    }
    // ---- edge histogram range ----
    for (int i = tid; i < MAXB; i += 256) { hP[i] = 0; hU[i] = 0; }
    __syncthreads();
    int E4 = E >> 2;
    const int4* s4 = (const int4*)esrc;
    const int4* d4 = (const int4*)edst;
    int stride = HB * 256;
    for (int i = bix * 256 + tid; i < E4; i += stride) {
        int4 s = s4[i], d = d4[i];
        atomicAdd(&hU[s.x >> BSH], 1); atomicAdd(&hU[s.y >> BSH], 1);
        atomicAdd(&hU[s.z >> BSH], 1); atomicAdd(&hU[s.w >> BSH], 1);
        atomicAdd(&hP[d.x >> BSH], 1); atomicAdd(&hP[d.y >> BSH], 1);
        atomicAdd(&hP[d.z >> BSH], 1); atomicAdd(&hP[d.w >> BSH], 1);
    }
    if (bix == 0 && tid < (E & 3)) {
        int e = E4 * 4 + tid;
        atomicAdd(&hU[esrc[e] >> BSH], 1);
        atomicAdd(&hP[edst[e] >> BSH], 1);
    }
    __syncthreads();
    for (int i = tid; i < NBP; i += 256) if (hP[i]) atomicAdd(&bcntP[i], hP[i]);
    for (int i = tid; i < NBU; i += 256) if (hU[i]) atomicAdd(&bcntU[i], hU[i]);
}

// ---- scan bucket counts -> bases[NB+1], cursor[NB]; block 0=P, 1=U, 2=L ----
__global__ __launch_bounds__(256) void k_scanBuckets(const int* __restrict__ cntP,
                                                     int* __restrict__ basesP,
                                                     int* __restrict__ curP, int NBP,
                                                     const int* __restrict__ cntU,
                                                     int* __restrict__ basesU,
                                                     int* __restrict__ curU, int NBU,
                                                     const int* __restrict__ cntL,
                                                     int* __restrict__ basesL,
                                                     int* __restrict__ curL, int NBL) {
    const int* cnt; int* bases; int* cur; int NB;
    if (blockIdx.x == 0)      { cnt = cntP; bases = basesP; cur = curP; NB = NBP; }
    else if (blockIdx.x == 1) { cnt = cntU; bases = basesU; cur = curU; NB = NBU; }
    else                      { cnt = cntL; bases = basesL; cur = curL; NB = NBL; }
    __shared__ int sA[MAXB];
    __shared__ int sB[MAXB];
    int tid = threadIdx.x;
    int v0 = (tid < NB) ? cnt[tid] : 0;
    int v1 = (tid + 256 < NB) ? cnt[tid + 256] : 0;
    sA[tid] = v0; sA[tid + 256] = v1;
    __syncthreads();
    int* src = sA; int* dst = sB;
    for (int off = 1; off < MAXB; off <<= 1) {
        dst[tid] = src[tid] + ((tid >= off) ? src[tid - off] : 0);
        int i2 = tid + 256;
        dst[i2] = src[i2] + ((i2 >= off) ? src[i2 - off] : 0);
        __syncthreads();
        int* t = src; src = dst; dst = t;
    }
    if (tid < NB)       { bases[tid] = src[tid] - v0;             cur[tid] = src[tid] - v0; }
    if (tid + 256 < NB) { bases[tid + 256] = src[tid + 256] - v1; cur[tid + 256] = src[tid + 256] - v1; }
    if (tid == 0) bases[NB] = src[MAXB - 1];
}

// ---- pass B (3 ranges fused): partition (key,payload) into bucket order.
// [0,pblocks)=P edges, [pblocks,2*pblocks)=U edges, [2*pblocks,..)=label edges
// (label payload = global index; pay==nullptr selects iota). ----
__global__ __launch_bounds__(256) void k_partition3(
    const int* __restrict__ keysP, const int* __restrict__ payP,
    int* __restrict__ curPp, uint2* __restrict__ pairsP, int NBP,
    const int* __restrict__ keysU, const int* __restrict__ payU,
    int* __restrict__ curUp, uint2* __restrict__ pairsU, int NBU,
    int E, int pblocks,
    const int* __restrict__ keysL,
    int* __restrict__ curLp, uint2* __restrict__ pairsL, int NBL, int EL) {
    __shared__ int hist[MAXB];
    __shared__ int sA[MAXB];
    __shared__ int sB[MAXB];
    __shared__ int bx[MAXB];
    __shared__ int gbase[MAXB];
    __shared__ uint2 prs[CHUNK];
    const int* keys; const int* pay; int* cursor; uint2* pairs; int NB, cb, nE;
    if ((int)blockIdx.x < pblocks) {
        keys = keysP; pay = payP; cursor = curPp; pairs = pairsP; NB = NBP;
        cb = blockIdx.x; nE = E;
    } else if ((int)blockIdx.x < 2 * pblocks) {
        keys = keysU; pay = payU; cursor = curUp; pairs = pairsU; NB = NBU;
        cb = blockIdx.x - pblocks; nE = E;
    } else {
        keys = keysL; pay = nullptr; cursor = curLp; pairs = pairsL; NB = NBL;
        cb = blockIdx.x - 2 * pblocks; nE = EL;
    }
    int tid = threadIdx.x;
    int i0 = cb * CHUNK;
    int count = min(CHUNK, nE - i0);
    for (int i = tid; i < MAXB; i += 256) hist[i] = 0;
    __syncthreads();
    int keyr[RPT], payr[RPT], rankr[RPT];
#pragma unroll
    for (int r = 0; r < RPT; ++r) {
        int idx = r * 256 + tid;
        if (idx < count) {
            int k = keys[i0 + idx];
            keyr[r] = k;
            payr[r] = pay ? pay[i0 + idx] : (i0 + idx);
            rankr[r] = atomicAdd(&hist[k >> BSH], 1);
        } else keyr[r] = -1;
    }
    __syncthreads();
    // exclusive scan of hist -> bx (ping-pong, 512 wide)
    sA[tid] = hist[tid]; sA[tid + 256] = hist[tid + 256];
    __syncthreads();
    int* src = sA; int* dst = sB;
    for (int off = 1; off < MAXB; off <<= 1) {
        dst[tid] = src[tid] + ((tid >= off) ? src[tid - off] : 0);
        int i2 = tid + 256;
        dst[i2] = src[i2] + ((i2 >= off) ? src[i2 - off] : 0);
        __syncthreads();
        int* t = src; src = dst; dst = t;
    }
    bx[tid] = src[tid] - hist[tid];
    bx[tid + 256] = src[tid + 256] - hist[tid + 256];
    __syncthreads();
    for (int b = tid; b < NB; b += 256) {
        int c = hist[b];
        gbase[b] = c ? atomicAdd(&cursor[b], c) : 0;
    }
    // stage into LDS in bucket order
#pragma unroll
    for (int r = 0; r < RPT; ++r) {
        if (keyr[r] >= 0)
            prs[bx[keyr[r] >> BSH] + rankr[r]] = make_uint2((u32)keyr[r], (u32)payr[r]);
    }
    __syncthreads();
    // coalesced segment copy-out
    for (int j = tid; j < count; j += 256) {
        uint2 pr = prs[j];
        int b = pr.x >> BSH;
        pairs[gbase[b] + (j - bx[b])] = pr;
    }
}

// ---- pass C: per-bucket fine fill -> nbr, deg, ptr(start); both directions fused ----
// nbr stores BYTE offsets into the 128B-row bf16 tables (id << 7).
__global__ __launch_bounds__(256) void k_bucketFill(
    const uint2* __restrict__ pairsP, const int* __restrict__ basesP, int NBP,
    int* __restrict__ nbr_p, int* __restrict__ deg_p, int* __restrict__ ptr_p, int NP,
    const uint2* __restrict__ pairsU, const int* __restrict__ basesU, int NBU,
    int* __restrict__ nbr_u, int* __restrict__ deg_u, int* __restrict__ ptr_u, int NU) {
    const uint2* pairs; const int* bases; int* nbr; int* deg; int* ptr; int N; int bucket;
    if ((int)blockIdx.x < NBP) {
        pairs = pairsP; bases = basesP; nbr = nbr_p; deg = deg_p; ptr = ptr_p; N = NP;
        bucket = blockIdx.x;
    } else {
        pairs = pairsU; bases = basesU; nbr = nbr_u; deg = deg_u; ptr = ptr_u; N = NU;
        bucket = blockIdx.x - NBP;
    }
    int tid = threadIdx.x;
    int base = bases[bucket];
    int cnt = bases[bucket + 1] - base;
    __shared__ int h[256];
    __shared__ int s[256];
    __shared__ int cur[256];
    h[tid] = 0;
    __syncthreads();
    for (int j = tid; j < cnt; j += 256) atomicAdd(&h[pairs[base + j].x & 255], 1);
    __syncthreads();
    int d = h[tid];
    s[tid] = d;
    __syncthreads();
    for (int off = 1; off < 256; off <<= 1) {
        int v = (tid >= off) ? s[tid - off] : 0;
        __syncthreads();
        s[tid] += v;
        __syncthreads();
    }
    int excl = s[tid] - d;
    int node = bucket * 256 + tid;
    if (node < N) { deg[node] = d; ptr[node] = base + excl; }
    cur[tid] = excl;
    __syncthreads();
    for (int j = tid; j < cnt; j += 256) {
        uint2 pr = pairs[base + j];
        int pos = atomicAdd(&cur[pr.x & 255], 1);
        nbr[base + pos] = (int)(pr.y << 7);     // byte offset of row (128B rows)
    }
}

#define ACC8(A0,A1,A2,A3,A4,A5,A6,A7,V) \
    A0 += bflo((V).x); A1 += bfhi((V).x); A2 += bflo((V).y); A3 += bfhi((V).y); \
    A4 += bflo((V).z); A5 += bfhi((V).z); A6 += bflo((V).w); A7 += bfhi((V).w);

// ------- fused dual gather-mean: nodes [0,NA) CSR A, [NA,NA+NB) CSR B -------
// wave per node; 8 lanes per bf16 row (uint4). R9 shape — do not restructure.
__global__ __launch_bounds__(256) void k_gather2(
    const u16* __restrict__ yA, const int* __restrict__ nbrA, const int* __restrict__ stpA,
    const int* __restrict__ degA, float* __restrict__ aggA, int NA,
    const u16* __restrict__ yB, const int* __restrict__ nbrB, const int* __restrict__ stpB,
    const int* __restrict__ degB, float* __restrict__ aggB, int NB) {
    int w = (blockIdx.x * 256 + threadIdx.x) >> 6;
    int lane = threadIdx.x & 63;
    if (w >= NA + NB) return;
    const u16* y; const int* nbr; const int* stp; const int* deg; float* agg; int n;
    if (w < NA) { y = yA; nbr = nbrA; stp = stpA; deg = degA; agg = aggA; n = w; }
    else        { y = yB; nbr = nbrB; stp = stpB; deg = degB; agg = aggB; n = w - NA; }
    const int q = lane >> 3, t = lane & 7;
    const int d = deg[n];
    const int st = stp[n];
    const char* yb = (const char*)y + t * 16;
    float a0=0,a1=0,a2=0,a3=0,a4=0,a5=0,a6=0,a7=0;
    for (int j = 0; j < d; j += 64) {
        const int cnt = min(d - j, 64);           // wave-uniform
        int offv = 0;
        if (lane < cnt) offv = nbr[st + j + lane];   // one coalesced 256B load
        // distribute + burst-issue all row loads (independent, exec-masked tails)
#define GLD(R) \
        int g##R = __shfl(offv, R * 8 + q, 64); \
        uint4 v##R = make_uint4(0u, 0u, 0u, 0u); \
        if (R * 8 + q < cnt) v##R = *(const uint4*)(yb + g##R);
        GLD(0) GLD(1) GLD(2) GLD(3) GLD(4) GLD(5) GLD(6) GLD(7)
#undef GLD
        // accumulate (rounds beyond cnt are uniform-skipped; masked lanes hold 0)
#define ACCR(R) if (R * 8 < cnt) { ACC8(a0,a1,a2,a3,a4,a5,a6,a7,v##R) }
        ACCR(0) ACCR(1) ACCR(2) ACCR(3) ACCR(4) ACCR(5) ACCR(6) ACCR(7)
#undef ACCR
    }
#pragma unroll
    for (int m = 8; m < 64; m <<= 1) {
        a0 += __shfl_xor(a0, m, 64); a1 += __shfl_xor(a1, m, 64);
        a2 += __shfl_xor(a2, m, 64); a3 += __shfl_xor(a3, m, 64);
        a4 += __shfl_xor(a4, m, 64); a5 += __shfl_xor(a5, m, 64);
        a6 += __shfl_xor(a6, m, 64); a7 += __shfl_xor(a7, m, 64);
    }
    if (q == 0) {
        float dinv = 1.0f / (float)max(d, 1);
        float* dstp = agg + n * 64 + t * 8;
        *(float4*)dstp       = make_float4(a0 * dinv, a1 * dinv, a2 * dinv, a3 * dinv);
        *(float4*)(dstp + 4) = make_float4(a4 * dinv, a5 * dinv, a6 * dinv, a7 * dinv);
    }
}

#define FMA_ROW(ACC, O, W4) \
    ACC[0] += (O) * (W4).x; ACC[1] += (O) * (W4).y; \
    ACC[2] += (O) * (W4).z; ACC[3] += (O) * (W4).w;

// ======= paired combine: two independent K-dim problems, block-range selected =======
// COMPILE-TIME flags, IDENTICAL for both sides (R11 rule). Single K-loop body.
// h = act((PRE?pre:0) + (BIAS?b:0) + x@W); always STORE; optional RELU + EMIT.
// K=64: ROWS=64 (33.8KB LDS). K=128: ROWS=32 (49.7KB LDS).
template <int K, bool PRE, bool BIAS, bool RELU, bool EMIT>
__global__ __launch_bounds__(256) void k_ctilePairX(
    const float* __restrict__ pre0, const float* __restrict__ bias0,
    const float* __restrict__ x0, const float* __restrict__ W0,
    float* __restrict__ h0, u16* __restrict__ hbf0, int N0, int g0,
    const float* __restrict__ pre1, const float* __restrict__ bias1,
    const float* __restrict__ x1, const float* __restrict__ W1,
    float* __restrict__ h1, u16* __restrict__ hbf1, int N1) {
    constexpr int ROWS = (K == 64) ? 64 : 32;
    constexpr int RR = ROWS / 16;
    constexpr int STRIDE = K + 4;
    constexpr int KF4 = K / 4;
    __shared__ float Ws[K * 64];
    __shared__ float op[ROWS * STRIDE];
    const float* pre; const float* bias; const float* x; const float* W;
    float* h; u16* hbf;
    int N, bid, gsz;
    if ((int)blockIdx.x < g0) {
        pre = pre0; bias = bias0; x = x0; W = W0; h = h0; hbf = hbf0; N = N0;
        bid = blockIdx.x; gsz = g0;
    } else {
        pre = pre1; bias = bias1; x = x1; W = W1; h = h1; hbf = hbf1; N = N1;
        bid = blockIdx.x - g0; gsz = gridDim.x - g0;
    }
    const int tid = threadIdx.x;
    for (int i = tid; i < K * 16; i += 256)
        ((float4*)Ws)[i] = ((const float4*)W)[i];
    const int c4 = (tid & 15) * 4;
    const int rb = (tid >> 4) * RR;
    float bx_ = 0.f, by_ = 0.f, bz_ = 0.f, bw_ = 0.f;
    if (BIAS) {
        float4 b4 = *(const float4*)(bias + c4);
        bx_ = b4.x; by_ = b4.y; bz_ = b4.z; bw_ = b4.w;
    }
    const int ntiles = (N + ROWS - 1) / ROWS;
    for (int tile = bid; tile < ntiles; tile += gsz) {
        const int row0 = tile * ROWS;
        __syncthreads();
        for (int i = tid; i < ROWS * KF4; i += 256) {
            int r = i / KF4, k4 = (i % KF4) * 4;
            int row = row0 + r;
            float4 v = make_float4(0.f, 0.f, 0.f, 0.f);
            if (row < N) v = *(const float4*)(x + (size_t)row * K + k4);
            *(float4*)(op + r * STRIDE + k4) = v;
        }
        __syncthreads();
        float acc[RR][4];
#pragma unroll
        for (int i = 0; i < RR; ++i) {
            float px = 0.f, py = 0.f, pz = 0.f, pw = 0.f;
            if (PRE) {
                int row = row0 + rb + i;
                if (row < N) {
                    float4 p = *(const float4*)(pre + row * 64 + c4);
                    px = p.x; py = p.y; pz = p.z; pw = p.w;
                }
            }
            acc[i][0] = bx_ + px; acc[i][1] = by_ + py;
            acc[i][2] = bz_ + pz; acc[i][3] = bw_ + pw;
        }
        for (int kk = 0; kk < K; kk += 4) {
            float4 w0 = *(const float4*)(Ws + (kk + 0) * 64 + c4);
            float4 w1 = *(const float4*)(Ws + (kk + 1) * 64 + c4);
            float4 w2 = *(const float4*)(Ws + (kk + 2) * 64 + c4);
            float4 w3 = *(const float4*)(Ws + (kk + 3) * 64 + c4);
#pragma unroll
            for (int i = 0; i < RR; ++i) {
                float4 o = *(const float4*)(op + (rb + i) * STRIDE + kk);
                FMA_ROW(acc[i], o.x, w0);
                FMA_ROW(acc[i], o.y, w1);
                FMA_ROW(acc[i], o.z, w2);
                FMA_ROW(acc[i], o.w, w3);
            }
        }
#pragma unroll
        for (int i = 0; i < RR; ++i) {
            int row = row0 + rb + i;
            if (row >= N) continue;
            float v0 = acc[i][0], v1 = acc[i][1], v2 = acc[i][2], v3 = acc[i][3];
            if (RELU) {
                v0 = fmaxf(v0, 0.f); v1 = fmaxf(v1, 0.f);
                v2 = fmaxf(v2, 0.f); v3 = fmaxf(v3, 0.f);
            }
            *(float4*)(h + row * 64 + c4) = make_float4(v0, v1, v2, v3);
            if (EMIT) {
                uint2 o;
                o.x = (u32)bf16r(v0) | ((u32)bf16r(v1) << 16);
                o.y = (u32)bf16r(v2) | ((u32)bf16r(v3) << 16);
                *(uint2*)(hbf + row * 64 + c4) = o;
            }
        }
    }
}

// ======= paired CONCAT combine: h = bias + [xa|xb] @ [Wa;Wb], K=128 =======
// ONE K-loop, ONE LDS weight tile (filled from two 64x64 sources).
template <bool BIAS>
__global__ __launch_bounds__(256) void k_ctilePairCat(
    const float* __restrict__ bias0, const float* __restrict__ xa0,
    const float* __restrict__ xb0, const float* __restrict__ Wa0,
    const float* __restrict__ Wb0, float* __restrict__ h0, int N0, int g0,
    const float* __restrict__ bias1, const float* __restrict__ xa1,
    const float* __restrict__ xb1, const float* __restrict__ Wa1,
    const float* __restrict__ Wb1, float* __restrict__ h1, int N1) {
    constexpr int ROWS = 32, RR = 2, STRIDE = 132, KF4 = 32;
    __shared__ float Ws[128 * 64];
    __shared__ float op[ROWS * STRIDE];
    const float* bias; const float* xa; const float* xb;
    const float* Wa; const float* Wb; float* h;
    int N, bid, gsz;
    if ((int)blockIdx.x < g0) {
        bias = bias0; xa = xa0; xb = xb0; Wa = Wa0; Wb = Wb0; h = h0; N = N0;
        bid = blockIdx.x; gsz = g0;
    } else {
        bias = bias1; xa = xa1; xb = xb1; Wa = Wa1; Wb = Wb1; h = h1; N = N1;
        bid = blockIdx.x - g0; gsz = gridDim.x - g0;
    }
    const int tid = threadIdx.x;
    // Ws rows [0,64) = Wa, rows [64,128) = Wb  (1024 float4 each)
    for (int i = tid; i < 64 * 16; i += 256) {
        ((float4*)Ws)[i]           = ((const float4*)Wa)[i];
        ((float4*)Ws)[64 * 16 + i] = ((const float4*)Wb)[i];
    }
    const int c4 = (tid & 15) * 4;
    const int rb = (tid >> 4) * RR;
    float bx_ = 0.f, by_ = 0.f, bz_ = 0.f, bw_ = 0.f;
    if (BIAS) {
        float4 b4 = *(const float4*)(bias + c4);
        bx_ = b4.x; by_ = b4.y; bz_ = b4.z; bw_ = b4.w;
    }
    const int ntiles = (N + ROWS - 1) / ROWS;
    for (int tile = bid; tile < ntiles; tile += gsz) {
        const int row0 = tile * ROWS;
        __syncthreads();
        for (int i = tid; i < ROWS * KF4; i += 256) {
            int r = i >> 5, k4 = (i & 31) * 4;
            int row = row0 + r;
            float4 v = make_float4(0.f, 0.f, 0.f, 0.f);
            if (row < N)
                v = (k4 < 64) ? *(const float4*)(xa + (size_t)row * 64 + k4)
                              : *(const float4*)(xb + (size_t)row * 64 + (k4 - 64));
            *(float4*)(op + r * STRIDE + k4) = v;
        }
        __syncthreads();
        float acc[RR][4];
#pragma unroll
        for (int i = 0; i < RR; ++i) {
            acc[i][0] = bx_; acc[i][1] = by_; acc[i][2] = bz_; acc[i][3] = bw_;
        }
        for (int kk = 0; kk < 128; kk += 4) {
            float4 w0 = *(const float4*)(Ws + (kk + 0) * 64 + c4);
            float4 w1 = *(const float4*)(Ws + (kk + 1) * 64 + c4);
            float4 w2 = *(const float4*)(Ws + (kk + 2) * 64 + c4);
            float4 w3 = *(const float4*)(Ws + (kk + 3) * 64 + c4);
#pragma unroll
            for (int i = 0; i < RR; ++i) {
                float4 o = *(const float4*)(op + (rb + i) * STRIDE + kk);
                FMA_ROW(acc[i], o.x, w0);
                FMA_ROW(acc[i], o.y, w1);
                FMA_ROW(acc[i], o.z, w2);
                FMA_ROW(acc[i], o.w, w3);
            }
        }
#pragma unroll
        for (int i = 0; i < RR; ++i) {
            int row = row0 + rb + i;
            if (row >= N) continue;
            *(float4*)(h + row * 64 + c4) =
                make_float4(acc[i][0], acc[i][1], acc[i][2], acc[i][3]);
        }
    }
}

// ------- sorted classifier: pairsL = (p, e) bucket-ordered by p.
// out[e] = dot64(hu[lu[e]], hp[p]); quarter-wave per pair, float4 lanes. -------
__global__ __launch_bounds__(256) void k_classifyS(const float* __restrict__ hu,
                                                   const float* __restrict__ hp,
                                                   const int* __restrict__ lu,
                                                   const uint2* __restrict__ pairsL,
                                                   float* __restrict__ out, int EL) {
    int w = (blockIdx.x * 256 + threadIdx.x) >> 6;
    int lane = threadIdx.x & 63;
    int q = lane >> 4, t = lane & 15;
    int j = w * 4 + q;
    float v = 0.f;
    int e = 0;
    bool ok = j < EL;
    if (ok) {
        uint2 pr = pairsL[j];
        int p = (int)pr.x;
        e = (int)pr.y;
        int u = lu[e];
        float4 a = *(const float4*)(hu + (size_t)u * 64 + t * 4);
        float4 b = *(const float4*)(hp + (size_t)p * 64 + t * 4);
        v = a.x * b.x + a.y * b.y + a.z * b.z + a.w * b.w;
    }
#pragma unroll
    for (int m = 1; m < 16; m <<= 1) v += __shfl_xor(v, m, 64);
    if (t == 0 && ok) out[e] = v;
}

extern "C" void kernel_launch(void* const* d_in, const int* in_sizes, int n_in,
                              void* d_out, int out_size, void* d_ws, size_t ws_size,
                              hipStream_t stream) {
    const float* x_user    = (const float*)d_in[0];
    const float* x_product = (const float*)d_in[1];
    const float* W1bl = (const float*)d_in[2];
    const float* b1b  = (const float*)d_in[3];
    const float* W1br = (const float*)d_in[4];
    const float* W1rl = (const float*)d_in[5];
    const float* b1r  = (const float*)d_in[6];
    const float* W1rr = (const float*)d_in[7];
    const float* W2bl = (const float*)d_in[8];
    const float* b2b  = (const float*)d_in[9];
    const float* W2br = (const float*)d_in[10];
    const float* W2rl = (const float*)d_in[11];
    const float* b2r  = (const float*)d_in[12];
    const float* W2rr = (const float*)d_in[13];
    const int* esrc = (const int*)d_in[14];
    const int* edst = (const int*)d_in[15];
    const int* lu   = (const int*)d_in[16];
    const int* lp   = (const int*)d_in[17];

    const int NU = in_sizes[0] / 64;
    const int NP = in_sizes[1] / 128;
    const int E  = in_sizes[14];
    const int EL = in_sizes[16];
    const int NBP = (NP + 255) >> BSH;
    const int NBU = (NU + 255) >> BSH;
    const int NBL = NBP;                        // lab_p keys share the P id space

    // ---- workspace layout ----
    char* ws = (char*)d_ws;
    size_t off = 0;
    auto alloc = [&](size_t bytes) -> void* {
        void* p = ws + off;
        off += (bytes + 255) & ~(size_t)255;
        return p;
    };
    int*   deg_u  = (int*)alloc((size_t)NU * 4);
    int*   deg_p  = (int*)alloc((size_t)NP * 4);
    int*   ptr_u  = (int*)alloc((size_t)NU * 4);
    int*   ptr_p  = (int*)alloc((size_t)NP * 4);
    int*   bcntP  = (int*)alloc((size_t)MAXB * 4);   // P,U,L contiguous: one memset
    int*   bcntU  = (int*)alloc((size_t)MAXB * 4);
    int*   bcntL  = (int*)alloc((size_t)MAXB * 4);
    int*   basesP = (int*)alloc((size_t)(MAXB + 1) * 4);
    int*   basesU = (int*)alloc((size_t)(MAXB + 1) * 4);
    int*   basesL = (int*)alloc((size_t)(MAXB + 1) * 4);
    int*   curP   = (int*)alloc((size_t)MAXB * 4);
    int*   curU   = (int*)alloc((size_t)MAXB * 4);
    int*   curL   = (int*)alloc((size_t)MAXB * 4);
    int*   nbr_u  = (int*)alloc((size_t)E * 4);
    int*   nbr_p  = (int*)alloc((size_t)E * 4);
    uint2* pairsL = (uint2*)alloc((size_t)EL * 8);   // survives until classify
    // union region: pairs (CSR build) then agg (gather onward)
    size_t aggBytes = (size_t)(NP + NU) * 64 * 4;
    size_t pairBytes = (size_t)E * 8 * 2;
    char* uni = (char*)alloc(aggBytes > pairBytes ? aggBytes : pairBytes);
    float* aggP   = (float*)uni;
    float* aggU   = (float*)(uni + (size_t)NP * 64 * 4);
    uint2* pairsP = (uint2*)uni;
    uint2* pairsU = (uint2*)(uni + (size_t)E * 8);
    u16*   bfA    = (u16*)alloc((size_t)NU * 64 * 2);  // x_user_bf, then h_u_bf
    u16*   bfB    = (u16*)alloc((size_t)NP * 64 * 2);  // y_p1_bf,  then h_p_bf
    float* h_p    = (float*)alloc((size_t)NP * 64 * 4);
    float* h_u    = (float*)alloc((size_t)NU * 64 * 4);
    // pre-gather dead-write sinks (h_u not yet live: fully overwritten later)
    float* sinkF  = h_u;                               // NP*64*4 = 12.8MB
    u16*   sinkB  = (u16*)((char*)h_u + (size_t)NP * 64 * 4);  // 6.4MB more

    // ---- CSR build + label sort: bucketed counting sort, three key streams ----
    hipMemsetAsync(bcntP, 0, (size_t)MAXB * 3 * 4, stream);  // P,U,L contiguous
    const int n8 = NU * 64 / 8;
    const int castBlocks = (n8 + 255) / 256;
    k_histCast<<<HB + LB + castBlocks, 256, 0, stream>>>(
        esrc, edst, bcntP, bcntU, NBP, NBU, E,
        lp, bcntL, NBL, EL, x_user, bfA, n8);
    k_scanBuckets<<<3, 256, 0, stream>>>(bcntP, basesP, curP, NBP,
                                         bcntU, basesU, curU, NBU,
                                         bcntL, basesL, curL, NBL);
    const int pblocks = (E + CHUNK - 1) / CHUNK;
    const int lblocks = (EL + CHUNK - 1) / CHUNK;
    k_partition3<<<2 * pblocks + lblocks, 256, 0, stream>>>(
        edst, esrc, curP, pairsP, NBP,
        esrc, edst, curU, pairsU, NBU, E, pblocks,
        lp, curL, pairsL, NBL, EL);
    k_bucketFill<<<NBP + NBU, 256, 0, stream>>>(pairsP, basesP, NBP, nbr_p, deg_p, ptr_p, NP,
                                                pairsU, basesU, NBU, nbr_u, deg_u, ptr_u, NU);

    const int tP32 = (NP + 31) / 32;
    const int tU32 = (NU + 31) / 32;
    const int tP64 = (NP + 63) / 64, tU64 = (NU + 63) / 64;
    auto cap = [](int t, int c) { return t < c ? t : c; };

    // ---- pre-gather combines, ONE paired launch (identical flags both sides):
    // side0: bfB = bf16(x_product@W1rl)   (fp32 store -> sinkF, dead)
    // side1: h_p = x_product@W1br         (bf16 emit -> sinkB, dead)
    {
        const int g0 = cap(tP32, 768);
        k_ctilePairX<128, false, false, false, true><<<g0 + cap(tP32, 768), 256, 0, stream>>>(
            nullptr, nullptr, x_product, W1rl, sinkF, bfB, NP, g0,
            nullptr, nullptr, x_product, W1br, h_p, sinkB, NP);
    }

    // ---- layer 1: fused dual gather, then ONE paired combine ----
    k_gather2<<<(NP + NU + 3) / 4, 256, 0, stream>>>(bfA, nbr_p, ptr_p, deg_p, aggP, NP,
                                                     bfB, nbr_u, ptr_u, deg_u, aggU, NU);
    // side0: h_p = relu(h_p + b1b + aggP@W1bl), emit bfB
    // side1: h_u = relu(aggU + b1r + x_user@W1rr), emit bfA
    {
        const int gP = cap(tP64, 512), gU = cap(tU64, 1024);
        k_ctilePairX<64, true, true, true, true><<<gP + gU, 256, 0, stream>>>(
            h_p, b1b, aggP, W1bl, h_p, bfB, NP, gP,
            aggU, b1r, x_user, W1rr, h_u, bfA, NU);
    }

    // ---- layer 2: fused dual gather, then ONE concat-K combine ----
    k_gather2<<<(NP + NU + 3) / 4, 256, 0, stream>>>(bfA, nbr_p, ptr_p, deg_p, aggP, NP,
                                                     bfB, nbr_u, ptr_u, deg_u, aggU, NU);
    // side0: h_p = b2b + [aggP|h_p] @ [W2bl;W2br]
    // side1: h_u = b2r + [aggU|h_u] @ [W2rl;W2rr]
    {
        const int gP = cap(tP32, 512), gU = cap(tU32, 1024);
        k_ctilePairCat<true><<<gP + gU, 256, 0, stream>>>(
            b2b, aggP, h_p, W2bl, W2br, h_p, NP, gP,
            b2r, aggU, h_u, W2rl, W2rr, h_u, NU);
    }

    // ---- classifier over p-sorted label pairs ----
    k_classifyS<<<((EL + 3) / 4 + 3) / 4, 256, 0, stream>>>(h_u, h_p, lu, pairsL,
                                                            (float*)d_out, EL);
}

// Round 7
// 482.044 us; speedup vs baseline: 1.3341x; 1.0213x over previous
//
#include <hip/hip_runtime.h>

// 2-layer hetero GraphSAGE, fp32 compute, bf16 gather tables, bucketed CSR build,
// persistent-weight register-tiled combines.
// HARD RULES (accumulated post-mortems):
//  R6/R7: one K-loop (one weight matrix tile) per kernel body — dual-weight
//    loops spill to 256 VGPR + scratch. Fusion via PRE operand, block-range
//    select, or CONCAT-K (stacked weights in ONE LDS tile, one loop).
//  R8: split gathers lower FETCH but not time (latency-bound) — keep fused dual gather.
//  R9 (VERIFIED 73.9-74.2us): gather = one coalesced offset-vector load + __shfl
//    distribution + 8-deep burst of row loads with per-lane masks + ZERO-INIT.
//    The zero-inits are LOAD-LIVENESS ANCHORS (force v0..v7 live together).
//  R10: removing the anchors serializes the burst (74.4 -> 79.6). Gather is
//    memory-request-service bound at ~74us; VALU dieting doesn't move it.
//  R11 (REVERTED): RUNTIME epilogue flags -> VGPR 248, occupancy 10%, 3x
//    regression. Combine polymorphism must be COMPILE-TIME, identical flags
//    on both sides of a block-range pair. Block-range fusion of distinct
//    cold bodies (partition ranges + cast) is safe.
//  R13 (VERIFIED −22us): concat-K layer-2 single pass; pre-gather hoist.
//  R14 (−5us only): label-sorted classifier — hp/hu are L3-resident, so the
//    random classify reads were already cache-absorbed. L3 absorbs latency
//    estimates too, not just FETCH.
//  R15: histogram+scan passes DELETED. Buckets use fixed-slack layout
//    (base = bucket*SLACK, >20-sigma margin on Binomial occupancy); partition
//    allocates via atomic cursors on zeroed counters; CSR keeps gaps (ptr/deg
//    don't need global contiguity). Labels use pow2 slack for shift/mask
//    slot->bucket in classify. Cast folded into partition as a 4th range.

using u16 = unsigned short;
using u32 = unsigned int;

__device__ __forceinline__ u16 bf16r(float f) {            // round-to-nearest-even
    u32 b = __float_as_uint(f);
    b += 0x7fffu + ((b >> 16) & 1u);
    return (u16)(b >> 16);
}
__device__ __forceinline__ float bflo(u32 u) { return __uint_as_float(u << 16); }
__device__ __forceinline__ float bfhi(u32 u) { return __uint_as_float(u & 0xffff0000u); }

#define BSH 8          // bucket = key >> BSH, 256 node ids per bucket
#define MAXB 512       // max buckets per direction (NU=100000 -> 391)
#define CHUNK 4096     // edges per partition block
#define RPT 16         // CHUNK / 256

// ---- fused partition + cast: 4 block ranges.
// [0,pblocks) P edges; [pblocks,2p) U edges; [2p,2p+lblocks) label edges
// (payload = iota); [2p+lblocks,..) cast x_user -> bf16.
// Slack layout: pairs[b*SLACK + atomicAdd(cnt[b], c) ...]. Counters pre-zeroed.
__global__ __launch_bounds__(256) void k_partCast(
    const int* __restrict__ keysP, const int* __restrict__ payP,
    int* __restrict__ curPp, uint2* __restrict__ pairsP, int NBP, int SLP,
    const int* __restrict__ keysU, const int* __restrict__ payU,
    int* __restrict__ curUp, uint2* __restrict__ pairsU, int NBU, int SLU,
    int E, int pblocks,
    const int* __restrict__ keysL,
    int* __restrict__ curLp, uint2* __restrict__ pairsL, int NBL, int SLL,
    int EL, int lblocks,
    const float* __restrict__ xc, u16* __restrict__ yc, int n8) {
    __shared__ int hist[MAXB];
    __shared__ int sA[MAXB];
    __shared__ int sB[MAXB];
    __shared__ int bx[MAXB];
    __shared__ int gbase[MAXB];
    __shared__ uint2 prs[CHUNK];
    int tid = threadIdx.x;
    int bix = blockIdx.x;
    if (bix >= 2 * pblocks + lblocks) {          // ---- cast range ----
        int i = (bix - 2 * pblocks - lblocks) * 256 + tid;
        if (i < n8) {
            const float4* x4 = (const float4*)xc;
            float4 a = x4[i * 2], b = x4[i * 2 + 1];
            uint4 o;
            o.x = (u32)bf16r(a.x) | ((u32)bf16r(a.y) << 16);
            o.y = (u32)bf16r(a.z) | ((u32)bf16r(a.w) << 16);
            o.z = (u32)bf16r(b.x) | ((u32)bf16r(b.y) << 16);
            o.w = (u32)bf16r(b.z) | ((u32)bf16r(b.w) << 16);
            ((uint4*)yc)[i] = o;
        }
        return;
    }
    const int* keys; const int* pay; int* cursor; uint2* pairs;
    int NB, SL, cb, nE;
    if (bix < pblocks) {
        keys = keysP; pay = payP; cursor = curPp; pairs = pairsP; NB = NBP; SL = SLP;
        cb = bix; nE = E;
    } else if (bix < 2 * pblocks) {
        keys = keysU; pay = payU; cursor = curUp; pairs = pairsU; NB = NBU; SL = SLU;
        cb = bix - pblocks; nE = E;
    } else {
        keys = keysL; pay = nullptr; cursor = curLp; pairs = pairsL; NB = NBL; SL = SLL;
        cb = bix - 2 * pblocks; nE = EL;
    }
    int i0 = cb * CHUNK;
    int count = min(CHUNK, nE - i0);
    for (int i = tid; i < MAXB; i += 256) hist[i] = 0;
    __syncthreads();
    int keyr[RPT], payr[RPT], rankr[RPT];
#pragma unroll
    for (int r = 0; r < RPT; ++r) {
        int idx = r * 256 + tid;
        if (idx < count) {
            int k = keys[i0 + idx];
            keyr[r] = k;
            payr[r] = pay ? pay[i0 + idx] : (i0 + idx);
            rankr[r] = atomicAdd(&hist[k >> BSH], 1);
        } else keyr[r] = -1;
    }
    __syncthreads();
    // exclusive scan of per-chunk hist -> bx (ping-pong, 512 wide)
    sA[tid] = hist[tid]; sA[tid + 256] = hist[tid + 256];
    __syncthreads();
    int* src = sA; int* dst = sB;
    for (int off = 1; off < MAXB; off <<= 1) {
        dst[tid] = src[tid] + ((tid >= off) ? src[tid - off] : 0);
        int i2 = tid + 256;
        dst[i2] = src[i2] + ((i2 >= off) ? src[i2 - off] : 0);
        __syncthreads();
        int* t = src; src = dst; dst = t;
    }
    bx[tid] = src[tid] - hist[tid];
    bx[tid + 256] = src[tid + 256] - hist[tid + 256];
    __syncthreads();
    for (int b = tid; b < NB; b += 256) {
        int c = hist[b];
        gbase[b] = c ? (b * SL + atomicAdd(&cursor[b], c)) : 0;
    }
    // stage into LDS in bucket order
#pragma unroll
    for (int r = 0; r < RPT; ++r) {
        if (keyr[r] >= 0)
            prs[bx[keyr[r] >> BSH] + rankr[r]] = make_uint2((u32)keyr[r], (u32)payr[r]);
    }
    __syncthreads();
    // coalesced segment copy-out
    for (int j = tid; j < count; j += 256) {
        uint2 pr = prs[j];
        int b = pr.x >> BSH;
        pairs[gbase[b] + (j - bx[b])] = pr;
    }
}

// ---- per-bucket fine fill -> nbr, deg, ptr(start); both directions fused ----
// Slack layout: bucket region = [bucket*SL, bucket*SL + cnt[bucket]).
// nbr stores BYTE offsets into the 128B-row bf16 tables (id << 7).
__global__ __launch_bounds__(256) void k_bucketFill(
    const uint2* __restrict__ pairsP, const int* __restrict__ cntP, int NBP, int SLP,
    int* __restrict__ nbr_p, int* __restrict__ deg_p, int* __restrict__ ptr_p, int NP,
    const uint2* __restrict__ pairsU, const int* __restrict__ cntU, int NBU, int SLU,
    int* __restrict__ nbr_u, int* __restrict__ deg_u, int* __restrict__ ptr_u, int NU) {
    const uint2* pairs; const int* cntA; int* nbr; int* deg; int* ptr;
    int N, SL, bucket;
    if ((int)blockIdx.x < NBP) {
        pairs = pairsP; cntA = cntP; nbr = nbr_p; deg = deg_p; ptr = ptr_p; N = NP;
        SL = SLP; bucket = blockIdx.x;
    } else {
        pairs = pairsU; cntA = cntU; nbr = nbr_u; deg = deg_u; ptr = ptr_u; N = NU;
        SL = SLU; bucket = blockIdx.x - NBP;
    }
    int tid = threadIdx.x;
    int base = bucket * SL;
    int cnt = cntA[bucket];
    __shared__ int h[256];
    __shared__ int s[256];
    __shared__ int cur[256];
    h[tid] = 0;
    __syncthreads();
    for (int j = tid; j < cnt; j += 256) atomicAdd(&h[pairs[base + j].x & 255], 1);
    __syncthreads();
    int d = h[tid];
    s[tid] = d;
    __syncthreads();
    for (int off = 1; off < 256; off <<= 1) {
        int v = (tid >= off) ? s[tid - off] : 0;
        __syncthreads();
        s[tid] += v;
        __syncthreads();
    }
    int excl = s[tid] - d;
    int node = bucket * 256 + tid;
    if (node < N) { deg[node] = d; ptr[node] = base + excl; }
    cur[tid] = excl;
    __syncthreads();
    for (int j = tid; j < cnt; j += 256) {
        uint2 pr = pairs[base + j];
        int pos = atomicAdd(&cur[pr.x & 255], 1);
        nbr[base + pos] = (int)(pr.y << 7);     // byte offset of row (128B rows)
    }
}

#define ACC8(A0,A1,A2,A3,A4,A5,A6,A7,V) \
    A0 += bflo((V).x); A1 += bfhi((V).x); A2 += bflo((V).y); A3 += bfhi((V).y); \
    A4 += bflo((V).z); A5 += bfhi((V).z); A6 += bflo((V).w); A7 += bfhi((V).w);

// ------- fused dual gather-mean: nodes [0,NA) CSR A, [NA,NA+NB) CSR B -------
// wave per node; 8 lanes per bf16 row (uint4). R9 shape — do not restructure.
__global__ __launch_bounds__(256) void k_gather2(
    const u16* __restrict__ yA, const int* __restrict__ nbrA, const int* __restrict__ stpA,
    const int* __restrict__ degA, float* __restrict__ aggA, int NA,
    const u16* __restrict__ yB, const int* __restrict__ nbrB, const int* __restrict__ stpB,
    const int* __restrict__ degB, float* __restrict__ aggB, int NB) {
    int w = (blockIdx.x * 256 + threadIdx.x) >> 6;
    int lane = threadIdx.x & 63;
    if (w >= NA + NB) return;
    const u16* y; const int* nbr; const int* stp; const int* deg; float* agg; int n;
    if (w < NA) { y = yA; nbr = nbrA; stp = stpA; deg = degA; agg = aggA; n = w; }
    else        { y = yB; nbr = nbrB; stp = stpB; deg = degB; agg = aggB; n = w - NA; }
    const int q = lane >> 3, t = lane & 7;
    const int d = deg[n];
    const int st = stp[n];
    const char* yb = (const char*)y + t * 16;
    float a0=0,a1=0,a2=0,a3=0,a4=0,a5=0,a6=0,a7=0;
    for (int j = 0; j < d; j += 64) {
        const int cnt = min(d - j, 64);           // wave-uniform
        int offv = 0;
        if (lane < cnt) offv = nbr[st + j + lane];   // one coalesced 256B load
        // distribute + burst-issue all row loads (independent, exec-masked tails)
#define GLD(R) \
        int g##R = __shfl(offv, R * 8 + q, 64); \
        uint4 v##R = make_uint4(0u, 0u, 0u, 0u); \
        if (R * 8 + q < cnt) v##R = *(const uint4*)(yb + g##R);
        GLD(0) GLD(1) GLD(2) GLD(3) GLD(4) GLD(5) GLD(6) GLD(7)
#undef GLD
        // accumulate (rounds beyond cnt are uniform-skipped; masked lanes hold 0)
#define ACCR(R) if (R * 8 < cnt) { ACC8(a0,a1,a2,a3,a4,a5,a6,a7,v##R) }
        ACCR(0) ACCR(1) ACCR(2) ACCR(3) ACCR(4) ACCR(5) ACCR(6) ACCR(7)
#undef ACCR
    }
#pragma unroll
    for (int m = 8; m < 64; m <<= 1) {
        a0 += __shfl_xor(a0, m, 64); a1 += __shfl_xor(a1, m, 64);
        a2 += __shfl_xor(a2, m, 64); a3 += __shfl_xor(a3, m, 64);
        a4 += __shfl_xor(a4, m, 64); a5 += __shfl_xor(a5, m, 64);
        a6 += __shfl_xor(a6, m, 64); a7 += __shfl_xor(a7, m, 64);
    }
    if (q == 0) {
        float dinv = 1.0f / (float)max(d, 1);
        float* dstp = agg + n * 64 + t * 8;
        *(float4*)dstp       = make_float4(a0 * dinv, a1 * dinv, a2 * dinv, a3 * dinv);
        *(float4*)(dstp + 4) = make_float4(a4 * dinv, a5 * dinv, a6 * dinv, a7 * dinv);
    }
}

#define FMA_ROW(ACC, O, W4) \
    ACC[0] += (O) * (W4).x; ACC[1] += (O) * (W4).y; \
    ACC[2] += (O) * (W4).z; ACC[3] += (O) * (W4).w;

// ======= paired combine: two independent K-dim problems, block-range selected =======
// COMPILE-TIME flags, IDENTICAL for both sides (R11 rule). Single K-loop body.
// h = act((PRE?pre:0) + (BIAS?b:0) + x@W); always STORE; optional RELU + EMIT.
template <int K, bool PRE, bool BIAS, bool RELU, bool EMIT>
__global__ __launch_bounds__(256) void k_ctilePairX(
    const float* __restrict__ pre0, const float* __restrict__ bias0,
    const float* __restrict__ x0, const float* __restrict__ W0,
    float* __restrict__ h0, u16* __restrict__ hbf0, int N0, int g0,
    const float* __restrict__ pre1, const float* __restrict__ bias1,
    const float* __restrict__ x1, const float* __restrict__ W1,
    float* __restrict__ h1, u16* __restrict__ hbf1, int N1) {
    constexpr int ROWS = (K == 64) ? 64 : 32;
    constexpr int RR = ROWS / 16;
    constexpr int STRIDE = K + 4;
    constexpr int KF4 = K / 4;
    __shared__ float Ws[K * 64];
    __shared__ float op[ROWS * STRIDE];
    const float* pre; const float* bias; const float* x; const float* W;
    float* h; u16* hbf;
    int N, bid, gsz;
    if ((int)blockIdx.x < g0) {
        pre = pre0; bias = bias0; x = x0; W = W0; h = h0; hbf = hbf0; N = N0;
        bid = blockIdx.x; gsz = g0;
    } else {
        pre = pre1; bias = bias1; x = x1; W = W1; h = h1; hbf = hbf1; N = N1;
        bid = blockIdx.x - g0; gsz = gridDim.x - g0;
    }
    const int tid = threadIdx.x;
    for (int i = tid; i < K * 16; i += 256)
        ((float4*)Ws)[i] = ((const float4*)W)[i];
    const int c4 = (tid & 15) * 4;
    const int rb = (tid >> 4) * RR;
    float bx_ = 0.f, by_ = 0.f, bz_ = 0.f, bw_ = 0.f;
    if (BIAS) {
        float4 b4 = *(const float4*)(bias + c4);
        bx_ = b4.x; by_ = b4.y; bz_ = b4.z; bw_ = b4.w;
    }
    const int ntiles = (N + ROWS - 1) / ROWS;
    for (int tile = bid; tile < ntiles; tile += gsz) {
        const int row0 = tile * ROWS;
        __syncthreads();
        for (int i = tid; i < ROWS * KF4; i += 256) {
            int r = i / KF4, k4 = (i % KF4) * 4;
            int row = row0 + r;
            float4 v = make_float4(0.f, 0.f, 0.f, 0.f);
            if (row < N) v = *(const float4*)(x + (size_t)row * K + k4);
            *(float4*)(op + r * STRIDE + k4) = v;
        }
        __syncthreads();
        float acc[RR][4];
#pragma unroll
        for (int i = 0; i < RR; ++i) {
            float px = 0.f, py = 0.f, pz = 0.f, pw = 0.f;
            if (PRE) {
                int row = row0 + rb + i;
                if (row < N) {
                    float4 p = *(const float4*)(pre + row * 64 + c4);
                    px = p.x; py = p.y; pz = p.z; pw = p.w;
                }
            }
            acc[i][0] = bx_ + px; acc[i][1] = by_ + py;
            acc[i][2] = bz_ + pz; acc[i][3] = bw_ + pw;
        }
        for (int kk = 0; kk < K; kk += 4) {
            float4 w0 = *(const float4*)(Ws + (kk + 0) * 64 + c4);
            float4 w1 = *(const float4*)(Ws + (kk + 1) * 64 + c4);
            float4 w2 = *(const float4*)(Ws + (kk + 2) * 64 + c4);
            float4 w3 = *(const float4*)(Ws + (kk + 3) * 64 + c4);
#pragma unroll
            for (int i = 0; i < RR; ++i) {
                float4 o = *(const float4*)(op + (rb + i) * STRIDE + kk);
                FMA_ROW(acc[i], o.x, w0);
                FMA_ROW(acc[i], o.y, w1);
                FMA_ROW(acc[i], o.z, w2);
                FMA_ROW(acc[i], o.w, w3);
            }
        }
#pragma unroll
        for (int i = 0; i < RR; ++i) {
            int row = row0 + rb + i;
            if (row >= N) continue;
            float v0 = acc[i][0], v1 = acc[i][1], v2 = acc[i][2], v3 = acc[i][3];
            if (RELU) {
                v0 = fmaxf(v0, 0.f); v1 = fmaxf(v1, 0.f);
                v2 = fmaxf(v2, 0.f); v3 = fmaxf(v3, 0.f);
            }
            *(float4*)(h + row * 64 + c4) = make_float4(v0, v1, v2, v3);
            if (EMIT) {
                uint2 o;
                o.x = (u32)bf16r(v0) | ((u32)bf16r(v1) << 16);
                o.y = (u32)bf16r(v2) | ((u32)bf16r(v3) << 16);
                *(uint2*)(hbf + row * 64 + c4) = o;
            }
        }
    }
}

// ======= paired CONCAT combine: h = bias + [xa|xb] @ [Wa;Wb], K=128 =======
// ONE K-loop, ONE LDS weight tile (filled from two 64x64 sources).
template <bool BIAS>
__global__ __launch_bounds__(256) void k_ctilePairCat(
    const float* __restrict__ bias0, const float* __restrict__ xa0,
    const float* __restrict__ xb0, const float* __restrict__ Wa0,
    const float* __restrict__ Wb0, float* __restrict__ h0, int N0, int g0,
    const float* __restrict__ bias1, const float* __restrict__ xa1,
    const float* __restrict__ xb1, const float* __restrict__ Wa1,
    const float* __restrict__ Wb1, float* __restrict__ h1, int N1) {
    constexpr int ROWS = 32, RR = 2, STRIDE = 132, KF4 = 32;
    __shared__ float Ws[128 * 64];
    __shared__ float op[ROWS * STRIDE];
    const float* bias; const float* xa; const float* xb;
    const float* Wa; const float* Wb; float* h;
    int N, bid, gsz;
    if ((int)blockIdx.x < g0) {
        bias = bias0; xa = xa0; xb = xb0; Wa = Wa0; Wb = Wb0; h = h0; N = N0;
        bid = blockIdx.x; gsz = g0;
    } else {
        bias = bias1; xa = xa1; xb = xb1; Wa = Wa1; Wb = Wb1; h = h1; N = N1;
        bid = blockIdx.x - g0; gsz = gridDim.x - g0;
    }
    const int tid = threadIdx.x;
    for (int i = tid; i < 64 * 16; i += 256) {
        ((float4*)Ws)[i]           = ((const float4*)Wa)[i];
        ((float4*)Ws)[64 * 16 + i] = ((const float4*)Wb)[i];
    }
    const int c4 = (tid & 15) * 4;
    const int rb = (tid >> 4) * RR;
    float bx_ = 0.f, by_ = 0.f, bz_ = 0.f, bw_ = 0.f;
    if (BIAS) {
        float4 b4 = *(const float4*)(bias + c4);
        bx_ = b4.x; by_ = b4.y; bz_ = b4.z; bw_ = b4.w;
    }
    const int ntiles = (N + ROWS - 1) / ROWS;
    for (int tile = bid; tile < ntiles; tile += gsz) {
        const int row0 = tile * ROWS;
        __syncthreads();
        for (int i = tid; i < ROWS * KF4; i += 256) {
            int r = i >> 5, k4 = (i & 31) * 4;
            int row = row0 + r;
            float4 v = make_float4(0.f, 0.f, 0.f, 0.f);
            if (row < N)
                v = (k4 < 64) ? *(const float4*)(xa + (size_t)row * 64 + k4)
                              : *(const float4*)(xb + (size_t)row * 64 + (k4 - 64));
            *(float4*)(op + r * STRIDE + k4) = v;
        }
        __syncthreads();
        float acc[RR][4];
#pragma unroll
        for (int i = 0; i < RR; ++i) {
            acc[i][0] = bx_; acc[i][1] = by_; acc[i][2] = bz_; acc[i][3] = bw_;
        }
        for (int kk = 0; kk < 128; kk += 4) {
            float4 w0 = *(const float4*)(Ws + (kk + 0) * 64 + c4);
            float4 w1 = *(const float4*)(Ws + (kk + 1) * 64 + c4);
            float4 w2 = *(const float4*)(Ws + (kk + 2) * 64 + c4);
            float4 w3 = *(const float4*)(Ws + (kk + 3) * 64 + c4);
#pragma unroll
            for (int i = 0; i < RR; ++i) {
                float4 o = *(const float4*)(op + (rb + i) * STRIDE + kk);
                FMA_ROW(acc[i], o.x, w0);
                FMA_ROW(acc[i], o.y, w1);
                FMA_ROW(acc[i], o.z, w2);
                FMA_ROW(acc[i], o.w, w3);
            }
        }
#pragma unroll
        for (int i = 0; i < RR; ++i) {
            int row = row0 + rb + i;
            if (row >= N) continue;
            *(float4*)(h + row * 64 + c4) =
                make_float4(acc[i][0], acc[i][1], acc[i][2], acc[i][3]);
        }
    }
}

// ------- sorted classifier over slack layout: slot -> (bucket=slot>>lsh,
// within=slot&(SLL-1)); valid iff within < cntL[bucket]. pairsL = (p, e). -------
__global__ __launch_bounds__(256) void k_classifyS(const float* __restrict__ hu,
                                                   const float* __restrict__ hp,
                                                   const int* __restrict__ lu,
                                                   const uint2* __restrict__ pairsL,
                                                   const int* __restrict__ cntL,
                                                   int lsh,
                                                   float* __restrict__ out, int nslots) {
    int w = (blockIdx.x * 256 + threadIdx.x) >> 6;
    int lane = threadIdx.x & 63;
    int q = lane >> 4, t = lane & 15;
    int slot = w * 4 + q;
    float v = 0.f;
    int e = 0;
    bool ok = false;
    if (slot < nslots) {
        int bucket = slot >> lsh;
        int within = slot & ((1 << lsh) - 1);
        if (within < cntL[bucket]) {
            uint2 pr = pairsL[slot];
            int p = (int)pr.x;
            e = (int)pr.y;
            int u = lu[e];
            float4 a = *(const float4*)(hu + (size_t)u * 64 + t * 4);
            float4 b = *(const float4*)(hp + (size_t)p * 64 + t * 4);
            v = a.x * b.x + a.y * b.y + a.z * b.z + a.w * b.w;
            ok = true;
        }
    }
#pragma unroll
    for (int m = 1; m < 16; m <<= 1) v += __shfl_xor(v, m, 64);
    if (t == 0 && ok) out[e] = v;
}

extern "C" void kernel_launch(void* const* d_in, const int* in_sizes, int n_in,
                              void* d_out, int out_size, void* d_ws, size_t ws_size,
                              hipStream_t stream) {
    const float* x_user    = (const float*)d_in[0];
    const float* x_product = (const float*)d_in[1];
    const float* W1bl = (const float*)d_in[2];
    const float* b1b  = (const float*)d_in[3];
    const float* W1br = (const float*)d_in[4];
    const float* W1rl = (const float*)d_in[5];
    const float* b1r  = (const float*)d_in[6];
    const float* W1rr = (const float*)d_in[7];
    const float* W2bl = (const float*)d_in[8];
    const float* b2b  = (const float*)d_in[9];
    const float* W2br = (const float*)d_in[10];
    const float* W2rl = (const float*)d_in[11];
    const float* b2r  = (const float*)d_in[12];
    const float* W2rr = (const float*)d_in[13];
    const int* esrc = (const int*)d_in[14];
    const int* edst = (const int*)d_in[15];
    const int* lu   = (const int*)d_in[16];
    const int* lp   = (const int*)d_in[17];

    const int NU = in_sizes[0] / 64;
    const int NP = in_sizes[1] / 128;
    const int E  = in_sizes[14];
    const int EL = in_sizes[16];
    const int NBP = (NP + 255) >> BSH;
    const int NBU = (NU + 255) >> BSH;
    const int NBL = NBP;                        // lab_p keys share the P id space

    // ---- slack sizes: mean + mean/8 + 1024 (>20 sigma for Binomial buckets) ----
    const int SLP = E / NBP + E / (NBP * 8) + 1024;
    const int SLU = E / NBU + E / (NBU * 8) + 1024;
    int lneed = EL / NBL + EL / (NBL * 4) + 512;
    int lsh = 1;
    while ((1 << lsh) < lneed) ++lsh;           // pow2 slack for labels (4096 here)
    const int SLL = 1 << lsh;

    // ---- workspace layout ----
    char* ws = (char*)d_ws;
    size_t off = 0;
    auto alloc = [&](size_t bytes) -> void* {
        void* p = ws + off;
        off += (bytes + 255) & ~(size_t)255;
        return p;
    };
    int*   deg_u  = (int*)alloc((size_t)NU * 4);
    int*   deg_p  = (int*)alloc((size_t)NP * 4);
    int*   ptr_u  = (int*)alloc((size_t)NU * 4);
    int*   ptr_p  = (int*)alloc((size_t)NP * 4);
    int*   curP   = (int*)alloc((size_t)MAXB * 4);   // P,U,L contiguous: one memset
    int*   curU   = (int*)alloc((size_t)MAXB * 4);
    int*   curL   = (int*)alloc((size_t)MAXB * 4);
    int*   nbr_u  = (int*)alloc((size_t)NBU * SLU * 4);
    int*   nbr_p  = (int*)alloc((size_t)NBP * SLP * 4);
    uint2* pairsL = (uint2*)alloc((size_t)NBL * SLL * 8);  // survives until classify
    // union region: pairs (CSR build) then agg (gather onward)
    size_t aggBytes = (size_t)(NP + NU) * 64 * 4;
    size_t pairBytes = ((size_t)NBP * SLP + (size_t)NBU * SLU) * 8;
    char* uni = (char*)alloc(aggBytes > pairBytes ? aggBytes : pairBytes);
    float* aggP   = (float*)uni;
    float* aggU   = (float*)(uni + (size_t)NP * 64 * 4);
    uint2* pairsP = (uint2*)uni;
    uint2* pairsU = (uint2*)(uni + (size_t)NBP * SLP * 8);
    u16*   bfA    = (u16*)alloc((size_t)NU * 64 * 2);  // x_user_bf, then h_u_bf
    u16*   bfB    = (u16*)alloc((size_t)NP * 64 * 2);  // y_p1_bf,  then h_p_bf
    float* h_p    = (float*)alloc((size_t)NP * 64 * 4);
    float* h_u    = (float*)alloc((size_t)NU * 64 * 4);
    // pre-gather dead-write sinks (h_u not yet live: fully overwritten later)
    float* sinkF  = h_u;                               // NP*64*4 = 12.8MB
    u16*   sinkB  = (u16*)((char*)h_u + (size_t)NP * 64 * 4);  // 6.4MB more

    // ---- CSR build + label sort: single fused partition pass (no hist/scan) ----
    hipMemsetAsync(curP, 0, (size_t)MAXB * 3 * 4, stream);  // P,U,L contiguous
    const int n8 = NU * 64 / 8;
    const int castBlocks = (n8 + 255) / 256;
    const int pblocks = (E + CHUNK - 1) / CHUNK;
    const int lblocks = (EL + CHUNK - 1) / CHUNK;
    k_partCast<<<2 * pblocks + lblocks + castBlocks, 256, 0, stream>>>(
        edst, esrc, curP, pairsP, NBP, SLP,
        esrc, edst, curU, pairsU, NBU, SLU, E, pblocks,
        lp, curL, pairsL, NBL, SLL, EL, lblocks,
        x_user, bfA, n8);
    k_bucketFill<<<NBP + NBU, 256, 0, stream>>>(
        pairsP, curP, NBP, SLP, nbr_p, deg_p, ptr_p, NP,
        pairsU, curU, NBU, SLU, nbr_u, deg_u, ptr_u, NU);

    const int tP32 = (NP + 31) / 32;
    const int tU32 = (NU + 31) / 32;
    const int tP64 = (NP + 63) / 64, tU64 = (NU + 63) / 64;
    auto cap = [](int t, int c) { return t < c ? t : c; };

    // ---- pre-gather combines, ONE paired launch (identical flags both sides):
    // side0: bfB = bf16(x_product@W1rl)   (fp32 store -> sinkF, dead)
    // side1: h_p = x_product@W1br         (bf16 emit -> sinkB, dead)
    {
        const int g0 = cap(tP32, 768);
        k_ctilePairX<128, false, false, false, true><<<g0 + cap(tP32, 768), 256, 0, stream>>>(
            nullptr, nullptr, x_product, W1rl, sinkF, bfB, NP, g0,
            nullptr, nullptr, x_product, W1br, h_p, sinkB, NP);
    }

    // ---- layer 1: fused dual gather, then ONE paired combine ----
    k_gather2<<<(NP + NU + 3) / 4, 256, 0, stream>>>(bfA, nbr_p, ptr_p, deg_p, aggP, NP,
                                                     bfB, nbr_u, ptr_u, deg_u, aggU, NU);
    // side0: h_p = relu(h_p + b1b + aggP@W1bl), emit bfB
    // side1: h_u = relu(aggU + b1r + x_user@W1rr), emit bfA
    {
        const int gP = cap(tP64, 512), gU = cap(tU64, 1024);
        k_ctilePairX<64, true, true, true, true><<<gP + gU, 256, 0, stream>>>(
            h_p, b1b, aggP, W1bl, h_p, bfB, NP, gP,
            aggU, b1r, x_user, W1rr, h_u, bfA, NU);
    }

    // ---- layer 2: fused dual gather, then ONE concat-K combine ----
    k_gather2<<<(NP + NU + 3) / 4, 256, 0, stream>>>(bfA, nbr_p, ptr_p, deg_p, aggP, NP,
                                                     bfB, nbr_u, ptr_u, deg_u, aggU, NU);
    // side0: h_p = b2b + [aggP|h_p] @ [W2bl;W2br]
    // side1: h_u = b2r + [aggU|h_u] @ [W2rl;W2rr]
    {
        const int gP = cap(tP32, 512), gU = cap(tU32, 1024);
        k_ctilePairCat<true><<<gP + gU, 256, 0, stream>>>(
            b2b, aggP, h_p, W2bl, W2br, h_p, NP, gP,
            b2r, aggU, h_u, W2rl, W2rr, h_u, NU);
    }

    // ---- classifier over p-sorted label pairs (slack layout) ----
    const int nslots = NBL << lsh;
    k_classifyS<<<((nslots + 3) / 4 + 3) / 4, 256, 0, stream>>>(
        h_u, h_p, lu, pairsL, curL, lsh, (float*)d_out, nslots);
}

// Round 8
// 481.229 us; speedup vs baseline: 1.3364x; 1.0017x over previous
//
#include <hip/hip_runtime.h>

// 2-layer hetero GraphSAGE, fp32 compute, bf16 gather tables, bucketed CSR build,
// persistent-weight register-tiled combines.
// HARD RULES (accumulated post-mortems):
//  R6/R7: one K-loop (one weight matrix tile) per kernel body — dual-weight
//    loops spill to 256 VGPR + scratch. Fusion via PRE operand, block-range
//    select, or CONCAT-K (stacked weights in ONE LDS tile, one loop).
//  R8: split gathers lower FETCH but not time (latency-bound) — keep fused dual gather.
//  R9 (VERIFIED 73.9-74.3us): gather = one coalesced offset-vector load + __shfl
//    distribution + 8-deep burst of row loads with per-lane masks + ZERO-INIT.
//    The zero-inits are LOAD-LIVENESS ANCHORS (force v0..v7 live together).
//  R10: removing the anchors serializes the burst (74.4 -> 79.6). Gather is
//    memory-request-service + VALU-issue co-limited; load section is frozen.
//  R11 (REVERTED): RUNTIME epilogue flags -> VGPR 248, occupancy 10%, 3x
//    regression. Combine polymorphism must be COMPILE-TIME, identical flags
//    on both sides of a block-range pair. Block-range fusion of distinct
//    cold bodies (partition ranges + cast + ctile) is safe.
//  R13 (VERIFIED −22us): concat-K layer-2 single pass; pre-gather hoist.
//  R14 (−5us only): label-sorted classifier — hp/hu are L3-resident.
//  R15 (VERIFIED −10us): histogram+scan DELETED; fixed-slack bucket layout.
//  R16: (a) gather ACC section only: float2 accumulators + pair unpack so the
//    two adds per dword fuse to v_pk_add_f32 (ACC 16->12 ops/uint4); GLD
//    section untouched. (b) pre-gather K=128 combine folded into k_partCast
//    as block ranges 5-6 (unioned LDS 49.7KB, compile-time-identical sides) —
//    overlaps it with partition instead of serializing.

using u16 = unsigned short;
using u32 = unsigned int;

__device__ __forceinline__ u16 bf16r(float f) {            // round-to-nearest-even
    u32 b = __float_as_uint(f);
    b += 0x7fffu + ((b >> 16) & 1u);
    return (u16)(b >> 16);
}
__device__ __forceinline__ float2 bfup(u32 u) {            // (lo,hi) bf16 -> f32 pair
    return make_float2(__uint_as_float(u << 16), __uint_as_float(u & 0xffff0000u));
}

#define BSH 8          // bucket = key >> BSH, 256 node ids per bucket
#define MAXB 512       // max buckets per direction (NU=100000 -> 391)
#define CHUNK 4096     // edges per partition block
#define RPT 16         // CHUNK / 256

#define FMA_ROW(ACC, O, W4) \
    ACC[0] += (O) * (W4).x; ACC[1] += (O) * (W4).y; \
    ACC[2] += (O) * (W4).z; ACC[3] += (O) * (W4).w;

// ---- fused partition + cast + pre-gather ctile: 6 block ranges.
// [0,p) P edges; [p,2p) U edges; [2p,2p+l) label edges (payload = iota);
// [2p+l,ctStart) cast x_user -> bf16;
// [ctStart,ctStart+g128) ctile side0: bfB = bf16(xp@Wrl), fp32 -> sinkF (dead);
// [ctStart+g128,ctStart+2*g128) ctile side1: h_p = xp@Wbr, bf16 -> sinkB (dead).
// LDS explicitly unioned: partition 43.0KB | ctile 49.7KB -> 49.7KB.
__global__ __launch_bounds__(256) void k_partCast(
    const int* __restrict__ keysP, const int* __restrict__ payP,
    int* __restrict__ curPp, uint2* __restrict__ pairsP, int NBP, int SLP,
    const int* __restrict__ keysU, const int* __restrict__ payU,
    int* __restrict__ curUp, uint2* __restrict__ pairsU, int NBU, int SLU,
    int E, int pblocks,
    const int* __restrict__ keysL,
    int* __restrict__ curLp, uint2* __restrict__ pairsL, int NBL, int SLL,
    int EL, int lblocks,
    const float* __restrict__ xc, u16* __restrict__ yc, int n8,
    int ctStart, int g128,
    const float* __restrict__ xp, const float* __restrict__ Wrl,
    const float* __restrict__ Wbr, u16* __restrict__ bfB,
    float* __restrict__ h_p, float* __restrict__ sinkF,
    u16* __restrict__ sinkB, int NPc) {
    __shared__ __align__(16) char smem[49664];
    int tid = threadIdx.x;
    int bix = blockIdx.x;
    if (bix >= ctStart) {                        // ---- ctile ranges (5,6) ----
        float* Ws = (float*)smem;                // 128*64 floats = 32768 B
        float* op = (float*)(smem + 32768);      // 32*132 floats = 16896 B
        int cbix = bix - ctStart;
        const float* W; float* h; u16* hbf;
        int bid;
        if (cbix < g128) { W = Wrl; h = sinkF; hbf = bfB;   bid = cbix; }
        else             { W = Wbr; h = h_p;   hbf = sinkB; bid = cbix - g128; }
        for (int i = tid; i < 128 * 16; i += 256)
            ((float4*)Ws)[i] = ((const float4*)W)[i];
        const int c4 = (tid & 15) * 4;
        const int rb = (tid >> 4) * 2;
        const int ntiles = (NPc + 31) / 32;
        for (int tile = bid; tile < ntiles; tile += g128) {
            const int row0 = tile * 32;
            __syncthreads();
            for (int i = tid; i < 32 * 32; i += 256) {
                int r = i >> 5, k4 = (i & 31) * 4;
                int row = row0 + r;
                float4 v = make_float4(0.f, 0.f, 0.f, 0.f);
                if (row < NPc) v = *(const float4*)(xp + (size_t)row * 128 + k4);
                *(float4*)(op + r * 132 + k4) = v;
            }
            __syncthreads();
            float acc[2][4];
#pragma unroll
            for (int i = 0; i < 2; ++i) {
                acc[i][0] = 0.f; acc[i][1] = 0.f; acc[i][2] = 0.f; acc[i][3] = 0.f;
            }
            for (int kk = 0; kk < 128; kk += 4) {
                float4 w0 = *(const float4*)(Ws + (kk + 0) * 64 + c4);
                float4 w1 = *(const float4*)(Ws + (kk + 1) * 64 + c4);
                float4 w2 = *(const float4*)(Ws + (kk + 2) * 64 + c4);
                float4 w3 = *(const float4*)(Ws + (kk + 3) * 64 + c4);
#pragma unroll
                for (int i = 0; i < 2; ++i) {
                    float4 o = *(const float4*)(op + (rb + i) * 132 + kk);
                    FMA_ROW(acc[i], o.x, w0);
                    FMA_ROW(acc[i], o.y, w1);
                    FMA_ROW(acc[i], o.z, w2);
                    FMA_ROW(acc[i], o.w, w3);
                }
            }
#pragma unroll
            for (int i = 0; i < 2; ++i) {
                int row = row0 + rb + i;
                if (row >= NPc) continue;
                float v0 = acc[i][0], v1 = acc[i][1], v2 = acc[i][2], v3 = acc[i][3];
                *(float4*)(h + (size_t)row * 64 + c4) = make_float4(v0, v1, v2, v3);
                uint2 o;
                o.x = (u32)bf16r(v0) | ((u32)bf16r(v1) << 16);
                o.y = (u32)bf16r(v2) | ((u32)bf16r(v3) << 16);
                *(uint2*)(hbf + (size_t)row * 64 + c4) = o;
            }
        }
        return;
    }
    if (bix >= 2 * pblocks + lblocks) {          // ---- cast range (4) ----
        int i = (bix - 2 * pblocks - lblocks) * 256 + tid;
        if (i < n8) {
            const float4* x4 = (const float4*)xc;
            float4 a = x4[i * 2], b = x4[i * 2 + 1];
            uint4 o;
            o.x = (u32)bf16r(a.x) | ((u32)bf16r(a.y) << 16);
            o.y = (u32)bf16r(a.z) | ((u32)bf16r(a.w) << 16);
            o.z = (u32)bf16r(b.x) | ((u32)bf16r(b.y) << 16);
            o.w = (u32)bf16r(b.z) | ((u32)bf16r(b.w) << 16);
            ((uint4*)yc)[i] = o;
        }
        return;
    }
    // ---- partition ranges (1-3) ----
    int* hist   = (int*)smem;                    // 512 ints
    int* sA     = (int*)(smem + 2048);
    int* sB     = (int*)(smem + 4096);
    int* bx     = (int*)(smem + 6144);
    int* gbase  = (int*)(smem + 8192);
    uint2* prs  = (uint2*)(smem + 10240);        // 4096 uint2 = 32768 B
    const int* keys; const int* pay; int* cursor; uint2* pairs;
    int NB, SL, cb, nE;
    if (bix < pblocks) {
        keys = keysP; pay = payP; cursor = curPp; pairs = pairsP; NB = NBP; SL = SLP;
        cb = bix; nE = E;
    } else if (bix < 2 * pblocks) {
        keys = keysU; pay = payU; cursor = curUp; pairs = pairsU; NB = NBU; SL = SLU;
        cb = bix - pblocks; nE = E;
    } else {
        keys = keysL; pay = nullptr; cursor = curLp; pairs = pairsL; NB = NBL; SL = SLL;
        cb = bix - 2 * pblocks; nE = EL;
    }
    int i0 = cb * CHUNK;
    int count = min(CHUNK, nE - i0);
    for (int i = tid; i < MAXB; i += 256) hist[i] = 0;
    __syncthreads();
    int keyr[RPT], payr[RPT], rankr[RPT];
#pragma unroll
    for (int r = 0; r < RPT; ++r) {
        int idx = r * 256 + tid;
        if (idx < count) {
            int k = keys[i0 + idx];
            keyr[r] = k;
            payr[r] = pay ? pay[i0 + idx] : (i0 + idx);
            rankr[r] = atomicAdd(&hist[k >> BSH], 1);
        } else keyr[r] = -1;
    }
    __syncthreads();
    // exclusive scan of per-chunk hist -> bx (ping-pong, 512 wide)
    sA[tid] = hist[tid]; sA[tid + 256] = hist[tid + 256];
    __syncthreads();
    int* src = sA; int* dst = sB;
    for (int off = 1; off < MAXB; off <<= 1) {
        dst[tid] = src[tid] + ((tid >= off) ? src[tid - off] : 0);
        int i2 = tid + 256;
        dst[i2] = src[i2] + ((i2 >= off) ? src[i2 - off] : 0);
        __syncthreads();
        int* t = src; src = dst; dst = t;
    }
    bx[tid] = src[tid] - hist[tid];
    bx[tid + 256] = src[tid + 256] - hist[tid + 256];
    __syncthreads();
    for (int b = tid; b < NB; b += 256) {
        int c = hist[b];
        gbase[b] = c ? (b * SL + atomicAdd(&cursor[b], c)) : 0;
    }
    // stage into LDS in bucket order
#pragma unroll
    for (int r = 0; r < RPT; ++r) {
        if (keyr[r] >= 0)
            prs[bx[keyr[r] >> BSH] + rankr[r]] = make_uint2((u32)keyr[r], (u32)payr[r]);
    }
    __syncthreads();
    // coalesced segment copy-out
    for (int j = tid; j < count; j += 256) {
        uint2 pr = prs[j];
        int b = pr.x >> BSH;
        pairs[gbase[b] + (j - bx[b])] = pr;
    }
}

// ---- per-bucket fine fill -> nbr, deg, ptr(start); both directions fused ----
// Slack layout: bucket region = [bucket*SL, bucket*SL + cnt[bucket]).
// nbr stores BYTE offsets into the 128B-row bf16 tables (id << 7).
__global__ __launch_bounds__(256) void k_bucketFill(
    const uint2* __restrict__ pairsP, const int* __restrict__ cntP, int NBP, int SLP,
    int* __restrict__ nbr_p, int* __restrict__ deg_p, int* __restrict__ ptr_p, int NP,
    const uint2* __restrict__ pairsU, const int* __restrict__ cntU, int NBU, int SLU,
    int* __restrict__ nbr_u, int* __restrict__ deg_u, int* __restrict__ ptr_u, int NU) {
    const uint2* pairs; const int* cntA; int* nbr; int* deg; int* ptr;
    int N, SL, bucket;
    if ((int)blockIdx.x < NBP) {
        pairs = pairsP; cntA = cntP; nbr = nbr_p; deg = deg_p; ptr = ptr_p; N = NP;
        SL = SLP; bucket = blockIdx.x;
    } else {
        pairs = pairsU; cntA = cntU; nbr = nbr_u; deg = deg_u; ptr = ptr_u; N = NU;
        SL = SLU; bucket = blockIdx.x - NBP;
    }
    int tid = threadIdx.x;
    int base = bucket * SL;
    int cnt = cntA[bucket];
    __shared__ int h[256];
    __shared__ int s[256];
    __shared__ int cur[256];
    h[tid] = 0;
    __syncthreads();
    for (int j = tid; j < cnt; j += 256) atomicAdd(&h[pairs[base + j].x & 255], 1);
    __syncthreads();
    int d = h[tid];
    s[tid] = d;
    __syncthreads();
    for (int off = 1; off < 256; off <<= 1) {
        int v = (tid >= off) ? s[tid - off] : 0;
        __syncthreads();
        s[tid] += v;
        __syncthreads();
    }
    int excl = s[tid] - d;
    int node = bucket * 256 + tid;
    if (node < N) { deg[node] = d; ptr[node] = base + excl; }
    cur[tid] = excl;
    __syncthreads();
    for (int j = tid; j < cnt; j += 256) {
        uint2 pr = pairs[base + j];
        int pos = atomicAdd(&cur[pr.x & 255], 1);
        nbr[base + pos] = (int)(pr.y << 7);     // byte offset of row (128B rows)
    }
}

// R16: float2 accumulators — the two adds per dword fuse to v_pk_add_f32.
#define ACC8(A01,A23,A45,A67,V) \
    A01 += bfup((V).x); A23 += bfup((V).y); A45 += bfup((V).z); A67 += bfup((V).w);

// ------- fused dual gather-mean: nodes [0,NA) CSR A, [NA,NA+NB) CSR B -------
// wave per node; 8 lanes per bf16 row (uint4). R9 load shape — do not restructure.
__global__ __launch_bounds__(256) void k_gather2(
    const u16* __restrict__ yA, const int* __restrict__ nbrA, const int* __restrict__ stpA,
    const int* __restrict__ degA, float* __restrict__ aggA, int NA,
    const u16* __restrict__ yB, const int* __restrict__ nbrB, const int* __restrict__ stpB,
    const int* __restrict__ degB, float* __restrict__ aggB, int NB) {
    int w = (blockIdx.x * 256 + threadIdx.x) >> 6;
    int lane = threadIdx.x & 63;
    if (w >= NA + NB) return;
    const u16* y; const int* nbr; const int* stp; const int* deg; float* agg; int n;
    if (w < NA) { y = yA; nbr = nbrA; stp = stpA; deg = degA; agg = aggA; n = w; }
    else        { y = yB; nbr = nbrB; stp = stpB; deg = degB; agg = aggB; n = w - NA; }
    const int q = lane >> 3, t = lane & 7;
    const int d = deg[n];
    const int st = stp[n];
    const char* yb = (const char*)y + t * 16;
    float2 a01 = make_float2(0.f, 0.f), a23 = make_float2(0.f, 0.f);
    float2 a45 = make_float2(0.f, 0.f), a67 = make_float2(0.f, 0.f);
    for (int j = 0; j < d; j += 64) {
        const int cnt = min(d - j, 64);           // wave-uniform
        int offv = 0;
        if (lane < cnt) offv = nbr[st + j + lane];   // one coalesced 256B load
        // distribute + burst-issue all row loads (independent, exec-masked tails)
#define GLD(R) \
        int g##R = __shfl(offv, R * 8 + q, 64); \
        uint4 v##R = make_uint4(0u, 0u, 0u, 0u); \
        if (R * 8 + q < cnt) v##R = *(const uint4*)(yb + g##R);
        GLD(0) GLD(1) GLD(2) GLD(3) GLD(4) GLD(5) GLD(6) GLD(7)
#undef GLD
        // accumulate (rounds beyond cnt are uniform-skipped; masked lanes hold 0)
#define ACCR(R) if (R * 8 < cnt) { ACC8(a01,a23,a45,a67,v##R) }
        ACCR(0) ACCR(1) ACCR(2) ACCR(3) ACCR(4) ACCR(5) ACCR(6) ACCR(7)
#undef ACCR
    }
#pragma unroll
    for (int m = 8; m < 64; m <<= 1) {
        a01.x += __shfl_xor(a01.x, m, 64); a01.y += __shfl_xor(a01.y, m, 64);
        a23.x += __shfl_xor(a23.x, m, 64); a23.y += __shfl_xor(a23.y, m, 64);
        a45.x += __shfl_xor(a45.x, m, 64); a45.y += __shfl_xor(a45.y, m, 64);
        a67.x += __shfl_xor(a67.x, m, 64); a67.y += __shfl_xor(a67.y, m, 64);
    }
    if (q == 0) {
        float dinv = 1.0f / (float)max(d, 1);
        float* dstp = agg + n * 64 + t * 8;
        *(float4*)dstp       = make_float4(a01.x * dinv, a01.y * dinv, a23.x * dinv, a23.y * dinv);
        *(float4*)(dstp + 4) = make_float4(a45.x * dinv, a45.y * dinv, a67.x * dinv, a67.y * dinv);
    }
}

// ======= paired combine: two independent K-dim problems, block-range selected =======
// COMPILE-TIME flags, IDENTICAL for both sides (R11 rule). Single K-loop body.
// h = act((PRE?pre:0) + (BIAS?b:0) + x@W); always STORE; optional RELU + EMIT.
template <int K, bool PRE, bool BIAS, bool RELU, bool EMIT>
__global__ __launch_bounds__(256) void k_ctilePairX(
    const float* __restrict__ pre0, const float* __restrict__ bias0,
    const float* __restrict__ x0, const float* __restrict__ W0,
    float* __restrict__ h0, u16* __restrict__ hbf0, int N0, int g0,
    const float* __restrict__ pre1, const float* __restrict__ bias1,
    const float* __restrict__ x1, const float* __restrict__ W1,
    float* __restrict__ h1, u16* __restrict__ hbf1, int N1) {
    constexpr int ROWS = (K == 64) ? 64 : 32;
    constexpr int RR = ROWS / 16;
    constexpr int STRIDE = K + 4;
    constexpr int KF4 = K / 4;
    __shared__ float Ws[K * 64];
    __shared__ float op[ROWS * STRIDE];
    const float* pre; const float* bias; const float* x; const float* W;
    float* h; u16* hbf;
    int N, bid, gsz;
    if ((int)blockIdx.x < g0) {
        pre = pre0; bias = bias0; x = x0; W = W0; h = h0; hbf = hbf0; N = N0;
        bid = blockIdx.x; gsz = g0;
    } else {
        pre = pre1; bias = bias1; x = x1; W = W1; h = h1; hbf = hbf1; N = N1;
        bid = blockIdx.x - g0; gsz = gridDim.x - g0;
    }
    const int tid = threadIdx.x;
    for (int i = tid; i < K * 16; i += 256)
        ((float4*)Ws)[i] = ((const float4*)W)[i];
    const int c4 = (tid & 15) * 4;
    const int rb = (tid >> 4) * RR;
    float bx_ = 0.f, by_ = 0.f, bz_ = 0.f, bw_ = 0.f;
    if (BIAS) {
        float4 b4 = *(const float4*)(bias + c4);
        bx_ = b4.x; by_ = b4.y; bz_ = b4.z; bw_ = b4.w;
    }
    const int ntiles = (N + ROWS - 1) / ROWS;
    for (int tile = bid; tile < ntiles; tile += gsz) {
        const int row0 = tile * ROWS;
        __syncthreads();
        for (int i = tid; i < ROWS * KF4; i += 256) {
            int r = i / KF4, k4 = (i % KF4) * 4;
            int row = row0 + r;
            float4 v = make_float4(0.f, 0.f, 0.f, 0.f);
            if (row < N) v = *(const float4*)(x + (size_t)row * K + k4);
            *(float4*)(op + r * STRIDE + k4) = v;
        }
        __syncthreads();
        float acc[RR][4];
#pragma unroll
        for (int i = 0; i < RR; ++i) {
            float px = 0.f, py = 0.f, pz = 0.f, pw = 0.f;
            if (PRE) {
                int row = row0 + rb + i;
                if (row < N) {
                    float4 p = *(const float4*)(pre + row * 64 + c4);
                    px = p.x; py = p.y; pz = p.z; pw = p.w;
                }
            }
            acc[i][0] = bx_ + px; acc[i][1] = by_ + py;
            acc[i][2] = bz_ + pz; acc[i][3] = bw_ + pw;
        }
        for (int kk = 0; kk < K; kk += 4) {
            float4 w0 = *(const float4*)(Ws + (kk + 0) * 64 + c4);
            float4 w1 = *(const float4*)(Ws + (kk + 1) * 64 + c4);
            float4 w2 = *(const float4*)(Ws + (kk + 2) * 64 + c4);
            float4 w3 = *(const float4*)(Ws + (kk + 3) * 64 + c4);
#pragma unroll
            for (int i = 0; i < RR; ++i) {
                float4 o = *(const float4*)(op + (rb + i) * STRIDE + kk);
                FMA_ROW(acc[i], o.x, w0);
                FMA_ROW(acc[i], o.y, w1);
                FMA_ROW(acc[i], o.z, w2);
                FMA_ROW(acc[i], o.w, w3);
            }
        }
#pragma unroll
        for (int i = 0; i < RR; ++i) {
            int row = row0 + rb + i;
            if (row >= N) continue;
            float v0 = acc[i][0], v1 = acc[i][1], v2 = acc[i][2], v3 = acc[i][3];
            if (RELU) {
                v0 = fmaxf(v0, 0.f); v1 = fmaxf(v1, 0.f);
                v2 = fmaxf(v2, 0.f); v3 = fmaxf(v3, 0.f);
            }
            *(float4*)(h + row * 64 + c4) = make_float4(v0, v1, v2, v3);
            if (EMIT) {
                uint2 o;
                o.x = (u32)bf16r(v0) | ((u32)bf16r(v1) << 16);
                o.y = (u32)bf16r(v2) | ((u32)bf16r(v3) << 16);
                *(uint2*)(hbf + row * 64 + c4) = o;
            }
        }
    }
}

// ======= paired CONCAT combine: h = bias + [xa|xb] @ [Wa;Wb], K=128 =======
// ONE K-loop, ONE LDS weight tile (filled from two 64x64 sources).
template <bool BIAS>
__global__ __launch_bounds__(256) void k_ctilePairCat(
    const float* __restrict__ bias0, const float* __restrict__ xa0,
    const float* __restrict__ xb0, const float* __restrict__ Wa0,
    const float* __restrict__ Wb0, float* __restrict__ h0, int N0, int g0,
    const float* __restrict__ bias1, const float* __restrict__ xa1,
    const float* __restrict__ xb1, const float* __restrict__ Wa1,
    const float* __restrict__ Wb1, float* __restrict__ h1, int N1) {
    constexpr int ROWS = 32, RR = 2, STRIDE = 132, KF4 = 32;
    __shared__ float Ws[128 * 64];
    __shared__ float op[ROWS * STRIDE];
    const float* bias; const float* xa; const float* xb;
    const float* Wa; const float* Wb; float* h;
    int N, bid, gsz;
    if ((int)blockIdx.x < g0) {
        bias = bias0; xa = xa0; xb = xb0; Wa = Wa0; Wb = Wb0; h = h0; N = N0;
        bid = blockIdx.x; gsz = g0;
    } else {
        bias = bias1; xa = xa1; xb = xb1; Wa = Wa1; Wb = Wb1; h = h1; N = N1;
        bid = blockIdx.x - g0; gsz = gridDim.x - g0;
    }
    const int tid = threadIdx.x;
    for (int i = tid; i < 64 * 16; i += 256) {
        ((float4*)Ws)[i]           = ((const float4*)Wa)[i];
        ((float4*)Ws)[64 * 16 + i] = ((const float4*)Wb)[i];
    }
    const int c4 = (tid & 15) * 4;
    const int rb = (tid >> 4) * RR;
    float bx_ = 0.f, by_ = 0.f, bz_ = 0.f, bw_ = 0.f;
    if (BIAS) {
        float4 b4 = *(const float4*)(bias + c4);
        bx_ = b4.x; by_ = b4.y; bz_ = b4.z; bw_ = b4.w;
    }
    const int ntiles = (N + ROWS - 1) / ROWS;
    for (int tile = bid; tile < ntiles; tile += gsz) {
        const int row0 = tile * ROWS;
        __syncthreads();
        for (int i = tid; i < ROWS * KF4; i += 256) {
            int r = i >> 5, k4 = (i & 31) * 4;
            int row = row0 + r;
            float4 v = make_float4(0.f, 0.f, 0.f, 0.f);
            if (row < N)
                v = (k4 < 64) ? *(const float4*)(xa + (size_t)row * 64 + k4)
                              : *(const float4*)(xb + (size_t)row * 64 + (k4 - 64));
            *(float4*)(op + r * STRIDE + k4) = v;
        }
        __syncthreads();
        float acc[RR][4];
#pragma unroll
        for (int i = 0; i < RR; ++i) {
            acc[i][0] = bx_; acc[i][1] = by_; acc[i][2] = bz_; acc[i][3] = bw_;
        }
        for (int kk = 0; kk < 128; kk += 4) {
            float4 w0 = *(const float4*)(Ws + (kk + 0) * 64 + c4);
            float4 w1 = *(const float4*)(Ws + (kk + 1) * 64 + c4);
            float4 w2 = *(const float4*)(Ws + (kk + 2) * 64 + c4);
            float4 w3 = *(const float4*)(Ws + (kk + 3) * 64 + c4);
#pragma unroll
            for (int i = 0; i < RR; ++i) {
                float4 o = *(const float4*)(op + (rb + i) * STRIDE + kk);
                FMA_ROW(acc[i], o.x, w0);
                FMA_ROW(acc[i], o.y, w1);
                FMA_ROW(acc[i], o.z, w2);
                FMA_ROW(acc[i], o.w, w3);
            }
        }
#pragma unroll
        for (int i = 0; i < RR; ++i) {
            int row = row0 + rb + i;
            if (row >= N) continue;
            *(float4*)(h + row * 64 + c4) =
                make_float4(acc[i][0], acc[i][1], acc[i][2], acc[i][3]);
        }
    }
}

// ------- sorted classifier over slack layout: slot -> (bucket=slot>>lsh,
// within=slot&(SLL-1)); valid iff within < cntL[bucket]. pairsL = (p, e). -------
__global__ __launch_bounds__(256) void k_classifyS(const float* __restrict__ hu,
                                                   const float* __restrict__ hp,
                                                   const int* __restrict__ lu,
                                                   const uint2* __restrict__ pairsL,
                                                   const int* __restrict__ cntL,
                                                   int lsh,
                                                   float* __restrict__ out, int nslots) {
    int w = (blockIdx.x * 256 + threadIdx.x) >> 6;
    int lane = threadIdx.x & 63;
    int q = lane >> 4, t = lane & 15;
    int slot = w * 4 + q;
    float v = 0.f;
    int e = 0;
    bool ok = false;
    if (slot < nslots) {
        int bucket = slot >> lsh;
        int within = slot & ((1 << lsh) - 1);
        if (within < cntL[bucket]) {
            uint2 pr = pairsL[slot];
            int p = (int)pr.x;
            e = (int)pr.y;
            int u = lu[e];
            float4 a = *(const float4*)(hu + (size_t)u * 64 + t * 4);
            float4 b = *(const float4*)(hp + (size_t)p * 64 + t * 4);
            v = a.x * b.x + a.y * b.y + a.z * b.z + a.w * b.w;
            ok = true;
        }
    }
#pragma unroll
    for (int m = 1; m < 16; m <<= 1) v += __shfl_xor(v, m, 64);
    if (t == 0 && ok) out[e] = v;
}

extern "C" void kernel_launch(void* const* d_in, const int* in_sizes, int n_in,
                              void* d_out, int out_size, void* d_ws, size_t ws_size,
                              hipStream_t stream) {
    const float* x_user    = (const float*)d_in[0];
    const float* x_product = (const float*)d_in[1];
    const float* W1bl = (const float*)d_in[2];
    const float* b1b  = (const float*)d_in[3];
    const float* W1br = (const float*)d_in[4];
    const float* W1rl = (const float*)d_in[5];
    const float* b1r  = (const float*)d_in[6];
    const float* W1rr = (const float*)d_in[7];
    const float* W2bl = (const float*)d_in[8];
    const float* b2b  = (const float*)d_in[9];
    const float* W2br = (const float*)d_in[10];
    const float* W2rl = (const float*)d_in[11];
    const float* b2r  = (const float*)d_in[12];
    const float* W2rr = (const float*)d_in[13];
    const int* esrc = (const int*)d_in[14];
    const int* edst = (const int*)d_in[15];
    const int* lu   = (const int*)d_in[16];
    const int* lp   = (const int*)d_in[17];

    const int NU = in_sizes[0] / 64;
    const int NP = in_sizes[1] / 128;
    const int E  = in_sizes[14];
    const int EL = in_sizes[16];
    const int NBP = (NP + 255) >> BSH;
    const int NBU = (NU + 255) >> BSH;
    const int NBL = NBP;                        // lab_p keys share the P id space

    // ---- slack sizes: mean + mean/8 + 1024 (>20 sigma for Binomial buckets) ----
    const int SLP = E / NBP + E / (NBP * 8) + 1024;
    const int SLU = E / NBU + E / (NBU * 8) + 1024;
    int lneed = EL / NBL + EL / (NBL * 4) + 512;
    int lsh = 1;
    while ((1 << lsh) < lneed) ++lsh;           // pow2 slack for labels (4096 here)
    const int SLL = 1 << lsh;

    // ---- workspace layout ----
    char* ws = (char*)d_ws;
    size_t off = 0;
    auto alloc = [&](size_t bytes) -> void* {
        void* p = ws + off;
        off += (bytes + 255) & ~(size_t)255;
        return p;
    };
    int*   deg_u  = (int*)alloc((size_t)NU * 4);
    int*   deg_p  = (int*)alloc((size_t)NP * 4);
    int*   ptr_u  = (int*)alloc((size_t)NU * 4);
    int*   ptr_p  = (int*)alloc((size_t)NP * 4);
    int*   curP   = (int*)alloc((size_t)MAXB * 4);   // P,U,L contiguous: one memset
    int*   curU   = (int*)alloc((size_t)MAXB * 4);
    int*   curL   = (int*)alloc((size_t)MAXB * 4);
    int*   nbr_u  = (int*)alloc((size_t)NBU * SLU * 4);
    int*   nbr_p  = (int*)alloc((size_t)NBP * SLP * 4);
    uint2* pairsL = (uint2*)alloc((size_t)NBL * SLL * 8);  // survives until classify
    // union region: pairs (CSR build) then agg (gather onward)
    size_t aggBytes = (size_t)(NP + NU) * 64 * 4;
    size_t pairBytes = ((size_t)NBP * SLP + (size_t)NBU * SLU) * 8;
    char* uni = (char*)alloc(aggBytes > pairBytes ? aggBytes : pairBytes);
    float* aggP   = (float*)uni;
    float* aggU   = (float*)(uni + (size_t)NP * 64 * 4);
    uint2* pairsP = (uint2*)uni;
    uint2* pairsU = (uint2*)(uni + (size_t)NBP * SLP * 8);
    u16*   bfA    = (u16*)alloc((size_t)NU * 64 * 2);  // x_user_bf, then h_u_bf
    u16*   bfB    = (u16*)alloc((size_t)NP * 64 * 2);  // y_p1_bf,  then h_p_bf
    float* h_p    = (float*)alloc((size_t)NP * 64 * 4);
    float* h_u    = (float*)alloc((size_t)NU * 64 * 4);
    // pre-gather dead-write sinks (h_u not yet live: fully overwritten later)
    float* sinkF  = h_u;                               // NP*64*4 = 12.8MB
    u16*   sinkB  = (u16*)((char*)h_u + (size_t)NP * 64 * 4);  // 6.4MB more

    const int tP32 = (NP + 31) / 32;
    const int tU32 = (NU + 31) / 32;
    const int tP64 = (NP + 63) / 64, tU64 = (NU + 63) / 64;
    auto cap = [](int t, int c) { return t < c ? t : c; };

    // ---- CSR build + label sort + cast + pre-gather ctile: ONE fused launch ----
    hipMemsetAsync(curP, 0, (size_t)MAXB * 3 * 4, stream);  // P,U,L contiguous
    const int n8 = NU * 64 / 8;
    const int castBlocks = (n8 + 255) / 256;
    const int pblocks = (E + CHUNK - 1) / CHUNK;
    const int lblocks = (EL + CHUNK - 1) / CHUNK;
    const int g128 = cap(tP32, 768);
    const int ctStart = 2 * pblocks + lblocks + castBlocks;
    k_partCast<<<ctStart + 2 * g128, 256, 0, stream>>>(
        edst, esrc, curP, pairsP, NBP, SLP,
        esrc, edst, curU, pairsU, NBU, SLU, E, pblocks,
        lp, curL, pairsL, NBL, SLL, EL, lblocks,
        x_user, bfA, n8,
        ctStart, g128,
        x_product, W1rl, W1br, bfB, h_p, sinkF, sinkB, NP);
    k_bucketFill<<<NBP + NBU, 256, 0, stream>>>(
        pairsP, curP, NBP, SLP, nbr_p, deg_p, ptr_p, NP,
        pairsU, curU, NBU, SLU, nbr_u, deg_u, ptr_u, NU);

    // ---- layer 1: fused dual gather, then ONE paired combine ----
    k_gather2<<<(NP + NU + 3) / 4, 256, 0, stream>>>(bfA, nbr_p, ptr_p, deg_p, aggP, NP,
                                                     bfB, nbr_u, ptr_u, deg_u, aggU, NU);
    // side0: h_p = relu(h_p + b1b + aggP@W1bl), emit bfB
    // side1: h_u = relu(aggU + b1r + x_user@W1rr), emit bfA
    {
        const int gP = cap(tP64, 512), gU = cap(tU64, 1024);
        k_ctilePairX<64, true, true, true, true><<<gP + gU, 256, 0, stream>>>(
            h_p, b1b, aggP, W1bl, h_p, bfB, NP, gP,
            aggU, b1r, x_user, W1rr, h_u, bfA, NU);
    }

    // ---- layer 2: fused dual gather, then ONE concat-K combine ----
    k_gather2<<<(NP + NU + 3) / 4, 256, 0, stream>>>(bfA, nbr_p, ptr_p, deg_p, aggP, NP,
                                                     bfB, nbr_u, ptr_u, deg_u, aggU, NU);
    // side0: h_p = b2b + [aggP|h_p] @ [W2bl;W2br]
    // side1: h_u = b2r + [aggU|h_u] @ [W2rl;W2rr]
    {
        const int gP = cap(tP32, 512), gU = cap(tU32, 1024);
        k_ctilePairCat<true><<<gP + gU, 256, 0, stream>>>(
            b2b, aggP, h_p, W2bl, W2br, h_p, NP, gP,
            b2r, aggU, h_u, W2rl, W2rr, h_u, NU);
    }

    // ---- classifier over p-sorted label pairs (slack layout) ----
    const int nslots = NBL << lsh;
    k_classifyS<<<((nslots + 3) / 4 + 3) / 4, 256, 0, stream>>>(
        h_u, h_p, lu, pairsL, curL, lsh, (float*)d_out, nslots);
}